// Round 4
// baseline (575.097 us; speedup 1.0000x reference)
//
#include <hip/hip_runtime.h>

#define N_NODES 50000
#define N_EDGES 800000
#define N_GRAPHS 512
#define F_IN 128
#define HDIM 96
#define NCLS 10
#define BN_EPS 1e-5f
#define NBUCK ((N_NODES + 15) / 16)   // CSR fill buckets of 16 nodes

typedef unsigned int u32;
typedef unsigned short u16;

__device__ __forceinline__ u16 f2bf(float f) {
    u32 u = __float_as_uint(f);
    u32 r = (u + 0x7fffu + ((u >> 16) & 1u)) >> 16;   // RNE
    return (u16)r;
}
__device__ __forceinline__ float bflo(u32 w) { return __uint_as_float(w << 16); }
__device__ __forceinline__ float bfhi(u32 w) { return __uint_as_float(w & 0xffff0000u); }

// ---------------- column stats (sum, sumsq) over rows ----------------
template<int NC>
__global__ __launch_bounds__(2*NC) void colstats_kernel(const float* __restrict__ in,
                                                        float* __restrict__ stats,
                                                        int nrows) {
    const int col  = threadIdx.x % NC;
    const int half = threadIdx.x / NC;
    float s = 0.f, ss = 0.f;
    for (int r = blockIdx.x * 2 + half; r < nrows; r += gridDim.x * 2) {
        float v = in[(size_t)r * NC + col];
        s += v; ss += v * v;
    }
    __shared__ float shs[2][NC], shq[2][NC];
    shs[half][col] = s; shq[half][col] = ss;
    __syncthreads();
    if (half == 0) {
        atomicAdd(&stats[col],      s  + shs[1][col]);
        atomicAdd(&stats[NC + col], ss + shq[1][col]);
    }
}

// stats -> per-column affine (a = w*rsqrt(var+eps), c = b - mu*a)
__global__ void finalize_bn_kernel(const float* __restrict__ stats,
                                   const float* __restrict__ w,
                                   const float* __restrict__ b,
                                   float* __restrict__ ac, int ncols, float inv_n) {
    int k = blockIdx.x * blockDim.x + threadIdx.x;
    if (k < ncols) {
        float mu  = stats[k] * inv_n;
        float var = stats[ncols + k] * inv_n - mu * mu;
        float a   = w[k] * rsqrtf(var + BN_EPS);
        ac[k]         = a;
        ac[ncols + k] = b[k] - mu * a;
    }
}

// ---------------- CSR build (by dst) ----------------
__global__ void hist_kernel(const int* __restrict__ dst, int* __restrict__ deg, int ne) {
    int e = blockIdx.x * blockDim.x + threadIdx.x;
    if (e < ne) atomicAdd(&deg[dst[e]], 1);
}

// multi-block exclusive scan
__global__ __launch_bounds__(1024) void scan1_kernel(const int* __restrict__ deg,
                                                     int* __restrict__ tmp,
                                                     int* __restrict__ partial, int n) {
    __shared__ int sh[1024];
    const int i = blockIdx.x * 1024 + threadIdx.x;
    const int d = (i < n) ? deg[i] : 0;
    sh[threadIdx.x] = d;
    __syncthreads();
    for (int off = 1; off < 1024; off <<= 1) {
        int v = 0;
        if (threadIdx.x >= off) v = sh[threadIdx.x - off];
        __syncthreads();
        sh[threadIdx.x] += v;
        __syncthreads();
    }
    if (i < n) tmp[i] = sh[threadIdx.x] - d;
    if (threadIdx.x == 1023) partial[blockIdx.x] = sh[1023];
}

__global__ void scan2_kernel(int* __restrict__ partial, int nparts) {
    const int t = threadIdx.x;
    int d = (t < nparts) ? partial[t] : 0;
    int v = d;
    for (int off = 1; off < 64; off <<= 1) {
        int u = __shfl_up(v, off, 64);
        if (t >= off) v += u;
    }
    if (t < nparts) partial[t] = v - d;
}

__global__ __launch_bounds__(1024) void scan3_kernel(const int* __restrict__ tmp,
                                                     const int* __restrict__ partial,
                                                     const int* __restrict__ deg,
                                                     int* __restrict__ row_ptr,
                                                     int* __restrict__ cursor, int n) {
    const int i = blockIdx.x * 1024 + threadIdx.x;
    if (i < n) {
        int v = tmp[i] + partial[blockIdx.x];
        row_ptr[i] = v; cursor[i] = v;
        if (i == n - 1) row_ptr[n] = v + deg[i];
    }
}

// bucket stream cursors come free from row_ptr (bucket b covers nodes [16b, 16b+16))
__global__ void init_bcursor_kernel(const int* __restrict__ row_ptr, int* __restrict__ bcursor) {
    int b = blockIdx.x * blockDim.x + threadIdx.x;
    if (b < NBUCK) bcursor[b] = row_ptr[b * 16];
}

// pass A: compute final csr position, write (src,pos) bucket-grouped (L2-local streams)
__global__ void fillA_kernel(const int* __restrict__ src, const int* __restrict__ dst,
                             int* __restrict__ cursor, int* __restrict__ bcursor,
                             uint2* __restrict__ ebuf, int ne) {
    int e = blockIdx.x * blockDim.x + threadIdx.x;
    if (e < ne) {
        int d = dst[e];
        int pos = atomicAdd(&cursor[d], 1);
        int q   = atomicAdd(&bcursor[d >> 4], 1);
        ebuf[q] = make_uint2((u32)src[e], (u32)pos);
    }
}

// pass B: stream bucket-grouped pairs, scatter into csr (writes localized per block)
__global__ void fillB_kernel(const uint2* __restrict__ ebuf, int* __restrict__ csr, int ne) {
    int e = blockIdx.x * blockDim.x + threadIdx.x;
    if (e < ne) {
        uint2 v = ebuf[e];
        csr[v.y] = (int)v.x;
    }
}

// ---------------- GIN aggregation: m[n] = h[n] + sum_{s in nbr(n)} h[s] ----------------
__global__ __launch_bounds__(192) void agg_kernel(const u16* __restrict__ hb,
                                                  const int* __restrict__ row_ptr,
                                                  const int* __restrict__ csr,
                                                  float* __restrict__ m, int n) {
    const int jj   = threadIdx.x % 24;       // columns jj*4 .. jj*4+3
    const int node = blockIdx.x * 8 + threadIdx.x / 24;
    if (node >= n) return;
    const int p0 = row_ptr[node], p1 = row_ptr[node + 1];
    uint2 sv = *(const uint2*)&hb[(size_t)node * 96 + jj * 4];
    float a0 = bflo(sv.x), a1 = bfhi(sv.x), a2 = bflo(sv.y), a3 = bfhi(sv.y);
    int p = p0;
    for (; p + 8 <= p1; p += 8) {
        int s0 = csr[p],     s1 = csr[p + 1], s2 = csr[p + 2], s3 = csr[p + 3];
        int s4 = csr[p + 4], s5 = csr[p + 5], s6 = csr[p + 6], s7 = csr[p + 7];
        uint2 v0 = *(const uint2*)&hb[(size_t)s0 * 96 + jj * 4];
        uint2 v1 = *(const uint2*)&hb[(size_t)s1 * 96 + jj * 4];
        uint2 v2 = *(const uint2*)&hb[(size_t)s2 * 96 + jj * 4];
        uint2 v3 = *(const uint2*)&hb[(size_t)s3 * 96 + jj * 4];
        uint2 v4 = *(const uint2*)&hb[(size_t)s4 * 96 + jj * 4];
        uint2 v5 = *(const uint2*)&hb[(size_t)s5 * 96 + jj * 4];
        uint2 v6 = *(const uint2*)&hb[(size_t)s6 * 96 + jj * 4];
        uint2 v7 = *(const uint2*)&hb[(size_t)s7 * 96 + jj * 4];
        a0 += ((bflo(v0.x) + bflo(v1.x)) + (bflo(v2.x) + bflo(v3.x)))
            + ((bflo(v4.x) + bflo(v5.x)) + (bflo(v6.x) + bflo(v7.x)));
        a1 += ((bfhi(v0.x) + bfhi(v1.x)) + (bfhi(v2.x) + bfhi(v3.x)))
            + ((bfhi(v4.x) + bfhi(v5.x)) + (bfhi(v6.x) + bfhi(v7.x)));
        a2 += ((bflo(v0.y) + bflo(v1.y)) + (bflo(v2.y) + bflo(v3.y)))
            + ((bflo(v4.y) + bflo(v5.y)) + (bflo(v6.y) + bflo(v7.y)));
        a3 += ((bfhi(v0.y) + bfhi(v1.y)) + (bfhi(v2.y) + bfhi(v3.y)))
            + ((bfhi(v4.y) + bfhi(v5.y)) + (bfhi(v6.y) + bfhi(v7.y)));
    }
    for (; p + 4 <= p1; p += 4) {
        int s0 = csr[p], s1 = csr[p + 1], s2 = csr[p + 2], s3 = csr[p + 3];
        uint2 v0 = *(const uint2*)&hb[(size_t)s0 * 96 + jj * 4];
        uint2 v1 = *(const uint2*)&hb[(size_t)s1 * 96 + jj * 4];
        uint2 v2 = *(const uint2*)&hb[(size_t)s2 * 96 + jj * 4];
        uint2 v3 = *(const uint2*)&hb[(size_t)s3 * 96 + jj * 4];
        a0 += (bflo(v0.x) + bflo(v1.x)) + (bflo(v2.x) + bflo(v3.x));
        a1 += (bfhi(v0.x) + bfhi(v1.x)) + (bfhi(v2.x) + bfhi(v3.x));
        a2 += (bflo(v0.y) + bflo(v1.y)) + (bflo(v2.y) + bflo(v3.y));
        a3 += (bfhi(v0.y) + bfhi(v1.y)) + (bfhi(v2.y) + bfhi(v3.y));
    }
    for (; p < p1; p++) {
        int s = csr[p];
        uint2 v = *(const uint2*)&hb[(size_t)s * 96 + jj * 4];
        a0 += bflo(v.x); a1 += bfhi(v.x); a2 += bflo(v.y); a3 += bfhi(v.y);
    }
    *(float4*)&m[(size_t)node * 96 + jj * 4] = make_float4(a0, a1, a2, a3);
}

// ---------------- weight-resident tiled matmul ----------------
// POOL: instead of writing rows, atomicAdd into g[batch[row]*96+col] (last layer).
template<int KDIM, bool IN_AFF, bool IN_RELU, bool OUT_RELU, bool STATS, bool OUT_BF16, bool POOL>
__global__ __launch_bounds__(192) void mm_kernel(const float* __restrict__ in,
                                                 const float* __restrict__ W,
                                                 const float* __restrict__ bias,
                                                 const float* __restrict__ ac,
                                                 void* __restrict__ out_,
                                                 float* __restrict__ stats,
                                                 const int* __restrict__ batch, int nrows) {
    constexpr int KG = KDIM / 4;
    __shared__ float ws[KDIM][96];
    __shared__ float xs[32][KDIM];   // columns stored XOR-swizzled: [r][4*((k/4)^(r&7)) + k%4]
    const int tid = threadIdx.x;
    const int cg  = tid % 24;        // cols 4cg .. 4cg+3
    const int rg  = tid / 24;        // rows rg, rg+8, rg+16, rg+24 within chunk

    for (int i = tid; i < KDIM * 24; i += 192) {
        int k = i / 24, c4 = i % 24;
        *(float4*)&ws[k][c4 * 4] = *(const float4*)&W[(size_t)k * 96 + c4 * 4];
    }
    const float4 bj = *(const float4*)&bias[cg * 4];

    float s0=0,s1=0,s2=0,s3=0, q0=0,q1=0,q2=0,q3=0;

    const int nchunks = (nrows + 31) / 32;
    for (int chunk = blockIdx.x; chunk < nchunks; chunk += gridDim.x) {
        const int row0 = chunk * 32;
        __syncthreads();
        for (int i = tid; i < 32 * KG; i += 192) {
            int r = i / KG, g = i % KG;
            int gr = row0 + r;
            float4 v = make_float4(0.f, 0.f, 0.f, 0.f);
            if (gr < nrows) v = *(const float4*)&in[(size_t)gr * KDIM + g * 4];
            if constexpr (IN_AFF) {
                float4 a = *(const float4*)&ac[g * 4];
                float4 c = *(const float4*)&ac[KDIM + g * 4];
                v.x = v.x * a.x + c.x; v.y = v.y * a.y + c.y;
                v.z = v.z * a.z + c.z; v.w = v.w * a.w + c.w;
            }
            if constexpr (IN_RELU) {
                v.x = fmaxf(v.x, 0.f); v.y = fmaxf(v.y, 0.f);
                v.z = fmaxf(v.z, 0.f); v.w = fmaxf(v.w, 0.f);
            }
            *(float4*)&xs[r][4 * (g ^ (r & 7))] = v;
        }
        __syncthreads();

        float acc[4][4];
        #pragma unroll
        for (int m = 0; m < 4; m++) {
            acc[m][0] = bj.x; acc[m][1] = bj.y; acc[m][2] = bj.z; acc[m][3] = bj.w;
        }

        #pragma unroll 4
        for (int g = 0; g < KG; g++) {
            const int xi = 4 * (g ^ rg);
            float4 xv0 = *(const float4*)&xs[rg     ][xi];
            float4 xv1 = *(const float4*)&xs[rg +  8][xi];
            float4 xv2 = *(const float4*)&xs[rg + 16][xi];
            float4 xv3 = *(const float4*)&xs[rg + 24][xi];
            #pragma unroll
            for (int i = 0; i < 4; i++) {
                float4 wv = *(const float4*)&ws[g * 4 + i][cg * 4];
                float x0 = (i==0)?xv0.x:(i==1)?xv0.y:(i==2)?xv0.z:xv0.w;
                float x1 = (i==0)?xv1.x:(i==1)?xv1.y:(i==2)?xv1.z:xv1.w;
                float x2 = (i==0)?xv2.x:(i==1)?xv2.y:(i==2)?xv2.z:xv2.w;
                float x3 = (i==0)?xv3.x:(i==1)?xv3.y:(i==2)?xv3.z:xv3.w;
                acc[0][0] = fmaf(x0, wv.x, acc[0][0]); acc[0][1] = fmaf(x0, wv.y, acc[0][1]);
                acc[0][2] = fmaf(x0, wv.z, acc[0][2]); acc[0][3] = fmaf(x0, wv.w, acc[0][3]);
                acc[1][0] = fmaf(x1, wv.x, acc[1][0]); acc[1][1] = fmaf(x1, wv.y, acc[1][1]);
                acc[1][2] = fmaf(x1, wv.z, acc[1][2]); acc[1][3] = fmaf(x1, wv.w, acc[1][3]);
                acc[2][0] = fmaf(x2, wv.x, acc[2][0]); acc[2][1] = fmaf(x2, wv.y, acc[2][1]);
                acc[2][2] = fmaf(x2, wv.z, acc[2][2]); acc[2][3] = fmaf(x2, wv.w, acc[2][3]);
                acc[3][0] = fmaf(x3, wv.x, acc[3][0]); acc[3][1] = fmaf(x3, wv.y, acc[3][1]);
                acc[3][2] = fmaf(x3, wv.z, acc[3][2]); acc[3][3] = fmaf(x3, wv.w, acc[3][3]);
            }
        }

        if constexpr (POOL) {
            float* gbuf = (float*)out_;
            const int r0 = row0 + rg;
            // rows r0, r0+8, r0+16, r0+24; batch is sorted -> often same graph
            int b0 = (r0      < nrows) ? batch[r0]      : -1;
            int b3 = (r0 + 24 < nrows) ? batch[r0 + 24] : -2;
            #pragma unroll
            for (int m = 0; m < 4; m++) {
                if constexpr (OUT_RELU) {
                    acc[m][0] = fmaxf(acc[m][0], 0.f); acc[m][1] = fmaxf(acc[m][1], 0.f);
                    acc[m][2] = fmaxf(acc[m][2], 0.f); acc[m][3] = fmaxf(acc[m][3], 0.f);
                }
            }
            if (b0 == b3) {
                float4 t = make_float4(acc[0][0]+acc[1][0]+acc[2][0]+acc[3][0],
                                       acc[0][1]+acc[1][1]+acc[2][1]+acc[3][1],
                                       acc[0][2]+acc[1][2]+acc[2][2]+acc[3][2],
                                       acc[0][3]+acc[1][3]+acc[2][3]+acc[3][3]);
                float* gp = &gbuf[(size_t)b0 * 96 + cg * 4];
                atomicAdd(gp,     t.x); atomicAdd(gp + 1, t.y);
                atomicAdd(gp + 2, t.z); atomicAdd(gp + 3, t.w);
            } else {
                #pragma unroll
                for (int m = 0; m < 4; m++) {
                    const int gr = r0 + 8 * m;
                    if (gr < nrows) {
                        float* gp = &gbuf[(size_t)batch[gr] * 96 + cg * 4];
                        atomicAdd(gp,     acc[m][0]); atomicAdd(gp + 1, acc[m][1]);
                        atomicAdd(gp + 2, acc[m][2]); atomicAdd(gp + 3, acc[m][3]);
                    }
                }
            }
        } else {
            #pragma unroll
            for (int m = 0; m < 4; m++) {
                const int gr = row0 + rg + 8 * m;
                if (gr < nrows) {
                    float4 o = make_float4(acc[m][0], acc[m][1], acc[m][2], acc[m][3]);
                    if constexpr (OUT_RELU) {
                        o.x = fmaxf(o.x, 0.f); o.y = fmaxf(o.y, 0.f);
                        o.z = fmaxf(o.z, 0.f); o.w = fmaxf(o.w, 0.f);
                    }
                    if constexpr (OUT_BF16) {
                        u16* ob = (u16*)out_;
                        ushort4 t;
                        t.x = f2bf(o.x); t.y = f2bf(o.y); t.z = f2bf(o.z); t.w = f2bf(o.w);
                        *(ushort4*)&ob[(size_t)gr * 96 + cg * 4] = t;
                    } else {
                        float* of = (float*)out_;
                        *(float4*)&of[(size_t)gr * 96 + cg * 4] = o;
                    }
                    if constexpr (STATS) {
                        s0 += o.x; q0 += o.x * o.x;
                        s1 += o.y; q1 += o.y * o.y;
                        s2 += o.z; q2 += o.z * o.z;
                        s3 += o.w; q3 += o.w * o.w;
                    }
                }
            }
        }
    }

    if constexpr (STATS) {
        __syncthreads();
        float* rs = &xs[0][0];
        float* rq = rs + 8 * 96;
        rs[rg * 96 + cg * 4 + 0] = s0; rs[rg * 96 + cg * 4 + 1] = s1;
        rs[rg * 96 + cg * 4 + 2] = s2; rs[rg * 96 + cg * 4 + 3] = s3;
        rq[rg * 96 + cg * 4 + 0] = q0; rq[rg * 96 + cg * 4 + 1] = q1;
        rq[rg * 96 + cg * 4 + 2] = q2; rq[rg * 96 + cg * 4 + 3] = q3;
        __syncthreads();
        if (tid < 96) {
            float a = 0.f, b = 0.f;
            #pragma unroll
            for (int r = 0; r < 8; r++) { a += rs[r * 96 + tid]; b += rq[r * 96 + tid]; }
            atomicAdd(&stats[tid],      a);
            atomicAdd(&stats[96 + tid], b);
        }
    }
}

// ---------------- head: logits = BN(g1) @ Wc + bc, then log_softmax ----------------
__global__ void head_kernel(const float* __restrict__ g1, const float* __restrict__ ac,
                            const float* __restrict__ Wc, const float* __restrict__ bc,
                            float* __restrict__ out, int ngraphs) {
    int gi = blockIdx.x * blockDim.x + threadIdx.x;
    if (gi >= ngraphs) return;
    float v[NCLS];
    #pragma unroll
    for (int c = 0; c < NCLS; c++) v[c] = bc[c];
    for (int k = 0; k < HDIM; k++) {
        float x = g1[(size_t)gi * HDIM + k] * ac[k] + ac[HDIM + k];
        #pragma unroll
        for (int c = 0; c < NCLS; c++) v[c] = fmaf(x, Wc[k * NCLS + c], v[c]);
    }
    float mx = v[0];
    #pragma unroll
    for (int c = 1; c < NCLS; c++) mx = fmaxf(mx, v[c]);
    float sum = 0.f;
    #pragma unroll
    for (int c = 0; c < NCLS; c++) sum += expf(v[c] - mx);
    float lse = mx + logf(sum);
    #pragma unroll
    for (int c = 0; c < NCLS; c++) out[(size_t)gi * NCLS + c] = v[c] - lse;
}

extern "C" void kernel_launch(void* const* d_in, const int* in_sizes, int n_in,
                              void* d_out, int out_size, void* d_ws, size_t ws_size,
                              hipStream_t stream) {
    const float* x         = (const float*)d_in[0];
    const int*   ei        = (const int*)  d_in[1];
    const int*   batch     = (const int*)  d_in[2];
    const float* bn_feat_w = (const float*)d_in[3];
    const float* bn_feat_b = (const float*)d_in[4];
    const float* Wf        = (const float*)d_in[5];
    const float* bfv       = (const float*)d_in[6];
    const float* bn_fc_w   = (const float*)d_in[7];
    const float* bn_fc_b   = (const float*)d_in[8];
    const float* Wl        = (const float*)d_in[9];
    const float* bl        = (const float*)d_in[10];
    const float* bn_hid_w  = (const float*)d_in[11];
    const float* bn_hid_b  = (const float*)d_in[12];
    const float* Wc        = (const float*)d_in[13];
    const float* bc        = (const float*)d_in[14];
    float* out = (float*)d_out;

    char* p = (char*)d_ws;
    auto alloc = [&](size_t bytes) { char* q = p; p += (bytes + 255) & ~(size_t)255; return q; };
    u16*   hb     = (u16*)  alloc((size_t)N_NODES * HDIM * 2);
    float* buf    = (float*)alloc((size_t)N_NODES * HDIM * 4);
    float* g      = (float*)alloc((size_t)N_GRAPHS * HDIM * 4);
    float* g1     = (float*)alloc((size_t)N_GRAPHS * HDIM * 4);
    float* statsX = (float*)alloc(2 * F_IN * 4);
    float* acX    = (float*)alloc(2 * F_IN * 4);
    float* statsT = (float*)alloc(2 * HDIM * 4);
    float* acT    = (float*)alloc(2 * HDIM * 4);
    float* statsG = (float*)alloc(2 * HDIM * 4);
    float* acG    = (float*)alloc(2 * HDIM * 4);
    float* statsG1= (float*)alloc(2 * HDIM * 4);
    float* acHid  = (float*)alloc(2 * HDIM * 4);
    int* deg      = (int*)alloc((size_t)N_NODES * 4);
    int* row_ptr  = (int*)alloc((size_t)(N_NODES + 1) * 4);
    int* cursor   = (int*)alloc((size_t)N_NODES * 4);
    int* csr      = (int*)alloc((size_t)N_EDGES * 4);
    int* stmp     = (int*)alloc((size_t)N_NODES * 4);
    int* spart    = (int*)alloc(64 * 4);
    int* bcursor  = (int*)alloc((size_t)NBUCK * 4);
    uint2* ebuf   = (uint2*)alloc((size_t)N_EDGES * 8);

    const int* srcp = ei;
    const int* dstp = ei + N_EDGES;

    const int nchunks = (N_NODES + 31) / 32;
    const int grid128 = (nchunks < 512) ? nchunks : 512;
    const int grid96  = (nchunks < 750) ? nchunks : 750;
    const int gridG   = (N_GRAPHS + 31) / 32;
    const int nscan   = (N_NODES + 1023) / 1024;

    // BN(x) stats, then h = relu(BN(x) @ Wf + bf)  (h stored bf16)
    hipMemsetAsync(statsX, 0, 2 * F_IN * 4, stream);
    colstats_kernel<F_IN><<<256, 2 * F_IN, 0, stream>>>(x, statsX, N_NODES);
    finalize_bn_kernel<<<1, F_IN, 0, stream>>>(statsX, bn_feat_w, bn_feat_b, acX, F_IN, 1.0f / N_NODES);
    mm_kernel<F_IN, true, false, true, false, true, false><<<grid128, 192, 0, stream>>>(x, Wf, bfv, acX, hb, nullptr, nullptr, N_NODES);

    // CSR build (once; reused by all 3 layers)
    hipMemsetAsync(deg, 0, (size_t)N_NODES * 4, stream);
    hist_kernel<<<(N_EDGES + 255) / 256, 256, 0, stream>>>(dstp, deg, N_EDGES);
    scan1_kernel<<<nscan, 1024, 0, stream>>>(deg, stmp, spart, N_NODES);
    scan2_kernel<<<1, 64, 0, stream>>>(spart, nscan);
    scan3_kernel<<<nscan, 1024, 0, stream>>>(stmp, spart, deg, row_ptr, cursor, N_NODES);
    init_bcursor_kernel<<<(NBUCK + 255) / 256, 256, 0, stream>>>(row_ptr, bcursor);
    fillA_kernel<<<(N_EDGES + 255) / 256, 256, 0, stream>>>(srcp, dstp, cursor, bcursor, ebuf, N_EDGES);
    fillB_kernel<<<(N_EDGES + 255) / 256, 256, 0, stream>>>(ebuf, csr, N_EDGES);

    // zero pooled buffer (written by last layer's fused mm2)
    hipMemsetAsync(g, 0, (size_t)N_GRAPHS * HDIM * 4, stream);

    for (int l = 0; l < 3; l++) {
        const float* W1 = (const float*)d_in[15 + 6 * l];
        const float* b1 = (const float*)d_in[16 + 6 * l];
        const float* bw = (const float*)d_in[17 + 6 * l];
        const float* bb = (const float*)d_in[18 + 6 * l];
        const float* W2 = (const float*)d_in[19 + 6 * l];
        const float* b2 = (const float*)d_in[20 + 6 * l];
        // m = h + sum_nbr(h)  (bf16 gathers -> f32 buf)
        agg_kernel<<<(N_NODES + 7) / 8, 192, 0, stream>>>(hb, row_ptr, csr, buf, N_NODES);
        // t = m @ W1 + b1 (in-place on buf), fused stats(t)
        hipMemsetAsync(statsT, 0, 2 * HDIM * 4, stream);
        mm_kernel<HDIM, false, false, false, true, false, false><<<grid96, 192, 0, stream>>>(buf, W1, b1, nullptr, buf, statsT, nullptr, N_NODES);
        finalize_bn_kernel<<<1, HDIM, 0, stream>>>(statsT, bw, bb, acT, HDIM, 1.0f / N_NODES);
        // h = relu( relu(BN(t)) @ W2 + b2 ): layers 0,1 -> bf16 h; layer 2 -> fused pool
        if (l < 2) {
            mm_kernel<HDIM, true, true, true, false, true, false><<<grid96, 192, 0, stream>>>(buf, W2, b2, acT, hb, nullptr, nullptr, N_NODES);
        } else {
            mm_kernel<HDIM, true, true, true, false, false, true><<<grid96, 192, 0, stream>>>(buf, W2, b2, acT, g, nullptr, batch, N_NODES);
        }
    }

    // g1 = relu(BN_fc(g) @ Wl + bl), fused stats(g1)
    hipMemsetAsync(statsG, 0, 2 * HDIM * 4, stream);
    colstats_kernel<HDIM><<<64, 2 * HDIM, 0, stream>>>(g, statsG, N_GRAPHS);
    finalize_bn_kernel<<<1, HDIM, 0, stream>>>(statsG, bn_fc_w, bn_fc_b, acG, HDIM, 1.0f / N_GRAPHS);
    hipMemsetAsync(statsG1, 0, 2 * HDIM * 4, stream);
    mm_kernel<HDIM, true, false, true, true, false, false><<<gridG, 192, 0, stream>>>(g, Wl, bl, acG, g1, statsG1, nullptr, N_GRAPHS);
    finalize_bn_kernel<<<1, HDIM, 0, stream>>>(statsG1, bn_hid_w, bn_hid_b, acHid, HDIM, 1.0f / N_GRAPHS);

    // logits + log_softmax
    head_kernel<<<2, 256, 0, stream>>>(g1, acHid, Wc, bc, out, N_GRAPHS);
}

// Round 5
// 513.174 us; speedup vs baseline: 1.1207x; 1.1207x over previous
//
#include <hip/hip_runtime.h>

#define N_NODES 50000
#define N_EDGES 800000
#define N_GRAPHS 512
#define F_IN 128
#define HDIM 96
#define NCLS 10
#define BN_EPS 1e-5f

// partitioned CSR fill geometry
#define NPB 128                            // nodes per bucket
#define NBUCK2 ((N_NODES + NPB - 1) / NPB) // 391 buckets
#define NEB 64                             // edge-partition blocks
#define EPB ((N_EDGES + NEB - 1) / NEB)    // 12500 edges per block

typedef unsigned int u32;
typedef unsigned short u16;

__device__ __forceinline__ u16 f2bf(float f) {
    u32 u = __float_as_uint(f);
    u32 r = (u + 0x7fffu + ((u >> 16) & 1u)) >> 16;   // RNE
    return (u16)r;
}
__device__ __forceinline__ float bflo(u32 w) { return __uint_as_float(w << 16); }
__device__ __forceinline__ float bfhi(u32 w) { return __uint_as_float(w & 0xffff0000u); }

// ---------------- column stats (sum, sumsq) over rows ----------------
template<int NC>
__global__ __launch_bounds__(2*NC) void colstats_kernel(const float* __restrict__ in,
                                                        float* __restrict__ stats,
                                                        int nrows) {
    const int col  = threadIdx.x % NC;
    const int half = threadIdx.x / NC;
    float s = 0.f, ss = 0.f;
    for (int r = blockIdx.x * 2 + half; r < nrows; r += gridDim.x * 2) {
        float v = in[(size_t)r * NC + col];
        s += v; ss += v * v;
    }
    __shared__ float shs[2][NC], shq[2][NC];
    shs[half][col] = s; shq[half][col] = ss;
    __syncthreads();
    if (half == 0) {
        atomicAdd(&stats[col],      s  + shs[1][col]);
        atomicAdd(&stats[NC + col], ss + shq[1][col]);
    }
}

// stats -> per-column affine (a = w*rsqrt(var+eps), c = b - mu*a)
__global__ void finalize_bn_kernel(const float* __restrict__ stats,
                                   const float* __restrict__ w,
                                   const float* __restrict__ b,
                                   float* __restrict__ ac, int ncols, float inv_n) {
    int k = blockIdx.x * blockDim.x + threadIdx.x;
    if (k < ncols) {
        float mu  = stats[k] * inv_n;
        float var = stats[ncols + k] * inv_n - mu * mu;
        float a   = w[k] * rsqrtf(var + BN_EPS);
        ac[k]         = a;
        ac[ncols + k] = b[k] - mu * a;
    }
}

// ---------------- CSR build (by dst), partitioned 2-pass ----------------
__global__ void hist_kernel(const int* __restrict__ dst, int* __restrict__ deg, int ne) {
    int e = blockIdx.x * blockDim.x + threadIdx.x;
    if (e < ne) atomicAdd(&deg[dst[e]], 1);
}

// generic multi-block exclusive scan (phase 1: per-block scan)
__global__ __launch_bounds__(1024) void scan1_kernel(const int* __restrict__ in,
                                                     int* __restrict__ tmp,
                                                     int* __restrict__ partial, int n) {
    __shared__ int sh[1024];
    const int i = blockIdx.x * 1024 + threadIdx.x;
    const int d = (i < n) ? in[i] : 0;
    sh[threadIdx.x] = d;
    __syncthreads();
    for (int off = 1; off < 1024; off <<= 1) {
        int v = 0;
        if (threadIdx.x >= off) v = sh[threadIdx.x - off];
        __syncthreads();
        sh[threadIdx.x] += v;
        __syncthreads();
    }
    if (i < n) tmp[i] = sh[threadIdx.x] - d;
    if (threadIdx.x == 1023) partial[blockIdx.x] = sh[1023];
}

// phase 2: one wave scans the <=64 block totals
__global__ void scan2_kernel(int* __restrict__ partial, int nparts) {
    const int t = threadIdx.x;
    int d = (t < nparts) ? partial[t] : 0;
    int v = d;
    for (int off = 1; off < 64; off <<= 1) {
        int u = __shfl_up(v, off, 64);
        if (t >= off) v += u;
    }
    if (t < nparts) partial[t] = v - d;
}

// phase 3a: row_ptr emit (with tail)
__global__ __launch_bounds__(1024) void scan3_rowptr_kernel(const int* __restrict__ tmp,
                                                            const int* __restrict__ partial,
                                                            const int* __restrict__ deg,
                                                            int* __restrict__ row_ptr, int n) {
    const int i = blockIdx.x * 1024 + threadIdx.x;
    if (i < n) {
        int v = tmp[i] + partial[blockIdx.x];
        row_ptr[i] = v;
        if (i == n - 1) row_ptr[n] = v + deg[i];
    }
}

// phase 3b: generic emit
__global__ __launch_bounds__(1024) void scan3_kernel(const int* __restrict__ tmp,
                                                     const int* __restrict__ partial,
                                                     int* __restrict__ out, int n) {
    const int i = blockIdx.x * 1024 + threadIdx.x;
    if (i < n) out[i] = tmp[i] + partial[blockIdx.x];
}

// count: per (bucket, edge-block) histogram via LDS
__global__ __launch_bounds__(256) void count_kernel(const int* __restrict__ dst,
                                                    int* __restrict__ cnt /*[NBUCK2][NEB]*/) {
    __shared__ int lc[NBUCK2];
    for (int i = threadIdx.x; i < NBUCK2; i += 256) lc[i] = 0;
    __syncthreads();
    const int lo = blockIdx.x * EPB;
    const int hi = min(lo + EPB, N_EDGES);
    for (int e = lo + threadIdx.x; e < hi; e += 256)
        atomicAdd(&lc[dst[e] / NPB], 1);
    __syncthreads();
    for (int i = threadIdx.x; i < NBUCK2; i += 256)
        cnt[i * NEB + blockIdx.x] = lc[i];
}

// distribute: append (src,dst) into block-private sub-streams of bucket-grouped ebuf
__global__ __launch_bounds__(256) void distribute_kernel(const int* __restrict__ src,
                                                         const int* __restrict__ dst,
                                                         const int* __restrict__ ofs /*[NBUCK2][NEB]*/,
                                                         uint2* __restrict__ ebuf) {
    __shared__ int lofs[NBUCK2];
    for (int i = threadIdx.x; i < NBUCK2; i += 256) lofs[i] = ofs[i * NEB + blockIdx.x];
    __syncthreads();
    const int lo = blockIdx.x * EPB;
    const int hi = min(lo + EPB, N_EDGES);
    for (int e = lo + threadIdx.x; e < hi; e += 256) {
        int d = dst[e];
        int q = atomicAdd(&lofs[d / NPB], 1);
        ebuf[q] = make_uint2((u32)src[e], (u32)d);
    }
}

// bucket fill: one block per bucket; all csr writes for the bucket's range come
// from this block only (single-writer lines -> no cross-XCD ping-pong)
__global__ __launch_bounds__(256) void bucket_fill_kernel(const uint2* __restrict__ ebuf,
                                                          const int* __restrict__ ofs,
                                                          const int* __restrict__ row_ptr,
                                                          int* __restrict__ csr) {
    __shared__ int cur[NPB];
    const int p    = blockIdx.x;
    const int base = p * NPB;
    const int nn   = min(NPB, N_NODES - base);
    for (int i = threadIdx.x; i < nn; i += 256) cur[i] = row_ptr[base + i];
    __syncthreads();
    const int e0 = ofs[p * NEB];
    const int e1 = (p + 1 < NBUCK2) ? ofs[(p + 1) * NEB] : N_EDGES;
    for (int e = e0 + threadIdx.x; e < e1; e += 256) {
        uint2 v = ebuf[e];
        int pos = atomicAdd(&cur[(int)v.y - base], 1);
        csr[pos] = (int)v.x;
    }
}

// ---------------- GIN aggregation: m[n] = h[n] + sum_{s in nbr(n)} h[s] ----------------
__global__ __launch_bounds__(192) void agg_kernel(const u16* __restrict__ hb,
                                                  const int* __restrict__ row_ptr,
                                                  const int* __restrict__ csr,
                                                  float* __restrict__ m, int n) {
    const int jj   = threadIdx.x % 24;       // columns jj*4 .. jj*4+3
    const int node = blockIdx.x * 8 + threadIdx.x / 24;
    if (node >= n) return;
    const int p0 = row_ptr[node], p1 = row_ptr[node + 1];
    uint2 sv = *(const uint2*)&hb[(size_t)node * 96 + jj * 4];
    float a0 = bflo(sv.x), a1 = bfhi(sv.x), a2 = bflo(sv.y), a3 = bfhi(sv.y);
    int p = p0;
    for (; p + 8 <= p1; p += 8) {
        int s0 = csr[p],     s1 = csr[p + 1], s2 = csr[p + 2], s3 = csr[p + 3];
        int s4 = csr[p + 4], s5 = csr[p + 5], s6 = csr[p + 6], s7 = csr[p + 7];
        uint2 v0 = *(const uint2*)&hb[(size_t)s0 * 96 + jj * 4];
        uint2 v1 = *(const uint2*)&hb[(size_t)s1 * 96 + jj * 4];
        uint2 v2 = *(const uint2*)&hb[(size_t)s2 * 96 + jj * 4];
        uint2 v3 = *(const uint2*)&hb[(size_t)s3 * 96 + jj * 4];
        uint2 v4 = *(const uint2*)&hb[(size_t)s4 * 96 + jj * 4];
        uint2 v5 = *(const uint2*)&hb[(size_t)s5 * 96 + jj * 4];
        uint2 v6 = *(const uint2*)&hb[(size_t)s6 * 96 + jj * 4];
        uint2 v7 = *(const uint2*)&hb[(size_t)s7 * 96 + jj * 4];
        a0 += ((bflo(v0.x) + bflo(v1.x)) + (bflo(v2.x) + bflo(v3.x)))
            + ((bflo(v4.x) + bflo(v5.x)) + (bflo(v6.x) + bflo(v7.x)));
        a1 += ((bfhi(v0.x) + bfhi(v1.x)) + (bfhi(v2.x) + bfhi(v3.x)))
            + ((bfhi(v4.x) + bfhi(v5.x)) + (bfhi(v6.x) + bfhi(v7.x)));
        a2 += ((bflo(v0.y) + bflo(v1.y)) + (bflo(v2.y) + bflo(v3.y)))
            + ((bflo(v4.y) + bflo(v5.y)) + (bflo(v6.y) + bflo(v7.y)));
        a3 += ((bfhi(v0.y) + bfhi(v1.y)) + (bfhi(v2.y) + bfhi(v3.y)))
            + ((bfhi(v4.y) + bfhi(v5.y)) + (bfhi(v6.y) + bfhi(v7.y)));
    }
    for (; p + 4 <= p1; p += 4) {
        int s0 = csr[p], s1 = csr[p + 1], s2 = csr[p + 2], s3 = csr[p + 3];
        uint2 v0 = *(const uint2*)&hb[(size_t)s0 * 96 + jj * 4];
        uint2 v1 = *(const uint2*)&hb[(size_t)s1 * 96 + jj * 4];
        uint2 v2 = *(const uint2*)&hb[(size_t)s2 * 96 + jj * 4];
        uint2 v3 = *(const uint2*)&hb[(size_t)s3 * 96 + jj * 4];
        a0 += (bflo(v0.x) + bflo(v1.x)) + (bflo(v2.x) + bflo(v3.x));
        a1 += (bfhi(v0.x) + bfhi(v1.x)) + (bfhi(v2.x) + bfhi(v3.x));
        a2 += (bflo(v0.y) + bflo(v1.y)) + (bflo(v2.y) + bflo(v3.y));
        a3 += (bfhi(v0.y) + bfhi(v1.y)) + (bfhi(v2.y) + bfhi(v3.y));
    }
    for (; p < p1; p++) {
        int s = csr[p];
        uint2 v = *(const uint2*)&hb[(size_t)s * 96 + jj * 4];
        a0 += bflo(v.x); a1 += bfhi(v.x); a2 += bflo(v.y); a3 += bfhi(v.y);
    }
    *(float4*)&m[(size_t)node * 96 + jj * 4] = make_float4(a0, a1, a2, a3);
}

// ---------------- weight-resident tiled matmul ----------------
// POOL: instead of writing rows, atomicAdd into g[batch[row]*96+col] (last layer).
template<int KDIM, bool IN_AFF, bool IN_RELU, bool OUT_RELU, bool STATS, bool OUT_BF16, bool POOL>
__global__ __launch_bounds__(192) void mm_kernel(const float* __restrict__ in,
                                                 const float* __restrict__ W,
                                                 const float* __restrict__ bias,
                                                 const float* __restrict__ ac,
                                                 void* __restrict__ out_,
                                                 float* __restrict__ stats,
                                                 const int* __restrict__ batch, int nrows) {
    constexpr int KG = KDIM / 4;
    __shared__ float ws[KDIM][96];
    __shared__ float xs[32][KDIM];   // columns stored XOR-swizzled: [r][4*((k/4)^(r&7)) + k%4]
    const int tid = threadIdx.x;
    const int cg  = tid % 24;        // cols 4cg .. 4cg+3
    const int rg  = tid / 24;        // rows rg, rg+8, rg+16, rg+24 within chunk

    for (int i = tid; i < KDIM * 24; i += 192) {
        int k = i / 24, c4 = i % 24;
        *(float4*)&ws[k][c4 * 4] = *(const float4*)&W[(size_t)k * 96 + c4 * 4];
    }
    const float4 bj = *(const float4*)&bias[cg * 4];

    float s0=0,s1=0,s2=0,s3=0, q0=0,q1=0,q2=0,q3=0;

    const int nchunks = (nrows + 31) / 32;
    for (int chunk = blockIdx.x; chunk < nchunks; chunk += gridDim.x) {
        const int row0 = chunk * 32;
        __syncthreads();
        for (int i = tid; i < 32 * KG; i += 192) {
            int r = i / KG, g = i % KG;
            int gr = row0 + r;
            float4 v = make_float4(0.f, 0.f, 0.f, 0.f);
            if (gr < nrows) v = *(const float4*)&in[(size_t)gr * KDIM + g * 4];
            if constexpr (IN_AFF) {
                float4 a = *(const float4*)&ac[g * 4];
                float4 c = *(const float4*)&ac[KDIM + g * 4];
                v.x = v.x * a.x + c.x; v.y = v.y * a.y + c.y;
                v.z = v.z * a.z + c.z; v.w = v.w * a.w + c.w;
            }
            if constexpr (IN_RELU) {
                v.x = fmaxf(v.x, 0.f); v.y = fmaxf(v.y, 0.f);
                v.z = fmaxf(v.z, 0.f); v.w = fmaxf(v.w, 0.f);
            }
            *(float4*)&xs[r][4 * (g ^ (r & 7))] = v;
        }
        __syncthreads();

        float acc[4][4];
        #pragma unroll
        for (int m = 0; m < 4; m++) {
            acc[m][0] = bj.x; acc[m][1] = bj.y; acc[m][2] = bj.z; acc[m][3] = bj.w;
        }

        #pragma unroll 4
        for (int g = 0; g < KG; g++) {
            const int xi = 4 * (g ^ rg);
            float4 xv0 = *(const float4*)&xs[rg     ][xi];
            float4 xv1 = *(const float4*)&xs[rg +  8][xi];
            float4 xv2 = *(const float4*)&xs[rg + 16][xi];
            float4 xv3 = *(const float4*)&xs[rg + 24][xi];
            #pragma unroll
            for (int i = 0; i < 4; i++) {
                float4 wv = *(const float4*)&ws[g * 4 + i][cg * 4];
                float x0 = (i==0)?xv0.x:(i==1)?xv0.y:(i==2)?xv0.z:xv0.w;
                float x1 = (i==0)?xv1.x:(i==1)?xv1.y:(i==2)?xv1.z:xv1.w;
                float x2 = (i==0)?xv2.x:(i==1)?xv2.y:(i==2)?xv2.z:xv2.w;
                float x3 = (i==0)?xv3.x:(i==1)?xv3.y:(i==2)?xv3.z:xv3.w;
                acc[0][0] = fmaf(x0, wv.x, acc[0][0]); acc[0][1] = fmaf(x0, wv.y, acc[0][1]);
                acc[0][2] = fmaf(x0, wv.z, acc[0][2]); acc[0][3] = fmaf(x0, wv.w, acc[0][3]);
                acc[1][0] = fmaf(x1, wv.x, acc[1][0]); acc[1][1] = fmaf(x1, wv.y, acc[1][1]);
                acc[1][2] = fmaf(x1, wv.z, acc[1][2]); acc[1][3] = fmaf(x1, wv.w, acc[1][3]);
                acc[2][0] = fmaf(x2, wv.x, acc[2][0]); acc[2][1] = fmaf(x2, wv.y, acc[2][1]);
                acc[2][2] = fmaf(x2, wv.z, acc[2][2]); acc[2][3] = fmaf(x2, wv.w, acc[2][3]);
                acc[3][0] = fmaf(x3, wv.x, acc[3][0]); acc[3][1] = fmaf(x3, wv.y, acc[3][1]);
                acc[3][2] = fmaf(x3, wv.z, acc[3][2]); acc[3][3] = fmaf(x3, wv.w, acc[3][3]);
            }
        }

        if constexpr (POOL) {
            float* gbuf = (float*)out_;
            const int r0 = row0 + rg;
            int b0 = (r0      < nrows) ? batch[r0]      : -1;
            int b3 = (r0 + 24 < nrows) ? batch[r0 + 24] : -2;
            #pragma unroll
            for (int m = 0; m < 4; m++) {
                if constexpr (OUT_RELU) {
                    acc[m][0] = fmaxf(acc[m][0], 0.f); acc[m][1] = fmaxf(acc[m][1], 0.f);
                    acc[m][2] = fmaxf(acc[m][2], 0.f); acc[m][3] = fmaxf(acc[m][3], 0.f);
                }
            }
            if (b0 == b3) {
                float4 t = make_float4(acc[0][0]+acc[1][0]+acc[2][0]+acc[3][0],
                                       acc[0][1]+acc[1][1]+acc[2][1]+acc[3][1],
                                       acc[0][2]+acc[1][2]+acc[2][2]+acc[3][2],
                                       acc[0][3]+acc[1][3]+acc[2][3]+acc[3][3]);
                float* gp = &gbuf[(size_t)b0 * 96 + cg * 4];
                atomicAdd(gp,     t.x); atomicAdd(gp + 1, t.y);
                atomicAdd(gp + 2, t.z); atomicAdd(gp + 3, t.w);
            } else {
                #pragma unroll
                for (int m = 0; m < 4; m++) {
                    const int gr = r0 + 8 * m;
                    if (gr < nrows) {
                        float* gp = &gbuf[(size_t)batch[gr] * 96 + cg * 4];
                        atomicAdd(gp,     acc[m][0]); atomicAdd(gp + 1, acc[m][1]);
                        atomicAdd(gp + 2, acc[m][2]); atomicAdd(gp + 3, acc[m][3]);
                    }
                }
            }
        } else {
            #pragma unroll
            for (int m = 0; m < 4; m++) {
                const int gr = row0 + rg + 8 * m;
                if (gr < nrows) {
                    float4 o = make_float4(acc[m][0], acc[m][1], acc[m][2], acc[m][3]);
                    if constexpr (OUT_RELU) {
                        o.x = fmaxf(o.x, 0.f); o.y = fmaxf(o.y, 0.f);
                        o.z = fmaxf(o.z, 0.f); o.w = fmaxf(o.w, 0.f);
                    }
                    if constexpr (OUT_BF16) {
                        u16* ob = (u16*)out_;
                        ushort4 t;
                        t.x = f2bf(o.x); t.y = f2bf(o.y); t.z = f2bf(o.z); t.w = f2bf(o.w);
                        *(ushort4*)&ob[(size_t)gr * 96 + cg * 4] = t;
                    } else {
                        float* of = (float*)out_;
                        *(float4*)&of[(size_t)gr * 96 + cg * 4] = o;
                    }
                    if constexpr (STATS) {
                        s0 += o.x; q0 += o.x * o.x;
                        s1 += o.y; q1 += o.y * o.y;
                        s2 += o.z; q2 += o.z * o.z;
                        s3 += o.w; q3 += o.w * o.w;
                    }
                }
            }
        }
    }

    if constexpr (STATS) {
        __syncthreads();
        float* rs = &xs[0][0];
        float* rq = rs + 8 * 96;
        rs[rg * 96 + cg * 4 + 0] = s0; rs[rg * 96 + cg * 4 + 1] = s1;
        rs[rg * 96 + cg * 4 + 2] = s2; rs[rg * 96 + cg * 4 + 3] = s3;
        rq[rg * 96 + cg * 4 + 0] = q0; rq[rg * 96 + cg * 4 + 1] = q1;
        rq[rg * 96 + cg * 4 + 2] = q2; rq[rg * 96 + cg * 4 + 3] = q3;
        __syncthreads();
        if (tid < 96) {
            float a = 0.f, b = 0.f;
            #pragma unroll
            for (int r = 0; r < 8; r++) { a += rs[r * 96 + tid]; b += rq[r * 96 + tid]; }
            atomicAdd(&stats[tid],      a);
            atomicAdd(&stats[96 + tid], b);
        }
    }
}

// ---------------- head: logits = BN(g1) @ Wc + bc, then log_softmax ----------------
__global__ void head_kernel(const float* __restrict__ g1, const float* __restrict__ ac,
                            const float* __restrict__ Wc, const float* __restrict__ bc,
                            float* __restrict__ out, int ngraphs) {
    int gi = blockIdx.x * blockDim.x + threadIdx.x;
    if (gi >= ngraphs) return;
    float v[NCLS];
    #pragma unroll
    for (int c = 0; c < NCLS; c++) v[c] = bc[c];
    for (int k = 0; k < HDIM; k++) {
        float x = g1[(size_t)gi * HDIM + k] * ac[k] + ac[HDIM + k];
        #pragma unroll
        for (int c = 0; c < NCLS; c++) v[c] = fmaf(x, Wc[k * NCLS + c], v[c]);
    }
    float mx = v[0];
    #pragma unroll
    for (int c = 1; c < NCLS; c++) mx = fmaxf(mx, v[c]);
    float sum = 0.f;
    #pragma unroll
    for (int c = 0; c < NCLS; c++) sum += expf(v[c] - mx);
    float lse = mx + logf(sum);
    #pragma unroll
    for (int c = 0; c < NCLS; c++) out[(size_t)gi * NCLS + c] = v[c] - lse;
}

extern "C" void kernel_launch(void* const* d_in, const int* in_sizes, int n_in,
                              void* d_out, int out_size, void* d_ws, size_t ws_size,
                              hipStream_t stream) {
    const float* x         = (const float*)d_in[0];
    const int*   ei        = (const int*)  d_in[1];
    const int*   batch     = (const int*)  d_in[2];
    const float* bn_feat_w = (const float*)d_in[3];
    const float* bn_feat_b = (const float*)d_in[4];
    const float* Wf        = (const float*)d_in[5];
    const float* bfv       = (const float*)d_in[6];
    const float* bn_fc_w   = (const float*)d_in[7];
    const float* bn_fc_b   = (const float*)d_in[8];
    const float* Wl        = (const float*)d_in[9];
    const float* bl        = (const float*)d_in[10];
    const float* bn_hid_w  = (const float*)d_in[11];
    const float* bn_hid_b  = (const float*)d_in[12];
    const float* Wc        = (const float*)d_in[13];
    const float* bc        = (const float*)d_in[14];
    float* out = (float*)d_out;

    char* p = (char*)d_ws;
    auto alloc = [&](size_t bytes) { char* q = p; p += (bytes + 255) & ~(size_t)255; return q; };
    u16*   hb     = (u16*)  alloc((size_t)N_NODES * HDIM * 2);
    float* buf    = (float*)alloc((size_t)N_NODES * HDIM * 4);
    float* g      = (float*)alloc((size_t)N_GRAPHS * HDIM * 4);
    float* g1     = (float*)alloc((size_t)N_GRAPHS * HDIM * 4);
    float* statsX = (float*)alloc(2 * F_IN * 4);
    float* acX    = (float*)alloc(2 * F_IN * 4);
    float* statsT = (float*)alloc(2 * HDIM * 4);
    float* acT    = (float*)alloc(2 * HDIM * 4);
    float* statsG = (float*)alloc(2 * HDIM * 4);
    float* acG    = (float*)alloc(2 * HDIM * 4);
    float* statsG1= (float*)alloc(2 * HDIM * 4);
    float* acHid  = (float*)alloc(2 * HDIM * 4);
    int* deg      = (int*)alloc((size_t)N_NODES * 4);
    int* row_ptr  = (int*)alloc((size_t)(N_NODES + 1) * 4);
    int* csr      = (int*)alloc((size_t)N_EDGES * 4);
    int* stmp     = (int*)alloc((size_t)N_NODES * 4);
    int* spart    = (int*)alloc(64 * 4);
    int* cnt      = (int*)alloc((size_t)NBUCK2 * NEB * 4);
    int* ofs      = (int*)alloc((size_t)NBUCK2 * NEB * 4);
    int* stmp2    = (int*)alloc((size_t)NBUCK2 * NEB * 4);
    int* spart2   = (int*)alloc(64 * 4);
    uint2* ebuf   = (uint2*)alloc((size_t)N_EDGES * 8);

    const int* srcp = ei;
    const int* dstp = ei + N_EDGES;

    const int nchunks = (N_NODES + 31) / 32;
    const int grid128 = (nchunks < 512) ? nchunks : 512;
    const int grid96  = (nchunks < 750) ? nchunks : 750;
    const int gridG   = (N_GRAPHS + 31) / 32;
    const int nscan   = (N_NODES + 1023) / 1024;
    const int ncb     = NBUCK2 * NEB;
    const int nscan2  = (ncb + 1023) / 1024;

    // BN(x) stats, then h = relu(BN(x) @ Wf + bf)  (h stored bf16)
    hipMemsetAsync(statsX, 0, 2 * F_IN * 4, stream);
    colstats_kernel<F_IN><<<256, 2 * F_IN, 0, stream>>>(x, statsX, N_NODES);
    finalize_bn_kernel<<<1, F_IN, 0, stream>>>(statsX, bn_feat_w, bn_feat_b, acX, F_IN, 1.0f / N_NODES);
    mm_kernel<F_IN, true, false, true, false, true, false><<<grid128, 192, 0, stream>>>(x, Wf, bfv, acX, hb, nullptr, nullptr, N_NODES);

    // CSR build (partitioned 2-pass; reused by all 3 layers)
    hipMemsetAsync(deg, 0, (size_t)N_NODES * 4, stream);
    hist_kernel<<<(N_EDGES + 255) / 256, 256, 0, stream>>>(dstp, deg, N_EDGES);
    scan1_kernel<<<nscan, 1024, 0, stream>>>(deg, stmp, spart, N_NODES);
    scan2_kernel<<<1, 64, 0, stream>>>(spart, nscan);
    scan3_rowptr_kernel<<<nscan, 1024, 0, stream>>>(stmp, spart, deg, row_ptr, N_NODES);
    count_kernel<<<NEB, 256, 0, stream>>>(dstp, cnt);
    scan1_kernel<<<nscan2, 1024, 0, stream>>>(cnt, stmp2, spart2, ncb);
    scan2_kernel<<<1, 64, 0, stream>>>(spart2, nscan2);
    scan3_kernel<<<nscan2, 1024, 0, stream>>>(stmp2, spart2, ofs, ncb);
    distribute_kernel<<<NEB, 256, 0, stream>>>(srcp, dstp, ofs, ebuf);
    bucket_fill_kernel<<<NBUCK2, 256, 0, stream>>>(ebuf, ofs, row_ptr, csr);

    // zero pooled buffer (written by last layer's fused mm2)
    hipMemsetAsync(g, 0, (size_t)N_GRAPHS * HDIM * 4, stream);

    for (int l = 0; l < 3; l++) {
        const float* W1 = (const float*)d_in[15 + 6 * l];
        const float* b1 = (const float*)d_in[16 + 6 * l];
        const float* bw = (const float*)d_in[17 + 6 * l];
        const float* bb = (const float*)d_in[18 + 6 * l];
        const float* W2 = (const float*)d_in[19 + 6 * l];
        const float* b2 = (const float*)d_in[20 + 6 * l];
        // m = h + sum_nbr(h)  (bf16 gathers -> f32 buf)
        agg_kernel<<<(N_NODES + 7) / 8, 192, 0, stream>>>(hb, row_ptr, csr, buf, N_NODES);
        // t = m @ W1 + b1 (in-place on buf), fused stats(t)
        hipMemsetAsync(statsT, 0, 2 * HDIM * 4, stream);
        mm_kernel<HDIM, false, false, false, true, false, false><<<grid96, 192, 0, stream>>>(buf, W1, b1, nullptr, buf, statsT, nullptr, N_NODES);
        finalize_bn_kernel<<<1, HDIM, 0, stream>>>(statsT, bw, bb, acT, HDIM, 1.0f / N_NODES);
        // h = relu( relu(BN(t)) @ W2 + b2 ): layers 0,1 -> bf16 h; layer 2 -> fused pool
        if (l < 2) {
            mm_kernel<HDIM, true, true, true, false, true, false><<<grid96, 192, 0, stream>>>(buf, W2, b2, acT, hb, nullptr, nullptr, N_NODES);
        } else {
            mm_kernel<HDIM, true, true, true, false, false, true><<<grid96, 192, 0, stream>>>(buf, W2, b2, acT, g, nullptr, batch, N_NODES);
        }
    }

    // g1 = relu(BN_fc(g) @ Wl + bl), fused stats(g1)
    hipMemsetAsync(statsG, 0, 2 * HDIM * 4, stream);
    colstats_kernel<HDIM><<<64, 2 * HDIM, 0, stream>>>(g, statsG, N_GRAPHS);
    finalize_bn_kernel<<<1, HDIM, 0, stream>>>(statsG, bn_fc_w, bn_fc_b, acG, HDIM, 1.0f / N_GRAPHS);
    hipMemsetAsync(statsG1, 0, 2 * HDIM * 4, stream);
    mm_kernel<HDIM, true, false, true, true, false, false><<<gridG, 192, 0, stream>>>(g, Wl, bl, acG, g1, statsG1, nullptr, N_GRAPHS);
    finalize_bn_kernel<<<1, HDIM, 0, stream>>>(statsG1, bn_hid_w, bn_hid_b, acHid, HDIM, 1.0f / N_GRAPHS);

    // logits + log_softmax
    head_kernel<<<2, 256, 0, stream>>>(g1, acHid, Wc, bc, out, N_GRAPHS);
}

// Round 6
// 405.580 us; speedup vs baseline: 1.4180x; 1.2653x over previous
//
#include <hip/hip_runtime.h>

#define N_NODES 50000
#define N_EDGES 800000
#define N_GRAPHS 512
#define F_IN 128
#define HDIM 96
#define NCLS 10
#define BN_EPS 1e-5f

// partitioned CSR fill geometry
#define NPB 128                            // nodes per bucket
#define NBUCK2 ((N_NODES + NPB - 1) / NPB) // 391 buckets
#define NEB 128                            // edge-partition blocks
#define EPB ((N_EDGES + NEB - 1) / NEB)    // 6250 edges per block

typedef unsigned int u32;
typedef unsigned short u16;
typedef __attribute__((ext_vector_type(8))) short bf16x8;
typedef __attribute__((ext_vector_type(4))) float f32x4;

__device__ __forceinline__ u16 f2bf(float f) {
    u32 u = __float_as_uint(f);
    u32 r = (u + 0x7fffu + ((u >> 16) & 1u)) >> 16;   // RNE
    return (u16)r;
}
__device__ __forceinline__ float bflo(u32 w) { return __uint_as_float(w << 16); }
__device__ __forceinline__ float bfhi(u32 w) { return __uint_as_float(w & 0xffff0000u); }

// ---------------- column stats (sum, sumsq) over rows ----------------
template<int NC>
__global__ __launch_bounds__(2*NC) void colstats_kernel(const float* __restrict__ in,
                                                        float* __restrict__ stats,
                                                        int nrows) {
    const int col  = threadIdx.x % NC;
    const int half = threadIdx.x / NC;
    float s = 0.f, ss = 0.f;
    for (int r = blockIdx.x * 2 + half; r < nrows; r += gridDim.x * 2) {
        float v = in[(size_t)r * NC + col];
        s += v; ss += v * v;
    }
    __shared__ float shs[2][NC], shq[2][NC];
    shs[half][col] = s; shq[half][col] = ss;
    __syncthreads();
    if (half == 0) {
        atomicAdd(&stats[col],      s  + shs[1][col]);
        atomicAdd(&stats[NC + col], ss + shq[1][col]);
    }
}

__global__ void finalize_bn_kernel(const float* __restrict__ stats,
                                   const float* __restrict__ w,
                                   const float* __restrict__ b,
                                   float* __restrict__ ac, int ncols, float inv_n) {
    int k = blockIdx.x * blockDim.x + threadIdx.x;
    if (k < ncols) {
        float mu  = stats[k] * inv_n;
        float var = stats[ncols + k] * inv_n - mu * mu;
        float a   = w[k] * rsqrtf(var + BN_EPS);
        ac[k]         = a;
        ac[ncols + k] = b[k] - mu * a;
    }
}

// ---------------- weight prep: Wt[n][k] = bf16( (FOLD? a_k:1) * W[k][n] ), bias fold ----------------
template<int KDIM, bool FOLD>
__global__ __launch_bounds__(256) void wprep_kernel(const float* __restrict__ W,
                                                    const float* __restrict__ bias,
                                                    const float* __restrict__ ac,
                                                    u16* __restrict__ wtb,
                                                    float* __restrict__ bmod) {
    int i = blockIdx.x * 256 + threadIdx.x;
    if (i < KDIM * 96) {
        int k = i / 96, n = i % 96;
        float v = W[i];
        if constexpr (FOLD) v *= ac[k];
        wtb[n * KDIM + k] = f2bf(v);
    }
    if (blockIdx.x == 0 && threadIdx.x < 96) {
        float b = bias[threadIdx.x];
        if constexpr (FOLD) {
            for (int k = 0; k < KDIM; k++) b += ac[KDIM + k] * W[k * 96 + threadIdx.x];
        }
        bmod[threadIdx.x] = b;
    }
}

// ---------------- CSR build (by dst), partitioned 2-pass ----------------
__global__ void hist_kernel(const int* __restrict__ dst, int* __restrict__ deg, int ne) {
    int e = blockIdx.x * blockDim.x + threadIdx.x;
    if (e < ne) atomicAdd(&deg[dst[e]], 1);
}

__global__ __launch_bounds__(1024) void scan1_kernel(const int* __restrict__ in,
                                                     int* __restrict__ tmp,
                                                     int* __restrict__ partial, int n) {
    __shared__ int sh[1024];
    const int i = blockIdx.x * 1024 + threadIdx.x;
    const int d = (i < n) ? in[i] : 0;
    sh[threadIdx.x] = d;
    __syncthreads();
    for (int off = 1; off < 1024; off <<= 1) {
        int v = 0;
        if (threadIdx.x >= off) v = sh[threadIdx.x - off];
        __syncthreads();
        sh[threadIdx.x] += v;
        __syncthreads();
    }
    if (i < n) tmp[i] = sh[threadIdx.x] - d;
    if (threadIdx.x == 1023) partial[blockIdx.x] = sh[1023];
}

__global__ void scan2_kernel(int* __restrict__ partial, int nparts) {
    const int t = threadIdx.x;
    int d = (t < nparts) ? partial[t] : 0;
    int v = d;
    for (int off = 1; off < 64; off <<= 1) {
        int u = __shfl_up(v, off, 64);
        if (t >= off) v += u;
    }
    if (t < nparts) partial[t] = v - d;
}

__global__ __launch_bounds__(1024) void scan3_rowptr_kernel(const int* __restrict__ tmp,
                                                            const int* __restrict__ partial,
                                                            const int* __restrict__ deg,
                                                            int* __restrict__ row_ptr, int n) {
    const int i = blockIdx.x * 1024 + threadIdx.x;
    if (i < n) {
        int v = tmp[i] + partial[blockIdx.x];
        row_ptr[i] = v;
        if (i == n - 1) row_ptr[n] = v + deg[i];
    }
}

__global__ __launch_bounds__(1024) void scan3_kernel(const int* __restrict__ tmp,
                                                     const int* __restrict__ partial,
                                                     int* __restrict__ out, int n) {
    const int i = blockIdx.x * 1024 + threadIdx.x;
    if (i < n) out[i] = tmp[i] + partial[blockIdx.x];
}

__global__ __launch_bounds__(256) void count_kernel(const int* __restrict__ dst,
                                                    int* __restrict__ cnt /*[NBUCK2][NEB]*/) {
    __shared__ int lc[NBUCK2];
    for (int i = threadIdx.x; i < NBUCK2; i += 256) lc[i] = 0;
    __syncthreads();
    const int lo = blockIdx.x * EPB;
    const int hi = min(lo + EPB, N_EDGES);
    for (int e = lo + threadIdx.x; e < hi; e += 256)
        atomicAdd(&lc[dst[e] / NPB], 1);
    __syncthreads();
    for (int i = threadIdx.x; i < NBUCK2; i += 256)
        cnt[i * NEB + blockIdx.x] = lc[i];
}

__global__ __launch_bounds__(256) void distribute_kernel(const int* __restrict__ src,
                                                         const int* __restrict__ dst,
                                                         const int* __restrict__ ofs,
                                                         uint2* __restrict__ ebuf) {
    __shared__ int lofs[NBUCK2];
    for (int i = threadIdx.x; i < NBUCK2; i += 256) lofs[i] = ofs[i * NEB + blockIdx.x];
    __syncthreads();
    const int lo = blockIdx.x * EPB;
    const int hi = min(lo + EPB, N_EDGES);
    for (int e = lo + threadIdx.x; e < hi; e += 256) {
        int d = dst[e];
        int q = atomicAdd(&lofs[d / NPB], 1);
        ebuf[q] = make_uint2((u32)src[e], (u32)d);
    }
}

__global__ __launch_bounds__(256) void bucket_fill_kernel(const uint2* __restrict__ ebuf,
                                                          const int* __restrict__ ofs,
                                                          const int* __restrict__ row_ptr,
                                                          int* __restrict__ csr) {
    __shared__ int cur[NPB];
    const int p    = blockIdx.x;
    const int base = p * NPB;
    const int nn   = min(NPB, N_NODES - base);
    for (int i = threadIdx.x; i < nn; i += 256) cur[i] = row_ptr[base + i];
    __syncthreads();
    const int e0 = ofs[p * NEB];
    const int e1 = (p + 1 < NBUCK2) ? ofs[(p + 1) * NEB] : N_EDGES;
    for (int e = e0 + threadIdx.x; e < e1; e += 256) {
        uint2 v = ebuf[e];
        int pos = atomicAdd(&cur[(int)v.y - base], 1);
        csr[pos] = (int)v.x;
    }
}

// ---------------- GIN aggregation: m[n] = h[n] + sum_nbr h[s]  (bf16 in/out) ----------------
__global__ __launch_bounds__(192) void agg_kernel(const u16* __restrict__ hb,
                                                  const int* __restrict__ row_ptr,
                                                  const int* __restrict__ csr,
                                                  u16* __restrict__ mb, int n) {
    const int jj   = threadIdx.x % 24;
    const int node = blockIdx.x * 8 + threadIdx.x / 24;
    if (node >= n) return;
    const int p0 = row_ptr[node], p1 = row_ptr[node + 1];
    uint2 sv = *(const uint2*)&hb[(size_t)node * 96 + jj * 4];
    float a0 = bflo(sv.x), a1 = bfhi(sv.x), a2 = bflo(sv.y), a3 = bfhi(sv.y);
    int p = p0;
    for (; p + 8 <= p1; p += 8) {
        int s0 = csr[p],     s1 = csr[p + 1], s2 = csr[p + 2], s3 = csr[p + 3];
        int s4 = csr[p + 4], s5 = csr[p + 5], s6 = csr[p + 6], s7 = csr[p + 7];
        uint2 v0 = *(const uint2*)&hb[(size_t)s0 * 96 + jj * 4];
        uint2 v1 = *(const uint2*)&hb[(size_t)s1 * 96 + jj * 4];
        uint2 v2 = *(const uint2*)&hb[(size_t)s2 * 96 + jj * 4];
        uint2 v3 = *(const uint2*)&hb[(size_t)s3 * 96 + jj * 4];
        uint2 v4 = *(const uint2*)&hb[(size_t)s4 * 96 + jj * 4];
        uint2 v5 = *(const uint2*)&hb[(size_t)s5 * 96 + jj * 4];
        uint2 v6 = *(const uint2*)&hb[(size_t)s6 * 96 + jj * 4];
        uint2 v7 = *(const uint2*)&hb[(size_t)s7 * 96 + jj * 4];
        a0 += ((bflo(v0.x) + bflo(v1.x)) + (bflo(v2.x) + bflo(v3.x)))
            + ((bflo(v4.x) + bflo(v5.x)) + (bflo(v6.x) + bflo(v7.x)));
        a1 += ((bfhi(v0.x) + bfhi(v1.x)) + (bfhi(v2.x) + bfhi(v3.x)))
            + ((bfhi(v4.x) + bfhi(v5.x)) + (bfhi(v6.x) + bfhi(v7.x)));
        a2 += ((bflo(v0.y) + bflo(v1.y)) + (bflo(v2.y) + bflo(v3.y)))
            + ((bflo(v4.y) + bflo(v5.y)) + (bflo(v6.y) + bflo(v7.y)));
        a3 += ((bfhi(v0.y) + bfhi(v1.y)) + (bfhi(v2.y) + bfhi(v3.y)))
            + ((bfhi(v4.y) + bfhi(v5.y)) + (bfhi(v6.y) + bfhi(v7.y)));
    }
    for (; p < p1; p++) {
        int s = csr[p];
        uint2 v = *(const uint2*)&hb[(size_t)s * 96 + jj * 4];
        a0 += bflo(v.x); a1 += bfhi(v.x); a2 += bflo(v.y); a3 += bfhi(v.y);
    }
    ushort4 o; o.x = f2bf(a0); o.y = f2bf(a1); o.z = f2bf(a2); o.w = f2bf(a3);
    *(ushort4*)&mb[(size_t)node * 96 + jj * 4] = o;
}

// ---------------- MFMA matmul: out[nrows][96] = f(in[nrows][KDIM]) @ W + bias ----------------
// 256 threads / 4 waves, 64x96 tile per block, mfma_f32_16x16x32_bf16.
// A frag: row=lane&15, k=(lane>>4)*8+i ; B frag: col=lane&15, same k ; D: col=lane&15, row=(lane>>4)*4+reg.
template<int KDIM, bool IN_F32, bool IN_AFF_RELU, bool OUT_RELU, bool STATS, bool OUT_BF16, bool POOL>
__global__ __launch_bounds__(256) void mmx_kernel(const void* __restrict__ in_,
                                                  const u16* __restrict__ wt,   // [96][KDIM] bf16
                                                  const float* __restrict__ bias,
                                                  const float* __restrict__ ac,
                                                  void* __restrict__ out_,
                                                  float* __restrict__ stats,
                                                  const int* __restrict__ batch,
                                                  int nrows) {
    constexpr int KP = KDIM + 8;    // padded u16 stride (16B-aligned rows, bank-spread)
    constexpr int KB = KDIM / 32;
    __shared__ u16 wlds[96 * KP];
    __shared__ u16 alds[64 * KP];
    __shared__ float sred[2][4][96];
    const int tid = threadIdx.x;

    for (int i = tid; i < 96 * (KDIM / 8); i += 256) {
        int nn = i / (KDIM / 8), c8 = i % (KDIM / 8);
        *(uint4*)&wlds[nn * KP + c8 * 8] = *(const uint4*)&wt[nn * KDIM + c8 * 8];
    }

    const int w    = tid >> 6;
    const int lane = tid & 63;
    const int r16  = lane & 15;
    const int kg   = lane >> 4;
    const int m0   = w * 16;
    float bn[6];
    #pragma unroll
    for (int nt = 0; nt < 6; nt++) bn[nt] = bias[nt * 16 + r16];
    float scol[6] = {0,0,0,0,0,0}, qcol[6] = {0,0,0,0,0,0};

    const int nchunks = (nrows + 63) / 64;
    for (int chunk = blockIdx.x; chunk < nchunks; chunk += gridDim.x) {
        const int row0 = chunk * 64;
        __syncthreads();                 // covers wlds staging + prev-chunk alds reads
        if constexpr (IN_F32) {
            const float* inf = (const float*)in_;
            for (int i = tid; i < 64 * (KDIM / 4); i += 256) {
                int r = i / (KDIM / 4), c4 = i % (KDIM / 4);
                int gr = row0 + r;
                float4 v = (gr < nrows) ? *(const float4*)&inf[(size_t)gr * KDIM + c4 * 4]
                                        : make_float4(0.f, 0.f, 0.f, 0.f);
                ushort4 o; o.x = f2bf(v.x); o.y = f2bf(v.y); o.z = f2bf(v.z); o.w = f2bf(v.w);
                *(ushort4*)&alds[r * KP + c4 * 4] = o;
            }
        } else {
            const u16* inb = (const u16*)in_;
            for (int i = tid; i < 64 * (KDIM / 8); i += 256) {
                int r = i / (KDIM / 8), c8 = i % (KDIM / 8);
                int gr = row0 + r;
                uint4 v = (gr < nrows) ? *(const uint4*)&inb[(size_t)gr * KDIM + c8 * 8]
                                       : make_uint4(0u, 0u, 0u, 0u);
                if constexpr (IN_AFF_RELU) {
                    u32 words[4] = {v.x, v.y, v.z, v.w};
                    #pragma unroll
                    for (int t2 = 0; t2 < 4; t2++) {
                        int k0 = c8 * 8 + t2 * 2;
                        float lo = fmaxf(bflo(words[t2]) * ac[k0]     + ac[KDIM + k0],     0.f);
                        float hi = fmaxf(bfhi(words[t2]) * ac[k0 + 1] + ac[KDIM + k0 + 1], 0.f);
                        words[t2] = (u32)f2bf(lo) | ((u32)f2bf(hi) << 16);
                    }
                    v.x = words[0]; v.y = words[1]; v.z = words[2]; v.w = words[3];
                }
                *(uint4*)&alds[r * KP + c8 * 8] = v;
            }
        }
        __syncthreads();

        bf16x8 af[KB];
        #pragma unroll
        for (int kb = 0; kb < KB; kb++)
            af[kb] = *(const bf16x8*)&alds[(m0 + r16) * KP + kb * 32 + kg * 8];

        f32x4 acc[6];
        #pragma unroll
        for (int nt = 0; nt < 6; nt++) acc[nt] = (f32x4){bn[nt], bn[nt], bn[nt], bn[nt]};
        #pragma unroll
        for (int kb = 0; kb < KB; kb++) {
            #pragma unroll
            for (int nt = 0; nt < 6; nt++) {
                bf16x8 bfr = *(const bf16x8*)&wlds[(nt * 16 + r16) * KP + kb * 32 + kg * 8];
                acc[nt] = __builtin_amdgcn_mfma_f32_16x16x32_bf16(af[kb], bfr, acc[nt], 0, 0, 0);
            }
        }

        const int gr0  = row0 + m0 + kg * 4;
        const bool full = (gr0 + 3 < nrows);
        if constexpr (POOL) {
            float* gbuf = (float*)out_;
            int bl = -1, bh = -2;
            if (full) { bl = batch[gr0]; bh = batch[gr0 + 3]; }
            #pragma unroll
            for (int nt = 0; nt < 6; nt++) {
                float v0 = acc[nt][0], v1 = acc[nt][1], v2 = acc[nt][2], v3 = acc[nt][3];
                if constexpr (OUT_RELU) {
                    v0 = fmaxf(v0, 0.f); v1 = fmaxf(v1, 0.f);
                    v2 = fmaxf(v2, 0.f); v3 = fmaxf(v3, 0.f);
                }
                const int n = nt * 16 + r16;
                if (full) {
                    if (bl == bh) {
                        atomicAdd(&gbuf[(size_t)bl * 96 + n], (v0 + v1) + (v2 + v3));
                    } else {
                        atomicAdd(&gbuf[(size_t)batch[gr0]     * 96 + n], v0);
                        atomicAdd(&gbuf[(size_t)batch[gr0 + 1] * 96 + n], v1);
                        atomicAdd(&gbuf[(size_t)batch[gr0 + 2] * 96 + n], v2);
                        atomicAdd(&gbuf[(size_t)batch[gr0 + 3] * 96 + n], v3);
                    }
                } else {
                    if (gr0     < nrows) atomicAdd(&gbuf[(size_t)batch[gr0]     * 96 + n], v0);
                    if (gr0 + 1 < nrows) atomicAdd(&gbuf[(size_t)batch[gr0 + 1] * 96 + n], v1);
                    if (gr0 + 2 < nrows) atomicAdd(&gbuf[(size_t)batch[gr0 + 2] * 96 + n], v2);
                }
            }
        } else {
            #pragma unroll
            for (int nt = 0; nt < 6; nt++) {
                float v[4] = {acc[nt][0], acc[nt][1], acc[nt][2], acc[nt][3]};
                if constexpr (OUT_RELU) {
                    #pragma unroll
                    for (int rr = 0; rr < 4; rr++) v[rr] = fmaxf(v[rr], 0.f);
                }
                const int n = nt * 16 + r16;
                #pragma unroll
                for (int rr = 0; rr < 4; rr++) {
                    const int gr = gr0 + rr;
                    if (full || gr < nrows) {
                        if constexpr (OUT_BF16) ((u16*)out_)[(size_t)gr * 96 + n] = f2bf(v[rr]);
                        else                    ((float*)out_)[(size_t)gr * 96 + n] = v[rr];
                        if constexpr (STATS) { scol[nt] += v[rr]; qcol[nt] += v[rr] * v[rr]; }
                    }
                }
            }
        }
    }

    if constexpr (STATS) {
        #pragma unroll
        for (int nt = 0; nt < 6; nt++) {
            scol[nt] += __shfl_xor(scol[nt], 16);
            scol[nt] += __shfl_xor(scol[nt], 32);
            qcol[nt] += __shfl_xor(qcol[nt], 16);
            qcol[nt] += __shfl_xor(qcol[nt], 32);
        }
        __syncthreads();
        if (kg == 0) {
            #pragma unroll
            for (int nt = 0; nt < 6; nt++) {
                sred[0][w][nt * 16 + r16] = scol[nt];
                sred[1][w][nt * 16 + r16] = qcol[nt];
            }
        }
        __syncthreads();
        if (tid < 96) {
            float a = sred[0][0][tid] + sred[0][1][tid] + sred[0][2][tid] + sred[0][3][tid];
            float b = sred[1][0][tid] + sred[1][1][tid] + sred[1][2][tid] + sred[1][3][tid];
            atomicAdd(&stats[tid],      a);
            atomicAdd(&stats[96 + tid], b);
        }
    }
}

// ---------------- f32 small matmul (G-sized tails) ----------------
template<int KDIM, bool IN_AFF, bool IN_RELU, bool OUT_RELU, bool STATS>
__global__ __launch_bounds__(192) void mm_kernel(const float* __restrict__ in,
                                                 const float* __restrict__ W,
                                                 const float* __restrict__ bias,
                                                 const float* __restrict__ ac,
                                                 float* __restrict__ out,
                                                 float* __restrict__ stats, int nrows) {
    constexpr int KG = KDIM / 4;
    __shared__ float ws[KDIM][96];
    __shared__ float xs[32][KDIM];
    const int tid = threadIdx.x;
    const int cg  = tid % 24;
    const int rg  = tid / 24;
    for (int i = tid; i < KDIM * 24; i += 192) {
        int k = i / 24, c4 = i % 24;
        *(float4*)&ws[k][c4 * 4] = *(const float4*)&W[(size_t)k * 96 + c4 * 4];
    }
    const float4 bj = *(const float4*)&bias[cg * 4];
    float s0=0,s1=0,s2=0,s3=0, q0=0,q1=0,q2=0,q3=0;
    const int nchunks = (nrows + 31) / 32;
    for (int chunk = blockIdx.x; chunk < nchunks; chunk += gridDim.x) {
        const int row0 = chunk * 32;
        __syncthreads();
        for (int i = tid; i < 32 * KG; i += 192) {
            int r = i / KG, g = i % KG;
            int gr = row0 + r;
            float4 v = make_float4(0.f, 0.f, 0.f, 0.f);
            if (gr < nrows) v = *(const float4*)&in[(size_t)gr * KDIM + g * 4];
            if constexpr (IN_AFF) {
                float4 a = *(const float4*)&ac[g * 4];
                float4 c = *(const float4*)&ac[KDIM + g * 4];
                v.x = v.x * a.x + c.x; v.y = v.y * a.y + c.y;
                v.z = v.z * a.z + c.z; v.w = v.w * a.w + c.w;
            }
            if constexpr (IN_RELU) {
                v.x = fmaxf(v.x, 0.f); v.y = fmaxf(v.y, 0.f);
                v.z = fmaxf(v.z, 0.f); v.w = fmaxf(v.w, 0.f);
            }
            *(float4*)&xs[r][4 * (g ^ (r & 7))] = v;
        }
        __syncthreads();
        float acc[4][4];
        #pragma unroll
        for (int m = 0; m < 4; m++) {
            acc[m][0] = bj.x; acc[m][1] = bj.y; acc[m][2] = bj.z; acc[m][3] = bj.w;
        }
        #pragma unroll 4
        for (int g = 0; g < KG; g++) {
            const int xi = 4 * (g ^ rg);
            float4 xv0 = *(const float4*)&xs[rg     ][xi];
            float4 xv1 = *(const float4*)&xs[rg +  8][xi];
            float4 xv2 = *(const float4*)&xs[rg + 16][xi];
            float4 xv3 = *(const float4*)&xs[rg + 24][xi];
            #pragma unroll
            for (int i = 0; i < 4; i++) {
                float4 wv = *(const float4*)&ws[g * 4 + i][cg * 4];
                float x0 = (i==0)?xv0.x:(i==1)?xv0.y:(i==2)?xv0.z:xv0.w;
                float x1 = (i==0)?xv1.x:(i==1)?xv1.y:(i==2)?xv1.z:xv1.w;
                float x2 = (i==0)?xv2.x:(i==1)?xv2.y:(i==2)?xv2.z:xv2.w;
                float x3 = (i==0)?xv3.x:(i==1)?xv3.y:(i==2)?xv3.z:xv3.w;
                acc[0][0] = fmaf(x0, wv.x, acc[0][0]); acc[0][1] = fmaf(x0, wv.y, acc[0][1]);
                acc[0][2] = fmaf(x0, wv.z, acc[0][2]); acc[0][3] = fmaf(x0, wv.w, acc[0][3]);
                acc[1][0] = fmaf(x1, wv.x, acc[1][0]); acc[1][1] = fmaf(x1, wv.y, acc[1][1]);
                acc[1][2] = fmaf(x1, wv.z, acc[1][2]); acc[1][3] = fmaf(x1, wv.w, acc[1][3]);
                acc[2][0] = fmaf(x2, wv.x, acc[2][0]); acc[2][1] = fmaf(x2, wv.y, acc[2][1]);
                acc[2][2] = fmaf(x2, wv.z, acc[2][2]); acc[2][3] = fmaf(x2, wv.w, acc[2][3]);
                acc[3][0] = fmaf(x3, wv.x, acc[3][0]); acc[3][1] = fmaf(x3, wv.y, acc[3][1]);
                acc[3][2] = fmaf(x3, wv.z, acc[3][2]); acc[3][3] = fmaf(x3, wv.w, acc[3][3]);
            }
        }
        #pragma unroll
        for (int m = 0; m < 4; m++) {
            const int gr = row0 + rg + 8 * m;
            if (gr < nrows) {
                float4 o = make_float4(acc[m][0], acc[m][1], acc[m][2], acc[m][3]);
                if constexpr (OUT_RELU) {
                    o.x = fmaxf(o.x, 0.f); o.y = fmaxf(o.y, 0.f);
                    o.z = fmaxf(o.z, 0.f); o.w = fmaxf(o.w, 0.f);
                }
                *(float4*)&out[(size_t)gr * 96 + cg * 4] = o;
                if constexpr (STATS) {
                    s0 += o.x; q0 += o.x * o.x; s1 += o.y; q1 += o.y * o.y;
                    s2 += o.z; q2 += o.z * o.z; s3 += o.w; q3 += o.w * o.w;
                }
            }
        }
    }
    if constexpr (STATS) {
        __syncthreads();
        float* rs = &xs[0][0];
        float* rq = rs + 8 * 96;
        rs[rg * 96 + cg * 4 + 0] = s0; rs[rg * 96 + cg * 4 + 1] = s1;
        rs[rg * 96 + cg * 4 + 2] = s2; rs[rg * 96 + cg * 4 + 3] = s3;
        rq[rg * 96 + cg * 4 + 0] = q0; rq[rg * 96 + cg * 4 + 1] = q1;
        rq[rg * 96 + cg * 4 + 2] = q2; rq[rg * 96 + cg * 4 + 3] = q3;
        __syncthreads();
        if (tid < 96) {
            float a = 0.f, b = 0.f;
            #pragma unroll
            for (int r = 0; r < 8; r++) { a += rs[r * 96 + tid]; b += rq[r * 96 + tid]; }
            atomicAdd(&stats[tid],      a);
            atomicAdd(&stats[96 + tid], b);
        }
    }
}

// ---------------- head ----------------
__global__ void head_kernel(const float* __restrict__ g1, const float* __restrict__ ac,
                            const float* __restrict__ Wc, const float* __restrict__ bc,
                            float* __restrict__ out, int ngraphs) {
    int gi = blockIdx.x * blockDim.x + threadIdx.x;
    if (gi >= ngraphs) return;
    float v[NCLS];
    #pragma unroll
    for (int c = 0; c < NCLS; c++) v[c] = bc[c];
    for (int k = 0; k < HDIM; k++) {
        float x = g1[(size_t)gi * HDIM + k] * ac[k] + ac[HDIM + k];
        #pragma unroll
        for (int c = 0; c < NCLS; c++) v[c] = fmaf(x, Wc[k * NCLS + c], v[c]);
    }
    float mx = v[0];
    #pragma unroll
    for (int c = 1; c < NCLS; c++) mx = fmaxf(mx, v[c]);
    float sum = 0.f;
    #pragma unroll
    for (int c = 0; c < NCLS; c++) sum += expf(v[c] - mx);
    float lse = mx + logf(sum);
    #pragma unroll
    for (int c = 0; c < NCLS; c++) out[(size_t)gi * NCLS + c] = v[c] - lse;
}

extern "C" void kernel_launch(void* const* d_in, const int* in_sizes, int n_in,
                              void* d_out, int out_size, void* d_ws, size_t ws_size,
                              hipStream_t stream) {
    const float* x         = (const float*)d_in[0];
    const int*   ei        = (const int*)  d_in[1];
    const int*   batch     = (const int*)  d_in[2];
    const float* bn_feat_w = (const float*)d_in[3];
    const float* bn_feat_b = (const float*)d_in[4];
    const float* Wf        = (const float*)d_in[5];
    const float* bfv       = (const float*)d_in[6];
    const float* bn_fc_w   = (const float*)d_in[7];
    const float* bn_fc_b   = (const float*)d_in[8];
    const float* Wl        = (const float*)d_in[9];
    const float* bl        = (const float*)d_in[10];
    const float* bn_hid_w  = (const float*)d_in[11];
    const float* bn_hid_b  = (const float*)d_in[12];
    const float* Wc        = (const float*)d_in[13];
    const float* bc        = (const float*)d_in[14];
    float* out = (float*)d_out;

    char* p = (char*)d_ws;
    auto alloc = [&](size_t bytes) { char* q = p; p += (bytes + 255) & ~(size_t)255; return q; };
    u16*   hb     = (u16*)  alloc((size_t)N_NODES * HDIM * 2);
    u16*   mb     = (u16*)  alloc((size_t)N_NODES * HDIM * 2);
    float* g      = (float*)alloc((size_t)N_GRAPHS * HDIM * 4);
    float* g1     = (float*)alloc((size_t)N_GRAPHS * HDIM * 4);
    float* statsX = (float*)alloc(2 * F_IN * 4);
    float* acX    = (float*)alloc(2 * F_IN * 4);
    float* statsT = (float*)alloc(2 * HDIM * 4);
    float* acT    = (float*)alloc(2 * HDIM * 4);
    float* statsG = (float*)alloc(2 * HDIM * 4);
    float* acG    = (float*)alloc(2 * HDIM * 4);
    float* statsG1= (float*)alloc(2 * HDIM * 4);
    float* acHid  = (float*)alloc(2 * HDIM * 4);
    u16*   wtF    = (u16*)  alloc(96 * F_IN * 2);
    float* bFmod  = (float*)alloc(96 * 4);
    u16*   wt1[3]; u16* wt2[3]; float* b1mod[3]; float* b2mod[3];
    for (int l = 0; l < 3; l++) {
        wt1[l] = (u16*)alloc(96 * HDIM * 2); b1mod[l] = (float*)alloc(96 * 4);
        wt2[l] = (u16*)alloc(96 * HDIM * 2); b2mod[l] = (float*)alloc(96 * 4);
    }
    int* deg      = (int*)alloc((size_t)N_NODES * 4);
    int* row_ptr  = (int*)alloc((size_t)(N_NODES + 1) * 4);
    int* csr      = (int*)alloc((size_t)N_EDGES * 4);
    int* stmp     = (int*)alloc((size_t)N_NODES * 4);
    int* spart    = (int*)alloc(64 * 4);
    int* cnt      = (int*)alloc((size_t)NBUCK2 * NEB * 4);
    int* ofs      = (int*)alloc((size_t)NBUCK2 * NEB * 4);
    int* stmp2    = (int*)alloc((size_t)NBUCK2 * NEB * 4);
    int* spart2   = (int*)alloc(64 * 4);
    uint2* ebuf   = (uint2*)alloc((size_t)N_EDGES * 8);

    const int* srcp = ei;
    const int* dstp = ei + N_EDGES;

    const int nch64  = (N_NODES + 63) / 64;
    const int gridF  = (nch64 < 768) ? nch64 : 768;   // K=128: 3 blk/CU
    const int grid96 = (nch64 < 1024) ? nch64 : 1024; // K=96:  4 blk/CU
    const int gridG  = (N_GRAPHS + 31) / 32;
    const int nscan  = (N_NODES + 1023) / 1024;
    const int ncb    = NBUCK2 * NEB;
    const int nscan2 = (ncb + 1023) / 1024;

    // BN(x) stats -> fold affine into Wf -> h = relu(x @ Wf' + bf')  (bf16 out)
    hipMemsetAsync(statsX, 0, 2 * F_IN * 4, stream);
    colstats_kernel<F_IN><<<256, 2 * F_IN, 0, stream>>>(x, statsX, N_NODES);
    finalize_bn_kernel<<<1, F_IN, 0, stream>>>(statsX, bn_feat_w, bn_feat_b, acX, F_IN, 1.0f / N_NODES);
    wprep_kernel<F_IN, true><<<(F_IN * 96 + 255) / 256, 256, 0, stream>>>(Wf, bfv, acX, wtF, bFmod);
    mmx_kernel<F_IN, true, false, true, false, true, false><<<gridF, 256, 0, stream>>>(x, wtF, bFmod, nullptr, hb, nullptr, nullptr, N_NODES);

    // weight preps for the 3 GIN layers
    for (int l = 0; l < 3; l++) {
        wprep_kernel<HDIM, false><<<(HDIM * 96 + 255) / 256, 256, 0, stream>>>((const float*)d_in[15 + 6 * l], (const float*)d_in[16 + 6 * l], nullptr, wt1[l], b1mod[l]);
        wprep_kernel<HDIM, false><<<(HDIM * 96 + 255) / 256, 256, 0, stream>>>((const float*)d_in[19 + 6 * l], (const float*)d_in[20 + 6 * l], nullptr, wt2[l], b2mod[l]);
    }

    // CSR build (partitioned 2-pass)
    hipMemsetAsync(deg, 0, (size_t)N_NODES * 4, stream);
    hist_kernel<<<(N_EDGES + 255) / 256, 256, 0, stream>>>(dstp, deg, N_EDGES);
    scan1_kernel<<<nscan, 1024, 0, stream>>>(deg, stmp, spart, N_NODES);
    scan2_kernel<<<1, 64, 0, stream>>>(spart, nscan);
    scan3_rowptr_kernel<<<nscan, 1024, 0, stream>>>(stmp, spart, deg, row_ptr, N_NODES);
    count_kernel<<<NEB, 256, 0, stream>>>(dstp, cnt);
    scan1_kernel<<<nscan2, 1024, 0, stream>>>(cnt, stmp2, spart2, ncb);
    scan2_kernel<<<1, 64, 0, stream>>>(spart2, nscan2);
    scan3_kernel<<<nscan2, 1024, 0, stream>>>(stmp2, spart2, ofs, ncb);
    distribute_kernel<<<NEB, 256, 0, stream>>>(srcp, dstp, ofs, ebuf);
    bucket_fill_kernel<<<NBUCK2, 256, 0, stream>>>(ebuf, ofs, row_ptr, csr);

    hipMemsetAsync(g, 0, (size_t)N_GRAPHS * HDIM * 4, stream);

    for (int l = 0; l < 3; l++) {
        const float* bw = (const float*)d_in[17 + 6 * l];
        const float* bb = (const float*)d_in[18 + 6 * l];
        // m = h + sum_nbr(h)  (bf16 in/out)
        agg_kernel<<<(N_NODES + 7) / 8, 192, 0, stream>>>(hb, row_ptr, csr, mb, N_NODES);
        // t = m @ W1 + b1 (bf16 in/out, in-place on mb), fused f32 stats(t)
        hipMemsetAsync(statsT, 0, 2 * HDIM * 4, stream);
        mmx_kernel<HDIM, false, false, false, true, true, false><<<grid96, 256, 0, stream>>>(mb, wt1[l], b1mod[l], nullptr, mb, statsT, nullptr, N_NODES);
        finalize_bn_kernel<<<1, HDIM, 0, stream>>>(statsT, bw, bb, acT, HDIM, 1.0f / N_NODES);
        // h = relu( relu(BN(t)) @ W2 + b2 ): layers 0,1 -> bf16 h; layer 2 -> fused pool
        if (l < 2) {
            mmx_kernel<HDIM, false, true, true, false, true, false><<<grid96, 256, 0, stream>>>(mb, wt2[l], b2mod[l], acT, hb, nullptr, nullptr, N_NODES);
        } else {
            mmx_kernel<HDIM, false, true, true, false, false, true><<<grid96, 256, 0, stream>>>(mb, wt2[l], b2mod[l], acT, g, nullptr, batch, N_NODES);
        }
    }

    // g1 = relu(BN_fc(g) @ Wl + bl), fused stats(g1)
    hipMemsetAsync(statsG, 0, 2 * HDIM * 4, stream);
    colstats_kernel<HDIM><<<64, 2 * HDIM, 0, stream>>>(g, statsG, N_GRAPHS);
    finalize_bn_kernel<<<1, HDIM, 0, stream>>>(statsG, bn_fc_w, bn_fc_b, acG, HDIM, 1.0f / N_GRAPHS);
    hipMemsetAsync(statsG1, 0, 2 * HDIM * 4, stream);
    mm_kernel<HDIM, true, false, true, true><<<gridG, 192, 0, stream>>>(g, Wl, bl, acG, g1, statsG1, N_GRAPHS);
    finalize_bn_kernel<<<1, HDIM, 0, stream>>>(statsG1, bn_hid_w, bn_hid_b, acHid, HDIM, 1.0f / N_GRAPHS);

    head_kernel<<<2, 256, 0, stream>>>(g1, acHid, Wc, bc, out, N_GRAPHS);
}

// Round 7
// 389.222 us; speedup vs baseline: 1.4776x; 1.0420x over previous
//
#include <hip/hip_runtime.h>

#define N_NODES 50000
#define N_EDGES 800000
#define N_GRAPHS 512
#define F_IN 128
#define HDIM 96
#define NCLS 10
#define BN_EPS 1e-5f

// partitioned CSR fill geometry
#define NPB 128                            // nodes per bucket
#define NBUCK2 ((N_NODES + NPB - 1) / NPB) // 391 buckets
#define NEB 128                            // edge-partition blocks
#define EPB ((N_EDGES + NEB - 1) / NEB)    // 6250 edges per block

typedef unsigned int u32;
typedef unsigned short u16;
typedef __attribute__((ext_vector_type(8))) short bf16x8;
typedef __attribute__((ext_vector_type(4))) float f32x4;

__device__ __forceinline__ u16 f2bf(float f) {
    u32 u = __float_as_uint(f);
    u32 r = (u + 0x7fffu + ((u >> 16) & 1u)) >> 16;   // RNE
    return (u16)r;
}
__device__ __forceinline__ float bflo(u32 w) { return __uint_as_float(w << 16); }
__device__ __forceinline__ float bfhi(u32 w) { return __uint_as_float(w & 0xffff0000u); }

// ---------------- column stats, vectorized (sum, sumsq) ----------------
// float4 loads, 8 rows/block-iter, LDS reduce, one atomic per column per block.
template<int NC>
__global__ __launch_bounds__(256) void colstats4_kernel(const float* __restrict__ in,
                                                        float* __restrict__ stats,
                                                        int nrows) {
    constexpr int CG  = NC / 4;       // col groups (32 for NC=128)
    constexpr int RPB = 256 / CG;     // rows per block-iter (8)
    const int cg = threadIdx.x % CG;
    const int rg = threadIdx.x / CG;
    float4 s = make_float4(0.f, 0.f, 0.f, 0.f);
    float4 q = make_float4(0.f, 0.f, 0.f, 0.f);
    for (int r = blockIdx.x * RPB + rg; r < nrows; r += gridDim.x * RPB) {
        float4 v = *(const float4*)&in[(size_t)r * NC + cg * 4];
        s.x += v.x; s.y += v.y; s.z += v.z; s.w += v.w;
        q.x += v.x * v.x; q.y += v.y * v.y; q.z += v.z * v.z; q.w += v.w * v.w;
    }
    __shared__ float ss[RPB][NC], sq[RPB][NC];
    *(float4*)&ss[rg][cg * 4] = s;
    *(float4*)&sq[rg][cg * 4] = q;
    __syncthreads();
    if (threadIdx.x < NC) {
        float a = 0.f, b = 0.f;
        #pragma unroll
        for (int r = 0; r < RPB; r++) { a += ss[r][threadIdx.x]; b += sq[r][threadIdx.x]; }
        atomicAdd(&stats[threadIdx.x],      a);
        atomicAdd(&stats[NC + threadIdx.x], b);
    }
}

// small-row column stats (graph-level tensors)
template<int NC>
__global__ __launch_bounds__(2*NC) void colstats_kernel(const float* __restrict__ in,
                                                        float* __restrict__ stats,
                                                        int nrows) {
    const int col  = threadIdx.x % NC;
    const int half = threadIdx.x / NC;
    float s = 0.f, ss = 0.f;
    for (int r = blockIdx.x * 2 + half; r < nrows; r += gridDim.x * 2) {
        float v = in[(size_t)r * NC + col];
        s += v; ss += v * v;
    }
    __shared__ float shs[2][NC], shq[2][NC];
    shs[half][col] = s; shq[half][col] = ss;
    __syncthreads();
    if (half == 0) {
        atomicAdd(&stats[col],      s  + shs[1][col]);
        atomicAdd(&stats[NC + col], ss + shq[1][col]);
    }
}

__global__ void finalize_bn_kernel(const float* __restrict__ stats,
                                   const float* __restrict__ w,
                                   const float* __restrict__ b,
                                   float* __restrict__ ac, int ncols, float inv_n) {
    int k = blockIdx.x * blockDim.x + threadIdx.x;
    if (k < ncols) {
        float mu  = stats[k] * inv_n;
        float var = stats[ncols + k] * inv_n - mu * mu;
        float a   = w[k] * rsqrtf(var + BN_EPS);
        ac[k]         = a;
        ac[ncols + k] = b[k] - mu * a;
    }
}

// ---------------- weight prep: Wt[n][k] = bf16( (FOLD? a_k:1) * W[k][n] ), bias fold ----------------
template<int KDIM, bool FOLD>
__global__ __launch_bounds__(256) void wprep_kernel(const float* __restrict__ W,
                                                    const float* __restrict__ bias,
                                                    const float* __restrict__ ac,
                                                    u16* __restrict__ wtb,
                                                    float* __restrict__ bmod) {
    int i = blockIdx.x * 256 + threadIdx.x;
    if (i < KDIM * 96) {
        int k = i / 96, n = i % 96;
        float v = W[i];
        if constexpr (FOLD) v *= ac[k];
        wtb[n * KDIM + k] = f2bf(v);
    }
    if (blockIdx.x == 0 && threadIdx.x < 96) {
        float b = bias[threadIdx.x];
        if constexpr (FOLD) {
            for (int k = 0; k < KDIM; k++) b += ac[KDIM + k] * W[k * 96 + threadIdx.x];
        }
        bmod[threadIdx.x] = b;
    }
}

// ---------------- CSR build (by dst), partitioned 2-pass ----------------
__global__ void hist_kernel(const int* __restrict__ dst, int* __restrict__ deg, int ne) {
    int e = blockIdx.x * blockDim.x + threadIdx.x;
    if (e < ne) atomicAdd(&deg[dst[e]], 1);
}

__global__ __launch_bounds__(1024) void scan1_kernel(const int* __restrict__ in,
                                                     int* __restrict__ tmp,
                                                     int* __restrict__ partial, int n) {
    __shared__ int sh[1024];
    const int i = blockIdx.x * 1024 + threadIdx.x;
    const int d = (i < n) ? in[i] : 0;
    sh[threadIdx.x] = d;
    __syncthreads();
    for (int off = 1; off < 1024; off <<= 1) {
        int v = 0;
        if (threadIdx.x >= off) v = sh[threadIdx.x - off];
        __syncthreads();
        sh[threadIdx.x] += v;
        __syncthreads();
    }
    if (i < n) tmp[i] = sh[threadIdx.x] - d;
    if (threadIdx.x == 1023) partial[blockIdx.x] = sh[1023];
}

__global__ void scan2_kernel(int* __restrict__ partial, int nparts) {
    const int t = threadIdx.x;
    int d = (t < nparts) ? partial[t] : 0;
    int v = d;
    for (int off = 1; off < 64; off <<= 1) {
        int u = __shfl_up(v, off, 64);
        if (t >= off) v += u;
    }
    if (t < nparts) partial[t] = v - d;
}

__global__ __launch_bounds__(1024) void scan3_rowptr_kernel(const int* __restrict__ tmp,
                                                            const int* __restrict__ partial,
                                                            const int* __restrict__ deg,
                                                            int* __restrict__ row_ptr, int n) {
    const int i = blockIdx.x * 1024 + threadIdx.x;
    if (i < n) {
        int v = tmp[i] + partial[blockIdx.x];
        row_ptr[i] = v;
        if (i == n - 1) row_ptr[n] = v + deg[i];
    }
}

__global__ __launch_bounds__(1024) void scan3_kernel(const int* __restrict__ tmp,
                                                     const int* __restrict__ partial,
                                                     int* __restrict__ out, int n) {
    const int i = blockIdx.x * 1024 + threadIdx.x;
    if (i < n) out[i] = tmp[i] + partial[blockIdx.x];
}

__global__ __launch_bounds__(256) void count_kernel(const int* __restrict__ dst,
                                                    int* __restrict__ cnt /*[NBUCK2][NEB]*/) {
    __shared__ int lc[NBUCK2];
    for (int i = threadIdx.x; i < NBUCK2; i += 256) lc[i] = 0;
    __syncthreads();
    const int lo = blockIdx.x * EPB;
    const int hi = min(lo + EPB, N_EDGES);
    for (int e = lo + threadIdx.x; e < hi; e += 256)
        atomicAdd(&lc[dst[e] / NPB], 1);
    __syncthreads();
    for (int i = threadIdx.x; i < NBUCK2; i += 256)
        cnt[i * NEB + blockIdx.x] = lc[i];
}

__global__ __launch_bounds__(256) void distribute_kernel(const int* __restrict__ src,
                                                         const int* __restrict__ dst,
                                                         const int* __restrict__ ofs,
                                                         uint2* __restrict__ ebuf) {
    __shared__ int lofs[NBUCK2];
    for (int i = threadIdx.x; i < NBUCK2; i += 256) lofs[i] = ofs[i * NEB + blockIdx.x];
    __syncthreads();
    const int lo = blockIdx.x * EPB;
    const int hi = min(lo + EPB, N_EDGES);
    for (int e = lo + threadIdx.x; e < hi; e += 256) {
        int d = dst[e];
        int q = atomicAdd(&lofs[d / NPB], 1);
        ebuf[q] = make_uint2((u32)src[e], (u32)d);
    }
}

__global__ __launch_bounds__(256) void bucket_fill_kernel(const uint2* __restrict__ ebuf,
                                                          const int* __restrict__ ofs,
                                                          const int* __restrict__ row_ptr,
                                                          int* __restrict__ csr) {
    __shared__ int cur[NPB];
    const int p    = blockIdx.x;
    const int base = p * NPB;
    const int nn   = min(NPB, N_NODES - base);
    for (int i = threadIdx.x; i < nn; i += 256) cur[i] = row_ptr[base + i];
    __syncthreads();
    const int e0 = ofs[p * NEB];
    const int e1 = (p + 1 < NBUCK2) ? ofs[(p + 1) * NEB] : N_EDGES;
    for (int e = e0 + threadIdx.x; e < e1; e += 256) {
        uint2 v = ebuf[e];
        int pos = atomicAdd(&cur[(int)v.y - base], 1);
        csr[pos] = (int)v.x;
    }
}

// ---------------- GIN aggregation: m[n] = h[n] + sum_nbr h[s]  (bf16 in/out) ----------------
__global__ __launch_bounds__(192) void agg_kernel(const u16* __restrict__ hb,
                                                  const int* __restrict__ row_ptr,
                                                  const int* __restrict__ csr,
                                                  u16* __restrict__ mb, int n) {
    const int jj   = threadIdx.x % 24;
    const int node = blockIdx.x * 8 + threadIdx.x / 24;
    if (node >= n) return;
    const int p0 = row_ptr[node], p1 = row_ptr[node + 1];
    uint2 sv = *(const uint2*)&hb[(size_t)node * 96 + jj * 4];
    float a0 = bflo(sv.x), a1 = bfhi(sv.x), a2 = bflo(sv.y), a3 = bfhi(sv.y);
    int p = p0;
    for (; p + 8 <= p1; p += 8) {
        int s0 = csr[p],     s1 = csr[p + 1], s2 = csr[p + 2], s3 = csr[p + 3];
        int s4 = csr[p + 4], s5 = csr[p + 5], s6 = csr[p + 6], s7 = csr[p + 7];
        uint2 v0 = *(const uint2*)&hb[(size_t)s0 * 96 + jj * 4];
        uint2 v1 = *(const uint2*)&hb[(size_t)s1 * 96 + jj * 4];
        uint2 v2 = *(const uint2*)&hb[(size_t)s2 * 96 + jj * 4];
        uint2 v3 = *(const uint2*)&hb[(size_t)s3 * 96 + jj * 4];
        uint2 v4 = *(const uint2*)&hb[(size_t)s4 * 96 + jj * 4];
        uint2 v5 = *(const uint2*)&hb[(size_t)s5 * 96 + jj * 4];
        uint2 v6 = *(const uint2*)&hb[(size_t)s6 * 96 + jj * 4];
        uint2 v7 = *(const uint2*)&hb[(size_t)s7 * 96 + jj * 4];
        a0 += ((bflo(v0.x) + bflo(v1.x)) + (bflo(v2.x) + bflo(v3.x)))
            + ((bflo(v4.x) + bflo(v5.x)) + (bflo(v6.x) + bflo(v7.x)));
        a1 += ((bfhi(v0.x) + bfhi(v1.x)) + (bfhi(v2.x) + bfhi(v3.x)))
            + ((bfhi(v4.x) + bfhi(v5.x)) + (bfhi(v6.x) + bfhi(v7.x)));
        a2 += ((bflo(v0.y) + bflo(v1.y)) + (bflo(v2.y) + bflo(v3.y)))
            + ((bflo(v4.y) + bflo(v5.y)) + (bflo(v6.y) + bflo(v7.y)));
        a3 += ((bfhi(v0.y) + bfhi(v1.y)) + (bfhi(v2.y) + bfhi(v3.y)))
            + ((bfhi(v4.y) + bfhi(v5.y)) + (bfhi(v6.y) + bfhi(v7.y)));
    }
    for (; p < p1; p++) {
        int s = csr[p];
        uint2 v = *(const uint2*)&hb[(size_t)s * 96 + jj * 4];
        a0 += bflo(v.x); a1 += bfhi(v.x); a2 += bflo(v.y); a3 += bfhi(v.y);
    }
    ushort4 o; o.x = f2bf(a0); o.y = f2bf(a1); o.z = f2bf(a2); o.w = f2bf(a3);
    *(ushort4*)&mb[(size_t)node * 96 + jj * 4] = o;
}

// ---------------- MFMA matmul: out[nrows][96] = f(in[nrows][KDIM]) @ W + bias ----------------
template<int KDIM, bool IN_F32, bool IN_AFF_RELU, bool OUT_RELU, bool STATS, bool OUT_BF16, bool POOL>
__global__ __launch_bounds__(256) void mmx_kernel(const void* __restrict__ in_,
                                                  const u16* __restrict__ wt,   // [96][KDIM] bf16
                                                  const float* __restrict__ bias,
                                                  const float* __restrict__ ac,
                                                  void* __restrict__ out_,
                                                  float* __restrict__ stats,
                                                  const int* __restrict__ batch,
                                                  int nrows) {
    constexpr int KP = KDIM + 8;
    constexpr int KB = KDIM / 32;
    __shared__ u16 wlds[96 * KP];
    __shared__ u16 alds[64 * KP];
    __shared__ float sred[2][4][96];
    const int tid = threadIdx.x;

    for (int i = tid; i < 96 * (KDIM / 8); i += 256) {
        int nn = i / (KDIM / 8), c8 = i % (KDIM / 8);
        *(uint4*)&wlds[nn * KP + c8 * 8] = *(const uint4*)&wt[nn * KDIM + c8 * 8];
    }

    const int w    = tid >> 6;
    const int lane = tid & 63;
    const int r16  = lane & 15;
    const int kg   = lane >> 4;
    const int m0   = w * 16;
    float bn[6];
    #pragma unroll
    for (int nt = 0; nt < 6; nt++) bn[nt] = bias[nt * 16 + r16];
    float scol[6] = {0,0,0,0,0,0}, qcol[6] = {0,0,0,0,0,0};

    const int nchunks = (nrows + 63) / 64;
    for (int chunk = blockIdx.x; chunk < nchunks; chunk += gridDim.x) {
        const int row0 = chunk * 64;
        __syncthreads();
        if constexpr (IN_F32) {
            const float* inf = (const float*)in_;
            for (int i = tid; i < 64 * (KDIM / 4); i += 256) {
                int r = i / (KDIM / 4), c4 = i % (KDIM / 4);
                int gr = row0 + r;
                float4 v = (gr < nrows) ? *(const float4*)&inf[(size_t)gr * KDIM + c4 * 4]
                                        : make_float4(0.f, 0.f, 0.f, 0.f);
                ushort4 o; o.x = f2bf(v.x); o.y = f2bf(v.y); o.z = f2bf(v.z); o.w = f2bf(v.w);
                *(ushort4*)&alds[r * KP + c4 * 4] = o;
            }
        } else {
            const u16* inb = (const u16*)in_;
            for (int i = tid; i < 64 * (KDIM / 8); i += 256) {
                int r = i / (KDIM / 8), c8 = i % (KDIM / 8);
                int gr = row0 + r;
                uint4 v = (gr < nrows) ? *(const uint4*)&inb[(size_t)gr * KDIM + c8 * 8]
                                       : make_uint4(0u, 0u, 0u, 0u);
                if constexpr (IN_AFF_RELU) {
                    u32 words[4] = {v.x, v.y, v.z, v.w};
                    #pragma unroll
                    for (int t2 = 0; t2 < 4; t2++) {
                        int k0 = c8 * 8 + t2 * 2;
                        float lo = fmaxf(bflo(words[t2]) * ac[k0]     + ac[KDIM + k0],     0.f);
                        float hi = fmaxf(bfhi(words[t2]) * ac[k0 + 1] + ac[KDIM + k0 + 1], 0.f);
                        words[t2] = (u32)f2bf(lo) | ((u32)f2bf(hi) << 16);
                    }
                    v.x = words[0]; v.y = words[1]; v.z = words[2]; v.w = words[3];
                }
                *(uint4*)&alds[r * KP + c8 * 8] = v;
            }
        }
        __syncthreads();

        bf16x8 af[KB];
        #pragma unroll
        for (int kb = 0; kb < KB; kb++)
            af[kb] = *(const bf16x8*)&alds[(m0 + r16) * KP + kb * 32 + kg * 8];

        f32x4 acc[6];
        #pragma unroll
        for (int nt = 0; nt < 6; nt++) acc[nt] = (f32x4){bn[nt], bn[nt], bn[nt], bn[nt]};
        #pragma unroll
        for (int kb = 0; kb < KB; kb++) {
            #pragma unroll
            for (int nt = 0; nt < 6; nt++) {
                bf16x8 bfr = *(const bf16x8*)&wlds[(nt * 16 + r16) * KP + kb * 32 + kg * 8];
                acc[nt] = __builtin_amdgcn_mfma_f32_16x16x32_bf16(af[kb], bfr, acc[nt], 0, 0, 0);
            }
        }

        const int gr0  = row0 + m0 + kg * 4;
        const bool full = (gr0 + 3 < nrows);
        if constexpr (POOL) {
            float* gbuf = (float*)out_;
            int bl = -1, bh = -2;
            if (full) { bl = batch[gr0]; bh = batch[gr0 + 3]; }
            #pragma unroll
            for (int nt = 0; nt < 6; nt++) {
                float v0 = acc[nt][0], v1 = acc[nt][1], v2 = acc[nt][2], v3 = acc[nt][3];
                if constexpr (OUT_RELU) {
                    v0 = fmaxf(v0, 0.f); v1 = fmaxf(v1, 0.f);
                    v2 = fmaxf(v2, 0.f); v3 = fmaxf(v3, 0.f);
                }
                const int n = nt * 16 + r16;
                if (full) {
                    if (bl == bh) {
                        atomicAdd(&gbuf[(size_t)bl * 96 + n], (v0 + v1) + (v2 + v3));
                    } else {
                        atomicAdd(&gbuf[(size_t)batch[gr0]     * 96 + n], v0);
                        atomicAdd(&gbuf[(size_t)batch[gr0 + 1] * 96 + n], v1);
                        atomicAdd(&gbuf[(size_t)batch[gr0 + 2] * 96 + n], v2);
                        atomicAdd(&gbuf[(size_t)batch[gr0 + 3] * 96 + n], v3);
                    }
                } else {
                    if (gr0     < nrows) atomicAdd(&gbuf[(size_t)batch[gr0]     * 96 + n], v0);
                    if (gr0 + 1 < nrows) atomicAdd(&gbuf[(size_t)batch[gr0 + 1] * 96 + n], v1);
                    if (gr0 + 2 < nrows) atomicAdd(&gbuf[(size_t)batch[gr0 + 2] * 96 + n], v2);
                }
            }
        } else {
            #pragma unroll
            for (int nt = 0; nt < 6; nt++) {
                float v[4] = {acc[nt][0], acc[nt][1], acc[nt][2], acc[nt][3]};
                if constexpr (OUT_RELU) {
                    #pragma unroll
                    for (int rr = 0; rr < 4; rr++) v[rr] = fmaxf(v[rr], 0.f);
                }
                const int n = nt * 16 + r16;
                #pragma unroll
                for (int rr = 0; rr < 4; rr++) {
                    const int gr = gr0 + rr;
                    if (full || gr < nrows) {
                        if constexpr (OUT_BF16) ((u16*)out_)[(size_t)gr * 96 + n] = f2bf(v[rr]);
                        else                    ((float*)out_)[(size_t)gr * 96 + n] = v[rr];
                        if constexpr (STATS) { scol[nt] += v[rr]; qcol[nt] += v[rr] * v[rr]; }
                    }
                }
            }
        }
    }

    if constexpr (STATS) {
        #pragma unroll
        for (int nt = 0; nt < 6; nt++) {
            scol[nt] += __shfl_xor(scol[nt], 16);
            scol[nt] += __shfl_xor(scol[nt], 32);
            qcol[nt] += __shfl_xor(qcol[nt], 16);
            qcol[nt] += __shfl_xor(qcol[nt], 32);
        }
        __syncthreads();
        if (kg == 0) {
            #pragma unroll
            for (int nt = 0; nt < 6; nt++) {
                sred[0][w][nt * 16 + r16] = scol[nt];
                sred[1][w][nt * 16 + r16] = qcol[nt];
            }
        }
        __syncthreads();
        if (tid < 96) {
            float a = sred[0][0][tid] + sred[0][1][tid] + sred[0][2][tid] + sred[0][3][tid];
            float b = sred[1][0][tid] + sred[1][1][tid] + sred[1][2][tid] + sred[1][3][tid];
            atomicAdd(&stats[tid],      a);
            atomicAdd(&stats[96 + tid], b);
        }
    }
}

// ---------------- f32 small matmul (G-sized tail) ----------------
template<int KDIM, bool IN_AFF, bool IN_RELU, bool OUT_RELU, bool STATS>
__global__ __launch_bounds__(192) void mm_kernel(const float* __restrict__ in,
                                                 const float* __restrict__ W,
                                                 const float* __restrict__ bias,
                                                 const float* __restrict__ ac,
                                                 float* __restrict__ out,
                                                 float* __restrict__ stats, int nrows) {
    constexpr int KG = KDIM / 4;
    __shared__ float ws[KDIM][96];
    __shared__ float xs[32][KDIM];
    const int tid = threadIdx.x;
    const int cg  = tid % 24;
    const int rg  = tid / 24;
    for (int i = tid; i < KDIM * 24; i += 192) {
        int k = i / 24, c4 = i % 24;
        *(float4*)&ws[k][c4 * 4] = *(const float4*)&W[(size_t)k * 96 + c4 * 4];
    }
    const float4 bj = *(const float4*)&bias[cg * 4];
    float s0=0,s1=0,s2=0,s3=0, q0=0,q1=0,q2=0,q3=0;
    const int nchunks = (nrows + 31) / 32;
    for (int chunk = blockIdx.x; chunk < nchunks; chunk += gridDim.x) {
        const int row0 = chunk * 32;
        __syncthreads();
        for (int i = tid; i < 32 * KG; i += 192) {
            int r = i / KG, g = i % KG;
            int gr = row0 + r;
            float4 v = make_float4(0.f, 0.f, 0.f, 0.f);
            if (gr < nrows) v = *(const float4*)&in[(size_t)gr * KDIM + g * 4];
            if constexpr (IN_AFF) {
                float4 a = *(const float4*)&ac[g * 4];
                float4 c = *(const float4*)&ac[KDIM + g * 4];
                v.x = v.x * a.x + c.x; v.y = v.y * a.y + c.y;
                v.z = v.z * a.z + c.z; v.w = v.w * a.w + c.w;
            }
            if constexpr (IN_RELU) {
                v.x = fmaxf(v.x, 0.f); v.y = fmaxf(v.y, 0.f);
                v.z = fmaxf(v.z, 0.f); v.w = fmaxf(v.w, 0.f);
            }
            *(float4*)&xs[r][4 * (g ^ (r & 7))] = v;
        }
        __syncthreads();
        float acc[4][4];
        #pragma unroll
        for (int m = 0; m < 4; m++) {
            acc[m][0] = bj.x; acc[m][1] = bj.y; acc[m][2] = bj.z; acc[m][3] = bj.w;
        }
        #pragma unroll 4
        for (int g = 0; g < KG; g++) {
            const int xi = 4 * (g ^ rg);
            float4 xv0 = *(const float4*)&xs[rg     ][xi];
            float4 xv1 = *(const float4*)&xs[rg +  8][xi];
            float4 xv2 = *(const float4*)&xs[rg + 16][xi];
            float4 xv3 = *(const float4*)&xs[rg + 24][xi];
            #pragma unroll
            for (int i = 0; i < 4; i++) {
                float4 wv = *(const float4*)&ws[g * 4 + i][cg * 4];
                float x0 = (i==0)?xv0.x:(i==1)?xv0.y:(i==2)?xv0.z:xv0.w;
                float x1 = (i==0)?xv1.x:(i==1)?xv1.y:(i==2)?xv1.z:xv1.w;
                float x2 = (i==0)?xv2.x:(i==1)?xv2.y:(i==2)?xv2.z:xv2.w;
                float x3 = (i==0)?xv3.x:(i==1)?xv3.y:(i==2)?xv3.z:xv3.w;
                acc[0][0] = fmaf(x0, wv.x, acc[0][0]); acc[0][1] = fmaf(x0, wv.y, acc[0][1]);
                acc[0][2] = fmaf(x0, wv.z, acc[0][2]); acc[0][3] = fmaf(x0, wv.w, acc[0][3]);
                acc[1][0] = fmaf(x1, wv.x, acc[1][0]); acc[1][1] = fmaf(x1, wv.y, acc[1][1]);
                acc[1][2] = fmaf(x1, wv.z, acc[1][2]); acc[1][3] = fmaf(x1, wv.w, acc[1][3]);
                acc[2][0] = fmaf(x2, wv.x, acc[2][0]); acc[2][1] = fmaf(x2, wv.y, acc[2][1]);
                acc[2][2] = fmaf(x2, wv.z, acc[2][2]); acc[2][3] = fmaf(x2, wv.w, acc[2][3]);
                acc[3][0] = fmaf(x3, wv.x, acc[3][0]); acc[3][1] = fmaf(x3, wv.y, acc[3][1]);
                acc[3][2] = fmaf(x3, wv.z, acc[3][2]); acc[3][3] = fmaf(x3, wv.w, acc[3][3]);
            }
        }
        #pragma unroll
        for (int m = 0; m < 4; m++) {
            const int gr = row0 + rg + 8 * m;
            if (gr < nrows) {
                float4 o = make_float4(acc[m][0], acc[m][1], acc[m][2], acc[m][3]);
                if constexpr (OUT_RELU) {
                    o.x = fmaxf(o.x, 0.f); o.y = fmaxf(o.y, 0.f);
                    o.z = fmaxf(o.z, 0.f); o.w = fmaxf(o.w, 0.f);
                }
                *(float4*)&out[(size_t)gr * 96 + cg * 4] = o;
                if constexpr (STATS) {
                    s0 += o.x; q0 += o.x * o.x; s1 += o.y; q1 += o.y * o.y;
                    s2 += o.z; q2 += o.z * o.z; s3 += o.w; q3 += o.w * o.w;
                }
            }
        }
    }
    if constexpr (STATS) {
        __syncthreads();
        float* rs = &xs[0][0];
        float* rq = rs + 8 * 96;
        rs[rg * 96 + cg * 4 + 0] = s0; rs[rg * 96 + cg * 4 + 1] = s1;
        rs[rg * 96 + cg * 4 + 2] = s2; rs[rg * 96 + cg * 4 + 3] = s3;
        rq[rg * 96 + cg * 4 + 0] = q0; rq[rg * 96 + cg * 4 + 1] = q1;
        rq[rg * 96 + cg * 4 + 2] = q2; rq[rg * 96 + cg * 4 + 3] = q3;
        __syncthreads();
        if (tid < 96) {
            float a = 0.f, b = 0.f;
            #pragma unroll
            for (int r = 0; r < 8; r++) { a += rs[r * 96 + tid]; b += rq[r * 96 + tid]; }
            atomicAdd(&stats[tid],      a);
            atomicAdd(&stats[96 + tid], b);
        }
    }
}

// ---------------- head ----------------
__global__ void head_kernel(const float* __restrict__ g1, const float* __restrict__ ac,
                            const float* __restrict__ Wc, const float* __restrict__ bc,
                            float* __restrict__ out, int ngraphs) {
    int gi = blockIdx.x * blockDim.x + threadIdx.x;
    if (gi >= ngraphs) return;
    float v[NCLS];
    #pragma unroll
    for (int c = 0; c < NCLS; c++) v[c] = bc[c];
    for (int k = 0; k < HDIM; k++) {
        float x = g1[(size_t)gi * HDIM + k] * ac[k] + ac[HDIM + k];
        #pragma unroll
        for (int c = 0; c < NCLS; c++) v[c] = fmaf(x, Wc[k * NCLS + c], v[c]);
    }
    float mx = v[0];
    #pragma unroll
    for (int c = 1; c < NCLS; c++) mx = fmaxf(mx, v[c]);
    float sum = 0.f;
    #pragma unroll
    for (int c = 0; c < NCLS; c++) sum += expf(v[c] - mx);
    float lse = mx + logf(sum);
    #pragma unroll
    for (int c = 0; c < NCLS; c++) out[(size_t)gi * NCLS + c] = v[c] - lse;
}

extern "C" void kernel_launch(void* const* d_in, const int* in_sizes, int n_in,
                              void* d_out, int out_size, void* d_ws, size_t ws_size,
                              hipStream_t stream) {
    const float* x         = (const float*)d_in[0];
    const int*   ei        = (const int*)  d_in[1];
    const int*   batch     = (const int*)  d_in[2];
    const float* bn_feat_w = (const float*)d_in[3];
    const float* bn_feat_b = (const float*)d_in[4];
    const float* Wf        = (const float*)d_in[5];
    const float* bfv       = (const float*)d_in[6];
    const float* bn_fc_w   = (const float*)d_in[7];
    const float* bn_fc_b   = (const float*)d_in[8];
    const float* Wl        = (const float*)d_in[9];
    const float* bl        = (const float*)d_in[10];
    const float* bn_hid_w  = (const float*)d_in[11];
    const float* bn_hid_b  = (const float*)d_in[12];
    const float* Wc        = (const float*)d_in[13];
    const float* bc        = (const float*)d_in[14];
    float* out = (float*)d_out;

    char* p = (char*)d_ws;
    auto alloc = [&](size_t bytes) { char* q = p; p += (bytes + 255) & ~(size_t)255; return q; };
    u16*   hb     = (u16*)  alloc((size_t)N_NODES * HDIM * 2);
    u16*   mb     = (u16*)  alloc((size_t)N_NODES * HDIM * 2);
    float* g      = (float*)alloc((size_t)N_GRAPHS * HDIM * 4);
    float* g1     = (float*)alloc((size_t)N_GRAPHS * HDIM * 4);
    float* statsX = (float*)alloc(2 * F_IN * 4);
    float* acX    = (float*)alloc(2 * F_IN * 4);
    float* statsT = (float*)alloc(2 * HDIM * 4);
    float* acT    = (float*)alloc(2 * HDIM * 4);
    float* statsG = (float*)alloc(2 * HDIM * 4);
    float* acG    = (float*)alloc(2 * HDIM * 4);
    float* statsG1= (float*)alloc(2 * HDIM * 4);
    float* acHid  = (float*)alloc(2 * HDIM * 4);
    u16*   wtF    = (u16*)  alloc(96 * F_IN * 2);
    float* bFmod  = (float*)alloc(96 * 4);
    u16*   wt1[3]; u16* wt2[3]; float* b1mod[3]; float* b2mod[3];
    for (int l = 0; l < 3; l++) {
        wt1[l] = (u16*)alloc(96 * HDIM * 2); b1mod[l] = (float*)alloc(96 * 4);
        wt2[l] = (u16*)alloc(96 * HDIM * 2); b2mod[l] = (float*)alloc(96 * 4);
    }
    int* deg      = (int*)alloc((size_t)N_NODES * 4);
    int* row_ptr  = (int*)alloc((size_t)(N_NODES + 1) * 4);
    int* csr      = (int*)alloc((size_t)N_EDGES * 4);
    int* stmp     = (int*)alloc((size_t)N_NODES * 4);
    int* spart    = (int*)alloc(64 * 4);
    int* cnt      = (int*)alloc((size_t)NBUCK2 * NEB * 4);
    int* ofs      = (int*)alloc((size_t)NBUCK2 * NEB * 4);
    int* stmp2    = (int*)alloc((size_t)NBUCK2 * NEB * 4);
    int* spart2   = (int*)alloc(64 * 4);
    uint2* ebuf   = (uint2*)alloc((size_t)N_EDGES * 8);

    const int* srcp = ei;
    const int* dstp = ei + N_EDGES;

    const int nch64  = (N_NODES + 63) / 64;
    const int gridF  = (nch64 < 768) ? nch64 : 768;
    const int grid96 = (nch64 < 1024) ? nch64 : 1024;
    const int gridG  = (N_GRAPHS + 31) / 32;
    const int nscan  = (N_NODES + 1023) / 1024;
    const int ncb    = NBUCK2 * NEB;
    const int nscan2 = (ncb + 1023) / 1024;

    // BN(x) stats -> fold affine into Wf -> h = relu(x @ Wf' + bf')  (bf16 out)
    hipMemsetAsync(statsX, 0, 2 * F_IN * 4, stream);
    colstats4_kernel<F_IN><<<256, 256, 0, stream>>>(x, statsX, N_NODES);
    finalize_bn_kernel<<<1, F_IN, 0, stream>>>(statsX, bn_feat_w, bn_feat_b, acX, F_IN, 1.0f / N_NODES);
    wprep_kernel<F_IN, true><<<(F_IN * 96 + 255) / 256, 256, 0, stream>>>(Wf, bfv, acX, wtF, bFmod);
    mmx_kernel<F_IN, true, false, true, false, true, false><<<gridF, 256, 0, stream>>>(x, wtF, bFmod, nullptr, hb, nullptr, nullptr, N_NODES);

    // weight preps for the 3 GIN layers
    for (int l = 0; l < 3; l++) {
        wprep_kernel<HDIM, false><<<(HDIM * 96 + 255) / 256, 256, 0, stream>>>((const float*)d_in[15 + 6 * l], (const float*)d_in[16 + 6 * l], nullptr, wt1[l], b1mod[l]);
        wprep_kernel<HDIM, false><<<(HDIM * 96 + 255) / 256, 256, 0, stream>>>((const float*)d_in[19 + 6 * l], (const float*)d_in[20 + 6 * l], nullptr, wt2[l], b2mod[l]);
    }

    // CSR build (partitioned 2-pass)
    hipMemsetAsync(deg, 0, (size_t)N_NODES * 4, stream);
    hist_kernel<<<(N_EDGES + 255) / 256, 256, 0, stream>>>(dstp, deg, N_EDGES);
    scan1_kernel<<<nscan, 1024, 0, stream>>>(deg, stmp, spart, N_NODES);
    scan2_kernel<<<1, 64, 0, stream>>>(spart, nscan);
    scan3_rowptr_kernel<<<nscan, 1024, 0, stream>>>(stmp, spart, deg, row_ptr, N_NODES);
    count_kernel<<<NEB, 256, 0, stream>>>(dstp, cnt);
    scan1_kernel<<<nscan2, 1024, 0, stream>>>(cnt, stmp2, spart2, ncb);
    scan2_kernel<<<1, 64, 0, stream>>>(spart2, nscan2);
    scan3_kernel<<<nscan2, 1024, 0, stream>>>(stmp2, spart2, ofs, ncb);
    distribute_kernel<<<NEB, 256, 0, stream>>>(srcp, dstp, ofs, ebuf);
    bucket_fill_kernel<<<NBUCK2, 256, 0, stream>>>(ebuf, ofs, row_ptr, csr);

    hipMemsetAsync(g, 0, (size_t)N_GRAPHS * HDIM * 4, stream);

    for (int l = 0; l < 3; l++) {
        const float* bw = (const float*)d_in[17 + 6 * l];
        const float* bb = (const float*)d_in[18 + 6 * l];
        // m = h + sum_nbr(h)  (bf16 in/out)
        agg_kernel<<<(N_NODES + 7) / 8, 192, 0, stream>>>(hb, row_ptr, csr, mb, N_NODES);
        // t = m @ W1 + b1 (bf16 in/out, in-place on mb), fused f32 stats(t)
        hipMemsetAsync(statsT, 0, 2 * HDIM * 4, stream);
        mmx_kernel<HDIM, false, false, false, true, true, false><<<grid96, 256, 0, stream>>>(mb, wt1[l], b1mod[l], nullptr, mb, statsT, nullptr, N_NODES);
        finalize_bn_kernel<<<1, HDIM, 0, stream>>>(statsT, bw, bb, acT, HDIM, 1.0f / N_NODES);
        // h = relu( relu(BN(t)) @ W2 + b2 ): layers 0,1 -> bf16 h; layer 2 -> fused pool
        if (l < 2) {
            mmx_kernel<HDIM, false, true, true, false, true, false><<<grid96, 256, 0, stream>>>(mb, wt2[l], b2mod[l], acT, hb, nullptr, nullptr, N_NODES);
        } else {
            mmx_kernel<HDIM, false, true, true, false, false, true><<<grid96, 256, 0, stream>>>(mb, wt2[l], b2mod[l], acT, g, nullptr, batch, N_NODES);
        }
    }

    // g1 = relu(BN_fc(g) @ Wl + bl), fused stats(g1)
    hipMemsetAsync(statsG, 0, 2 * HDIM * 4, stream);
    colstats_kernel<HDIM><<<64, 2 * HDIM, 0, stream>>>(g, statsG, N_GRAPHS);
    finalize_bn_kernel<<<1, HDIM, 0, stream>>>(statsG, bn_fc_w, bn_fc_b, acG, HDIM, 1.0f / N_GRAPHS);
    hipMemsetAsync(statsG1, 0, 2 * HDIM * 4, stream);
    mm_kernel<HDIM, true, false, true, true><<<gridG, 192, 0, stream>>>(g, Wl, bl, acG, g1, statsG1, N_GRAPHS);
    finalize_bn_kernel<<<1, HDIM, 0, stream>>>(statsG1, bn_hid_w, bn_hid_b, acHid, HDIM, 1.0f / N_GRAPHS);

    head_kernel<<<2, 256, 0, stream>>>(g1, acHid, Wc, bc, out, N_GRAPHS);
}

// Round 8
// 371.539 us; speedup vs baseline: 1.5479x; 1.0476x over previous
//
#include <hip/hip_runtime.h>

#define N_NODES 50000
#define N_EDGES 800000
#define N_GRAPHS 512
#define F_IN 128
#define HDIM 96
#define NCLS 10
#define BN_EPS 1e-5f

// partitioned CSR fill geometry
#define NPB 128                            // nodes per bucket
#define NBUCK2 ((N_NODES + NPB - 1) / NPB) // 391 buckets
#define NEB 128                            // edge-partition blocks
#define EPB ((N_EDGES + NEB - 1) / NEB)    // 6250 edges per block

typedef unsigned int u32;
typedef unsigned short u16;
typedef __attribute__((ext_vector_type(8))) short bf16x8;
typedef __attribute__((ext_vector_type(4))) float f32x4;

__device__ __forceinline__ u16 f2bf(float f) {
    u32 u = __float_as_uint(f);
    u32 r = (u + 0x7fffu + ((u >> 16) & 1u)) >> 16;   // RNE
    return (u16)r;
}
__device__ __forceinline__ float bflo(u32 w) { return __uint_as_float(w << 16); }
__device__ __forceinline__ float bfhi(u32 w) { return __uint_as_float(w & 0xffff0000u); }

// ---------------- column stats, vectorized (sum, sumsq) ----------------
template<int NC>
__global__ __launch_bounds__(256) void colstats4_kernel(const float* __restrict__ in,
                                                        float* __restrict__ stats,
                                                        int nrows) {
    constexpr int CG  = NC / 4;
    constexpr int RPB = 256 / CG;
    const int cg = threadIdx.x % CG;
    const int rg = threadIdx.x / CG;
    float4 s = make_float4(0.f, 0.f, 0.f, 0.f);
    float4 q = make_float4(0.f, 0.f, 0.f, 0.f);
    for (int r = blockIdx.x * RPB + rg; r < nrows; r += gridDim.x * RPB) {
        float4 v = *(const float4*)&in[(size_t)r * NC + cg * 4];
        s.x += v.x; s.y += v.y; s.z += v.z; s.w += v.w;
        q.x += v.x * v.x; q.y += v.y * v.y; q.z += v.z * v.z; q.w += v.w * v.w;
    }
    __shared__ float ss[RPB][NC], sq[RPB][NC];
    *(float4*)&ss[rg][cg * 4] = s;
    *(float4*)&sq[rg][cg * 4] = q;
    __syncthreads();
    if (threadIdx.x < NC) {
        float a = 0.f, b = 0.f;
        #pragma unroll
        for (int r = 0; r < RPB; r++) { a += ss[r][threadIdx.x]; b += sq[r][threadIdx.x]; }
        atomicAdd(&stats[threadIdx.x],      a);
        atomicAdd(&stats[NC + threadIdx.x], b);
    }
}

// small-row column stats (graph-level tensors)
template<int NC>
__global__ __launch_bounds__(2*NC) void colstats_kernel(const float* __restrict__ in,
                                                        float* __restrict__ stats,
                                                        int nrows) {
    const int col  = threadIdx.x % NC;
    const int half = threadIdx.x / NC;
    float s = 0.f, ss = 0.f;
    for (int r = blockIdx.x * 2 + half; r < nrows; r += gridDim.x * 2) {
        float v = in[(size_t)r * NC + col];
        s += v; ss += v * v;
    }
    __shared__ float shs[2][NC], shq[2][NC];
    shs[half][col] = s; shq[half][col] = ss;
    __syncthreads();
    if (half == 0) {
        atomicAdd(&stats[col],      s  + shs[1][col]);
        atomicAdd(&stats[NC + col], ss + shq[1][col]);
    }
}

__global__ void finalize_bn_kernel(const float* __restrict__ stats,
                                   const float* __restrict__ w,
                                   const float* __restrict__ b,
                                   float* __restrict__ ac, int ncols, float inv_n) {
    int k = blockIdx.x * blockDim.x + threadIdx.x;
    if (k < ncols) {
        float mu  = stats[k] * inv_n;
        float var = stats[ncols + k] * inv_n - mu * mu;
        float a   = w[k] * rsqrtf(var + BN_EPS);
        ac[k]         = a;
        ac[ncols + k] = b[k] - mu * a;
    }
}

// ---------------- weight prep ----------------
template<int KDIM, bool FOLD>
__global__ __launch_bounds__(256) void wprep_kernel(const float* __restrict__ W,
                                                    const float* __restrict__ bias,
                                                    const float* __restrict__ ac,
                                                    u16* __restrict__ wtb,
                                                    float* __restrict__ bmod) {
    int i = blockIdx.x * 256 + threadIdx.x;
    if (i < KDIM * 96) {
        int k = i / 96, n = i % 96;
        float v = W[i];
        if constexpr (FOLD) v *= ac[k];
        wtb[n * KDIM + k] = f2bf(v);
    }
    if (blockIdx.x == 0 && threadIdx.x < 96) {
        float b = bias[threadIdx.x];
        if constexpr (FOLD) {
            for (int k = 0; k < KDIM; k++) b += ac[KDIM + k] * W[k * 96 + threadIdx.x];
        }
        bmod[threadIdx.x] = b;
    }
}

// ---------------- CSR build (by dst), partitioned 2-pass ----------------
__global__ __launch_bounds__(1024) void scan1_kernel(const int* __restrict__ in,
                                                     int* __restrict__ tmp,
                                                     int* __restrict__ partial, int n) {
    __shared__ int sh[1024];
    const int i = blockIdx.x * 1024 + threadIdx.x;
    const int d = (i < n) ? in[i] : 0;
    sh[threadIdx.x] = d;
    __syncthreads();
    for (int off = 1; off < 1024; off <<= 1) {
        int v = 0;
        if (threadIdx.x >= off) v = sh[threadIdx.x - off];
        __syncthreads();
        sh[threadIdx.x] += v;
        __syncthreads();
    }
    if (i < n) tmp[i] = sh[threadIdx.x] - d;
    if (threadIdx.x == 1023) partial[blockIdx.x] = sh[1023];
}

__global__ void scan2_kernel(int* __restrict__ partial, int nparts) {
    const int t = threadIdx.x;
    int d = (t < nparts) ? partial[t] : 0;
    int v = d;
    for (int off = 1; off < 64; off <<= 1) {
        int u = __shfl_up(v, off, 64);
        if (t >= off) v += u;
    }
    if (t < nparts) partial[t] = v - d;
}

__global__ __launch_bounds__(1024) void scan3_rowptr_kernel(const int* __restrict__ tmp,
                                                            const int* __restrict__ partial,
                                                            const int* __restrict__ deg,
                                                            int* __restrict__ row_ptr, int n) {
    const int i = blockIdx.x * 1024 + threadIdx.x;
    if (i < n) {
        int v = tmp[i] + partial[blockIdx.x];
        row_ptr[i] = v;
        if (i == n - 1) row_ptr[n] = v + deg[i];
    }
}

__global__ __launch_bounds__(1024) void scan3_kernel(const int* __restrict__ tmp,
                                                     const int* __restrict__ partial,
                                                     int* __restrict__ out, int n) {
    const int i = blockIdx.x * 1024 + threadIdx.x;
    if (i < n) out[i] = tmp[i] + partial[blockIdx.x];
}

// one pass over dst: per-node degree (global atomics) + per-(bucket,block) counts (LDS)
__global__ __launch_bounds__(256) void count_kernel(const int* __restrict__ dst,
                                                    int* __restrict__ deg,
                                                    int* __restrict__ cnt /*[NBUCK2][NEB]*/) {
    __shared__ int lc[NBUCK2];
    for (int i = threadIdx.x; i < NBUCK2; i += 256) lc[i] = 0;
    __syncthreads();
    const int lo = blockIdx.x * EPB;
    const int hi = min(lo + EPB, N_EDGES);
    for (int e = lo + threadIdx.x; e < hi; e += 256) {
        int d = dst[e];
        atomicAdd(&lc[d / NPB], 1);
        atomicAdd(&deg[d], 1);
    }
    __syncthreads();
    for (int i = threadIdx.x; i < NBUCK2; i += 256)
        cnt[i * NEB + blockIdx.x] = lc[i];
}

// distribute: packed (src<<7 | local_dst) into block-private sub-streams
__global__ __launch_bounds__(256) void distribute_kernel(const int* __restrict__ src,
                                                         const int* __restrict__ dst,
                                                         const int* __restrict__ ofs,
                                                         u32* __restrict__ ebuf) {
    __shared__ int lofs[NBUCK2];
    for (int i = threadIdx.x; i < NBUCK2; i += 256) lofs[i] = ofs[i * NEB + blockIdx.x];
    __syncthreads();
    const int lo = blockIdx.x * EPB;
    const int hi = min(lo + EPB, N_EDGES);
    for (int e = lo + threadIdx.x; e < hi; e += 256) {
        int d = dst[e];
        int q = atomicAdd(&lofs[d / NPB], 1);
        ebuf[q] = ((u32)src[e] << 7) | (u32)(d & (NPB - 1));
    }
}

__global__ __launch_bounds__(256) void bucket_fill_kernel(const u32* __restrict__ ebuf,
                                                          const int* __restrict__ ofs,
                                                          const int* __restrict__ row_ptr,
                                                          int* __restrict__ csr) {
    __shared__ int cur[NPB];
    const int p    = blockIdx.x;
    const int base = p * NPB;
    const int nn   = min(NPB, N_NODES - base);
    for (int i = threadIdx.x; i < nn; i += 256) cur[i] = row_ptr[base + i];
    __syncthreads();
    const int e0 = ofs[p * NEB];
    const int e1 = (p + 1 < NBUCK2) ? ofs[(p + 1) * NEB] : N_EDGES;
    for (int e = e0 + threadIdx.x; e < e1; e += 256) {
        u32 v = ebuf[e];
        int pos = atomicAdd(&cur[v & (NPB - 1)], 1);
        csr[pos] = (int)(v >> 7);
    }
}

// ---------------- GIN aggregation: m[n] = h[n] + sum_nbr h[s]  (bf16 in/out) ----------------
// 12 threads/node, uint4 (8 bf16 = 16B) gathers, 8-deep edge unroll.
__global__ __launch_bounds__(192) void agg_kernel(const u16* __restrict__ hb,
                                                  const int* __restrict__ row_ptr,
                                                  const int* __restrict__ csr,
                                                  u16* __restrict__ mb, int n) {
    const int jj   = threadIdx.x % 12;       // columns jj*8 .. jj*8+7
    const int node = blockIdx.x * 16 + threadIdx.x / 12;
    if (node >= n) return;
    const int p0 = row_ptr[node], p1 = row_ptr[node + 1];
    uint4 sv = *(const uint4*)&hb[(size_t)node * 96 + jj * 8];
    float a0 = bflo(sv.x), a1 = bfhi(sv.x), a2 = bflo(sv.y), a3 = bfhi(sv.y);
    float a4 = bflo(sv.z), a5 = bfhi(sv.z), a6 = bflo(sv.w), a7 = bfhi(sv.w);
    int p = p0;
    for (; p + 8 <= p1; p += 8) {
        int s0 = csr[p],     s1 = csr[p + 1], s2 = csr[p + 2], s3 = csr[p + 3];
        int s4 = csr[p + 4], s5 = csr[p + 5], s6 = csr[p + 6], s7 = csr[p + 7];
        uint4 v0 = *(const uint4*)&hb[(size_t)s0 * 96 + jj * 8];
        uint4 v1 = *(const uint4*)&hb[(size_t)s1 * 96 + jj * 8];
        uint4 v2 = *(const uint4*)&hb[(size_t)s2 * 96 + jj * 8];
        uint4 v3 = *(const uint4*)&hb[(size_t)s3 * 96 + jj * 8];
        uint4 v4 = *(const uint4*)&hb[(size_t)s4 * 96 + jj * 8];
        uint4 v5 = *(const uint4*)&hb[(size_t)s5 * 96 + jj * 8];
        uint4 v6 = *(const uint4*)&hb[(size_t)s6 * 96 + jj * 8];
        uint4 v7 = *(const uint4*)&hb[(size_t)s7 * 96 + jj * 8];
        a0 += ((bflo(v0.x) + bflo(v1.x)) + (bflo(v2.x) + bflo(v3.x)))
            + ((bflo(v4.x) + bflo(v5.x)) + (bflo(v6.x) + bflo(v7.x)));
        a1 += ((bfhi(v0.x) + bfhi(v1.x)) + (bfhi(v2.x) + bfhi(v3.x)))
            + ((bfhi(v4.x) + bfhi(v5.x)) + (bfhi(v6.x) + bfhi(v7.x)));
        a2 += ((bflo(v0.y) + bflo(v1.y)) + (bflo(v2.y) + bflo(v3.y)))
            + ((bflo(v4.y) + bflo(v5.y)) + (bflo(v6.y) + bflo(v7.y)));
        a3 += ((bfhi(v0.y) + bfhi(v1.y)) + (bfhi(v2.y) + bfhi(v3.y)))
            + ((bfhi(v4.y) + bfhi(v5.y)) + (bfhi(v6.y) + bfhi(v7.y)));
        a4 += ((bflo(v0.z) + bflo(v1.z)) + (bflo(v2.z) + bflo(v3.z)))
            + ((bflo(v4.z) + bflo(v5.z)) + (bflo(v6.z) + bflo(v7.z)));
        a5 += ((bfhi(v0.z) + bfhi(v1.z)) + (bfhi(v2.z) + bfhi(v3.z)))
            + ((bfhi(v4.z) + bfhi(v5.z)) + (bfhi(v6.z) + bfhi(v7.z)));
        a6 += ((bflo(v0.w) + bflo(v1.w)) + (bflo(v2.w) + bflo(v3.w)))
            + ((bflo(v4.w) + bflo(v5.w)) + (bflo(v6.w) + bflo(v7.w)));
        a7 += ((bfhi(v0.w) + bfhi(v1.w)) + (bfhi(v2.w) + bfhi(v3.w)))
            + ((bfhi(v4.w) + bfhi(v5.w)) + (bfhi(v6.w) + bfhi(v7.w)));
    }
    for (; p + 4 <= p1; p += 4) {
        int s0 = csr[p], s1 = csr[p + 1], s2 = csr[p + 2], s3 = csr[p + 3];
        uint4 v0 = *(const uint4*)&hb[(size_t)s0 * 96 + jj * 8];
        uint4 v1 = *(const uint4*)&hb[(size_t)s1 * 96 + jj * 8];
        uint4 v2 = *(const uint4*)&hb[(size_t)s2 * 96 + jj * 8];
        uint4 v3 = *(const uint4*)&hb[(size_t)s3 * 96 + jj * 8];
        a0 += (bflo(v0.x) + bflo(v1.x)) + (bflo(v2.x) + bflo(v3.x));
        a1 += (bfhi(v0.x) + bfhi(v1.x)) + (bfhi(v2.x) + bfhi(v3.x));
        a2 += (bflo(v0.y) + bflo(v1.y)) + (bflo(v2.y) + bflo(v3.y));
        a3 += (bfhi(v0.y) + bfhi(v1.y)) + (bfhi(v2.y) + bfhi(v3.y));
        a4 += (bflo(v0.z) + bflo(v1.z)) + (bflo(v2.z) + bflo(v3.z));
        a5 += (bfhi(v0.z) + bfhi(v1.z)) + (bfhi(v2.z) + bfhi(v3.z));
        a6 += (bflo(v0.w) + bflo(v1.w)) + (bflo(v2.w) + bflo(v3.w));
        a7 += (bfhi(v0.w) + bfhi(v1.w)) + (bfhi(v2.w) + bfhi(v3.w));
    }
    for (; p < p1; p++) {
        int s = csr[p];
        uint4 v = *(const uint4*)&hb[(size_t)s * 96 + jj * 8];
        a0 += bflo(v.x); a1 += bfhi(v.x); a2 += bflo(v.y); a3 += bfhi(v.y);
        a4 += bflo(v.z); a5 += bfhi(v.z); a6 += bflo(v.w); a7 += bfhi(v.w);
    }
    uint4 o;
    o.x = (u32)f2bf(a0) | ((u32)f2bf(a1) << 16);
    o.y = (u32)f2bf(a2) | ((u32)f2bf(a3) << 16);
    o.z = (u32)f2bf(a4) | ((u32)f2bf(a5) << 16);
    o.w = (u32)f2bf(a6) | ((u32)f2bf(a7) << 16);
    *(uint4*)&mb[(size_t)node * 96 + jj * 8] = o;
}

// ---------------- MFMA matmul: out[nrows][96] = f(in[nrows][KDIM]) @ W + bias ----------------
template<int KDIM, bool IN_F32, bool IN_AFF_RELU, bool OUT_RELU, bool STATS, bool OUT_BF16, bool POOL>
__global__ __launch_bounds__(256) void mmx_kernel(const void* __restrict__ in_,
                                                  const u16* __restrict__ wt,   // [96][KDIM] bf16
                                                  const float* __restrict__ bias,
                                                  const float* __restrict__ ac,
                                                  void* __restrict__ out_,
                                                  float* __restrict__ stats,
                                                  const int* __restrict__ batch,
                                                  int nrows) {
    constexpr int KP = KDIM + 8;
    constexpr int KB = KDIM / 32;
    __shared__ u16 wlds[96 * KP];
    __shared__ u16 alds[64 * KP];
    __shared__ float sred[2][4][96];
    const int tid = threadIdx.x;

    for (int i = tid; i < 96 * (KDIM / 8); i += 256) {
        int nn = i / (KDIM / 8), c8 = i % (KDIM / 8);
        *(uint4*)&wlds[nn * KP + c8 * 8] = *(const uint4*)&wt[nn * KDIM + c8 * 8];
    }

    const int w    = tid >> 6;
    const int lane = tid & 63;
    const int r16  = lane & 15;
    const int kg   = lane >> 4;
    const int m0   = w * 16;
    float bn[6];
    #pragma unroll
    for (int nt = 0; nt < 6; nt++) bn[nt] = bias[nt * 16 + r16];
    float scol[6] = {0,0,0,0,0,0}, qcol[6] = {0,0,0,0,0,0};

    const int nchunks = (nrows + 63) / 64;
    for (int chunk = blockIdx.x; chunk < nchunks; chunk += gridDim.x) {
        const int row0 = chunk * 64;
        __syncthreads();
        if constexpr (IN_F32) {
            const float* inf = (const float*)in_;
            for (int i = tid; i < 64 * (KDIM / 4); i += 256) {
                int r = i / (KDIM / 4), c4 = i % (KDIM / 4);
                int gr = row0 + r;
                float4 v = (gr < nrows) ? *(const float4*)&inf[(size_t)gr * KDIM + c4 * 4]
                                        : make_float4(0.f, 0.f, 0.f, 0.f);
                ushort4 o; o.x = f2bf(v.x); o.y = f2bf(v.y); o.z = f2bf(v.z); o.w = f2bf(v.w);
                *(ushort4*)&alds[r * KP + c4 * 4] = o;
            }
        } else {
            const u16* inb = (const u16*)in_;
            for (int i = tid; i < 64 * (KDIM / 8); i += 256) {
                int r = i / (KDIM / 8), c8 = i % (KDIM / 8);
                int gr = row0 + r;
                uint4 v = (gr < nrows) ? *(const uint4*)&inb[(size_t)gr * KDIM + c8 * 8]
                                       : make_uint4(0u, 0u, 0u, 0u);
                if constexpr (IN_AFF_RELU) {
                    u32 words[4] = {v.x, v.y, v.z, v.w};
                    #pragma unroll
                    for (int t2 = 0; t2 < 4; t2++) {
                        int k0 = c8 * 8 + t2 * 2;
                        float lo = fmaxf(bflo(words[t2]) * ac[k0]     + ac[KDIM + k0],     0.f);
                        float hi = fmaxf(bfhi(words[t2]) * ac[k0 + 1] + ac[KDIM + k0 + 1], 0.f);
                        words[t2] = (u32)f2bf(lo) | ((u32)f2bf(hi) << 16);
                    }
                    v.x = words[0]; v.y = words[1]; v.z = words[2]; v.w = words[3];
                }
                *(uint4*)&alds[r * KP + c8 * 8] = v;
            }
        }
        __syncthreads();

        bf16x8 af[KB];
        #pragma unroll
        for (int kb = 0; kb < KB; kb++)
            af[kb] = *(const bf16x8*)&alds[(m0 + r16) * KP + kb * 32 + kg * 8];

        f32x4 acc[6];
        #pragma unroll
        for (int nt = 0; nt < 6; nt++) acc[nt] = (f32x4){bn[nt], bn[nt], bn[nt], bn[nt]};
        #pragma unroll
        for (int kb = 0; kb < KB; kb++) {
            #pragma unroll
            for (int nt = 0; nt < 6; nt++) {
                bf16x8 bfr = *(const bf16x8*)&wlds[(nt * 16 + r16) * KP + kb * 32 + kg * 8];
                acc[nt] = __builtin_amdgcn_mfma_f32_16x16x32_bf16(af[kb], bfr, acc[nt], 0, 0, 0);
            }
        }

        const int gr0  = row0 + m0 + kg * 4;
        const bool full = (gr0 + 3 < nrows);
        if constexpr (POOL) {
            float* gbuf = (float*)out_;
            int bl = -1, bh = -2;
            if (full) { bl = batch[gr0]; bh = batch[gr0 + 3]; }
            #pragma unroll
            for (int nt = 0; nt < 6; nt++) {
                float v0 = acc[nt][0], v1 = acc[nt][1], v2 = acc[nt][2], v3 = acc[nt][3];
                if constexpr (OUT_RELU) {
                    v0 = fmaxf(v0, 0.f); v1 = fmaxf(v1, 0.f);
                    v2 = fmaxf(v2, 0.f); v3 = fmaxf(v3, 0.f);
                }
                const int n = nt * 16 + r16;
                if (full) {
                    if (bl == bh) {
                        atomicAdd(&gbuf[(size_t)bl * 96 + n], (v0 + v1) + (v2 + v3));
                    } else {
                        atomicAdd(&gbuf[(size_t)batch[gr0]     * 96 + n], v0);
                        atomicAdd(&gbuf[(size_t)batch[gr0 + 1] * 96 + n], v1);
                        atomicAdd(&gbuf[(size_t)batch[gr0 + 2] * 96 + n], v2);
                        atomicAdd(&gbuf[(size_t)batch[gr0 + 3] * 96 + n], v3);
                    }
                } else {
                    if (gr0     < nrows) atomicAdd(&gbuf[(size_t)batch[gr0]     * 96 + n], v0);
                    if (gr0 + 1 < nrows) atomicAdd(&gbuf[(size_t)batch[gr0 + 1] * 96 + n], v1);
                    if (gr0 + 2 < nrows) atomicAdd(&gbuf[(size_t)batch[gr0 + 2] * 96 + n], v2);
                }
            }
        } else {
            #pragma unroll
            for (int nt = 0; nt < 6; nt++) {
                float v[4] = {acc[nt][0], acc[nt][1], acc[nt][2], acc[nt][3]};
                if constexpr (OUT_RELU) {
                    #pragma unroll
                    for (int rr = 0; rr < 4; rr++) v[rr] = fmaxf(v[rr], 0.f);
                }
                const int n = nt * 16 + r16;
                #pragma unroll
                for (int rr = 0; rr < 4; rr++) {
                    const int gr = gr0 + rr;
                    if (full || gr < nrows) {
                        if constexpr (OUT_BF16) ((u16*)out_)[(size_t)gr * 96 + n] = f2bf(v[rr]);
                        else                    ((float*)out_)[(size_t)gr * 96 + n] = v[rr];
                        if constexpr (STATS) { scol[nt] += v[rr]; qcol[nt] += v[rr] * v[rr]; }
                    }
                }
            }
        }
    }

    if constexpr (STATS) {
        #pragma unroll
        for (int nt = 0; nt < 6; nt++) {
            scol[nt] += __shfl_xor(scol[nt], 16);
            scol[nt] += __shfl_xor(scol[nt], 32);
            qcol[nt] += __shfl_xor(qcol[nt], 16);
            qcol[nt] += __shfl_xor(qcol[nt], 32);
        }
        __syncthreads();
        if (kg == 0) {
            #pragma unroll
            for (int nt = 0; nt < 6; nt++) {
                sred[0][w][nt * 16 + r16] = scol[nt];
                sred[1][w][nt * 16 + r16] = qcol[nt];
            }
        }
        __syncthreads();
        if (tid < 96) {
            float a = sred[0][0][tid] + sred[0][1][tid] + sred[0][2][tid] + sred[0][3][tid];
            float b = sred[1][0][tid] + sred[1][1][tid] + sred[1][2][tid] + sred[1][3][tid];
            atomicAdd(&stats[tid],      a);
            atomicAdd(&stats[96 + tid], b);
        }
    }
}

// ---------------- f32 small matmul (G-sized tail) ----------------
template<int KDIM, bool IN_AFF, bool IN_RELU, bool OUT_RELU, bool STATS>
__global__ __launch_bounds__(192) void mm_kernel(const float* __restrict__ in,
                                                 const float* __restrict__ W,
                                                 const float* __restrict__ bias,
                                                 const float* __restrict__ ac,
                                                 float* __restrict__ out,
                                                 float* __restrict__ stats, int nrows) {
    constexpr int KG = KDIM / 4;
    __shared__ float ws[KDIM][96];
    __shared__ float xs[32][KDIM];
    const int tid = threadIdx.x;
    const int cg  = tid % 24;
    const int rg  = tid / 24;
    for (int i = tid; i < KDIM * 24; i += 192) {
        int k = i / 24, c4 = i % 24;
        *(float4*)&ws[k][c4 * 4] = *(const float4*)&W[(size_t)k * 96 + c4 * 4];
    }
    const float4 bj = *(const float4*)&bias[cg * 4];
    float s0=0,s1=0,s2=0,s3=0, q0=0,q1=0,q2=0,q3=0;
    const int nchunks = (nrows + 31) / 32;
    for (int chunk = blockIdx.x; chunk < nchunks; chunk += gridDim.x) {
        const int row0 = chunk * 32;
        __syncthreads();
        for (int i = tid; i < 32 * KG; i += 192) {
            int r = i / KG, g = i % KG;
            int gr = row0 + r;
            float4 v = make_float4(0.f, 0.f, 0.f, 0.f);
            if (gr < nrows) v = *(const float4*)&in[(size_t)gr * KDIM + g * 4];
            if constexpr (IN_AFF) {
                float4 a = *(const float4*)&ac[g * 4];
                float4 c = *(const float4*)&ac[KDIM + g * 4];
                v.x = v.x * a.x + c.x; v.y = v.y * a.y + c.y;
                v.z = v.z * a.z + c.z; v.w = v.w * a.w + c.w;
            }
            if constexpr (IN_RELU) {
                v.x = fmaxf(v.x, 0.f); v.y = fmaxf(v.y, 0.f);
                v.z = fmaxf(v.z, 0.f); v.w = fmaxf(v.w, 0.f);
            }
            *(float4*)&xs[r][4 * (g ^ (r & 7))] = v;
        }
        __syncthreads();
        float acc[4][4];
        #pragma unroll
        for (int m = 0; m < 4; m++) {
            acc[m][0] = bj.x; acc[m][1] = bj.y; acc[m][2] = bj.z; acc[m][3] = bj.w;
        }
        #pragma unroll 4
        for (int g = 0; g < KG; g++) {
            const int xi = 4 * (g ^ rg);
            float4 xv0 = *(const float4*)&xs[rg     ][xi];
            float4 xv1 = *(const float4*)&xs[rg +  8][xi];
            float4 xv2 = *(const float4*)&xs[rg + 16][xi];
            float4 xv3 = *(const float4*)&xs[rg + 24][xi];
            #pragma unroll
            for (int i = 0; i < 4; i++) {
                float4 wv = *(const float4*)&ws[g * 4 + i][cg * 4];
                float x0 = (i==0)?xv0.x:(i==1)?xv0.y:(i==2)?xv0.z:xv0.w;
                float x1 = (i==0)?xv1.x:(i==1)?xv1.y:(i==2)?xv1.z:xv1.w;
                float x2 = (i==0)?xv2.x:(i==1)?xv2.y:(i==2)?xv2.z:xv2.w;
                float x3 = (i==0)?xv3.x:(i==1)?xv3.y:(i==2)?xv3.z:xv3.w;
                acc[0][0] = fmaf(x0, wv.x, acc[0][0]); acc[0][1] = fmaf(x0, wv.y, acc[0][1]);
                acc[0][2] = fmaf(x0, wv.z, acc[0][2]); acc[0][3] = fmaf(x0, wv.w, acc[0][3]);
                acc[1][0] = fmaf(x1, wv.x, acc[1][0]); acc[1][1] = fmaf(x1, wv.y, acc[1][1]);
                acc[1][2] = fmaf(x1, wv.z, acc[1][2]); acc[1][3] = fmaf(x1, wv.w, acc[1][3]);
                acc[2][0] = fmaf(x2, wv.x, acc[2][0]); acc[2][1] = fmaf(x2, wv.y, acc[2][1]);
                acc[2][2] = fmaf(x2, wv.z, acc[2][2]); acc[2][3] = fmaf(x2, wv.w, acc[2][3]);
                acc[3][0] = fmaf(x3, wv.x, acc[3][0]); acc[3][1] = fmaf(x3, wv.y, acc[3][1]);
                acc[3][2] = fmaf(x3, wv.z, acc[3][2]); acc[3][3] = fmaf(x3, wv.w, acc[3][3]);
            }
        }
        #pragma unroll
        for (int m = 0; m < 4; m++) {
            const int gr = row0 + rg + 8 * m;
            if (gr < nrows) {
                float4 o = make_float4(acc[m][0], acc[m][1], acc[m][2], acc[m][3]);
                if constexpr (OUT_RELU) {
                    o.x = fmaxf(o.x, 0.f); o.y = fmaxf(o.y, 0.f);
                    o.z = fmaxf(o.z, 0.f); o.w = fmaxf(o.w, 0.f);
                }
                *(float4*)&out[(size_t)gr * 96 + cg * 4] = o;
                if constexpr (STATS) {
                    s0 += o.x; q0 += o.x * o.x; s1 += o.y; q1 += o.y * o.y;
                    s2 += o.z; q2 += o.z * o.z; s3 += o.w; q3 += o.w * o.w;
                }
            }
        }
    }
    if constexpr (STATS) {
        __syncthreads();
        float* rs = &xs[0][0];
        float* rq = rs + 8 * 96;
        rs[rg * 96 + cg * 4 + 0] = s0; rs[rg * 96 + cg * 4 + 1] = s1;
        rs[rg * 96 + cg * 4 + 2] = s2; rs[rg * 96 + cg * 4 + 3] = s3;
        rq[rg * 96 + cg * 4 + 0] = q0; rq[rg * 96 + cg * 4 + 1] = q1;
        rq[rg * 96 + cg * 4 + 2] = q2; rq[rg * 96 + cg * 4 + 3] = q3;
        __syncthreads();
        if (tid < 96) {
            float a = 0.f, b = 0.f;
            #pragma unroll
            for (int r = 0; r < 8; r++) { a += rs[r * 96 + tid]; b += rq[r * 96 + tid]; }
            atomicAdd(&stats[tid],      a);
            atomicAdd(&stats[96 + tid], b);
        }
    }
}

// ---------------- head ----------------
__global__ void head_kernel(const float* __restrict__ g1, const float* __restrict__ ac,
                            const float* __restrict__ Wc, const float* __restrict__ bc,
                            float* __restrict__ out, int ngraphs) {
    int gi = blockIdx.x * blockDim.x + threadIdx.x;
    if (gi >= ngraphs) return;
    float v[NCLS];
    #pragma unroll
    for (int c = 0; c < NCLS; c++) v[c] = bc[c];
    for (int k = 0; k < HDIM; k++) {
        float x = g1[(size_t)gi * HDIM + k] * ac[k] + ac[HDIM + k];
        #pragma unroll
        for (int c = 0; c < NCLS; c++) v[c] = fmaf(x, Wc[k * NCLS + c], v[c]);
    }
    float mx = v[0];
    #pragma unroll
    for (int c = 1; c < NCLS; c++) mx = fmaxf(mx, v[c]);
    float sum = 0.f;
    #pragma unroll
    for (int c = 0; c < NCLS; c++) sum += expf(v[c] - mx);
    float lse = mx + logf(sum);
    #pragma unroll
    for (int c = 0; c < NCLS; c++) out[(size_t)gi * NCLS + c] = v[c] - lse;
}

extern "C" void kernel_launch(void* const* d_in, const int* in_sizes, int n_in,
                              void* d_out, int out_size, void* d_ws, size_t ws_size,
                              hipStream_t stream) {
    const float* x         = (const float*)d_in[0];
    const int*   ei        = (const int*)  d_in[1];
    const int*   batch     = (const int*)  d_in[2];
    const float* bn_feat_w = (const float*)d_in[3];
    const float* bn_feat_b = (const float*)d_in[4];
    const float* Wf        = (const float*)d_in[5];
    const float* bfv       = (const float*)d_in[6];
    const float* bn_fc_w   = (const float*)d_in[7];
    const float* bn_fc_b   = (const float*)d_in[8];
    const float* Wl        = (const float*)d_in[9];
    const float* bl        = (const float*)d_in[10];
    const float* bn_hid_w  = (const float*)d_in[11];
    const float* bn_hid_b  = (const float*)d_in[12];
    const float* Wc        = (const float*)d_in[13];
    const float* bc        = (const float*)d_in[14];
    float* out = (float*)d_out;

    char* p = (char*)d_ws;
    auto alloc = [&](size_t bytes) { char* q = p; p += (bytes + 255) & ~(size_t)255; return q; };
    u16*   hb     = (u16*)  alloc((size_t)N_NODES * HDIM * 2);
    u16*   mb     = (u16*)  alloc((size_t)N_NODES * HDIM * 2);
    float* g      = (float*)alloc((size_t)N_GRAPHS * HDIM * 4);
    float* g1     = (float*)alloc((size_t)N_GRAPHS * HDIM * 4);
    float* statsX = (float*)alloc(2 * F_IN * 4);
    float* acX    = (float*)alloc(2 * F_IN * 4);
    float* statsT = (float*)alloc(2 * HDIM * 4);
    float* acT    = (float*)alloc(2 * HDIM * 4);
    float* statsG = (float*)alloc(2 * HDIM * 4);
    float* acG    = (float*)alloc(2 * HDIM * 4);
    float* statsG1= (float*)alloc(2 * HDIM * 4);
    float* acHid  = (float*)alloc(2 * HDIM * 4);
    u16*   wtF    = (u16*)  alloc(96 * F_IN * 2);
    float* bFmod  = (float*)alloc(96 * 4);
    u16*   wt1[3]; u16* wt2[3]; float* b1mod[3]; float* b2mod[3];
    for (int l = 0; l < 3; l++) {
        wt1[l] = (u16*)alloc(96 * HDIM * 2); b1mod[l] = (float*)alloc(96 * 4);
        wt2[l] = (u16*)alloc(96 * HDIM * 2); b2mod[l] = (float*)alloc(96 * 4);
    }
    int* deg      = (int*)alloc((size_t)N_NODES * 4);
    int* row_ptr  = (int*)alloc((size_t)(N_NODES + 1) * 4);
    int* csr      = (int*)alloc((size_t)N_EDGES * 4);
    int* stmp     = (int*)alloc((size_t)N_NODES * 4);
    int* spart    = (int*)alloc(64 * 4);
    int* cnt      = (int*)alloc((size_t)NBUCK2 * NEB * 4);
    int* ofs      = (int*)alloc((size_t)NBUCK2 * NEB * 4);
    int* stmp2    = (int*)alloc((size_t)NBUCK2 * NEB * 4);
    int* spart2   = (int*)alloc(64 * 4);
    u32* ebuf     = (u32*)alloc((size_t)N_EDGES * 4);

    const int* srcp = ei;
    const int* dstp = ei + N_EDGES;

    const int nch64  = (N_NODES + 63) / 64;
    const int gridF  = (nch64 < 768) ? nch64 : 768;
    const int grid96 = (nch64 < 1024) ? nch64 : 1024;
    const int gridG  = (N_GRAPHS + 31) / 32;
    const int nscan  = (N_NODES + 1023) / 1024;
    const int ncb    = NBUCK2 * NEB;
    const int nscan2 = (ncb + 1023) / 1024;

    // BN(x) stats -> fold affine into Wf -> h = relu(x @ Wf' + bf')  (bf16 out)
    hipMemsetAsync(statsX, 0, 2 * F_IN * 4, stream);
    colstats4_kernel<F_IN><<<256, 256, 0, stream>>>(x, statsX, N_NODES);
    finalize_bn_kernel<<<1, F_IN, 0, stream>>>(statsX, bn_feat_w, bn_feat_b, acX, F_IN, 1.0f / N_NODES);
    wprep_kernel<F_IN, true><<<(F_IN * 96 + 255) / 256, 256, 0, stream>>>(Wf, bfv, acX, wtF, bFmod);
    mmx_kernel<F_IN, true, false, true, false, true, false><<<gridF, 256, 0, stream>>>(x, wtF, bFmod, nullptr, hb, nullptr, nullptr, N_NODES);

    // weight preps for the 3 GIN layers
    for (int l = 0; l < 3; l++) {
        wprep_kernel<HDIM, false><<<(HDIM * 96 + 255) / 256, 256, 0, stream>>>((const float*)d_in[15 + 6 * l], (const float*)d_in[16 + 6 * l], nullptr, wt1[l], b1mod[l]);
        wprep_kernel<HDIM, false><<<(HDIM * 96 + 255) / 256, 256, 0, stream>>>((const float*)d_in[19 + 6 * l], (const float*)d_in[20 + 6 * l], nullptr, wt2[l], b2mod[l]);
    }

    // CSR build (partitioned 2-pass; hist fused into count)
    hipMemsetAsync(deg, 0, (size_t)N_NODES * 4, stream);
    count_kernel<<<NEB, 256, 0, stream>>>(dstp, deg, cnt);
    scan1_kernel<<<nscan, 1024, 0, stream>>>(deg, stmp, spart, N_NODES);
    scan2_kernel<<<1, 64, 0, stream>>>(spart, nscan);
    scan3_rowptr_kernel<<<nscan, 1024, 0, stream>>>(stmp, spart, deg, row_ptr, N_NODES);
    scan1_kernel<<<nscan2, 1024, 0, stream>>>(cnt, stmp2, spart2, ncb);
    scan2_kernel<<<1, 64, 0, stream>>>(spart2, nscan2);
    scan3_kernel<<<nscan2, 1024, 0, stream>>>(stmp2, spart2, ofs, ncb);
    distribute_kernel<<<NEB, 256, 0, stream>>>(srcp, dstp, ofs, ebuf);
    bucket_fill_kernel<<<NBUCK2, 256, 0, stream>>>(ebuf, ofs, row_ptr, csr);

    hipMemsetAsync(g, 0, (size_t)N_GRAPHS * HDIM * 4, stream);

    for (int l = 0; l < 3; l++) {
        const float* bw = (const float*)d_in[17 + 6 * l];
        const float* bb = (const float*)d_in[18 + 6 * l];
        // m = h + sum_nbr(h)  (bf16 in/out, 16B gathers)
        agg_kernel<<<(N_NODES + 15) / 16, 192, 0, stream>>>(hb, row_ptr, csr, mb, N_NODES);
        // t = m @ W1 + b1 (bf16 in/out, in-place on mb), fused f32 stats(t)
        hipMemsetAsync(statsT, 0, 2 * HDIM * 4, stream);
        mmx_kernel<HDIM, false, false, false, true, true, false><<<grid96, 256, 0, stream>>>(mb, wt1[l], b1mod[l], nullptr, mb, statsT, nullptr, N_NODES);
        finalize_bn_kernel<<<1, HDIM, 0, stream>>>(statsT, bw, bb, acT, HDIM, 1.0f / N_NODES);
        // h = relu( relu(BN(t)) @ W2 + b2 ): layers 0,1 -> bf16 h; layer 2 -> fused pool
        if (l < 2) {
            mmx_kernel<HDIM, false, true, true, false, true, false><<<grid96, 256, 0, stream>>>(mb, wt2[l], b2mod[l], acT, hb, nullptr, nullptr, N_NODES);
        } else {
            mmx_kernel<HDIM, false, true, true, false, false, true><<<grid96, 256, 0, stream>>>(mb, wt2[l], b2mod[l], acT, g, nullptr, batch, N_NODES);
        }
    }

    // g1 = relu(BN_fc(g) @ Wl + bl), fused stats(g1)
    hipMemsetAsync(statsG, 0, 2 * HDIM * 4, stream);
    colstats_kernel<HDIM><<<64, 2 * HDIM, 0, stream>>>(g, statsG, N_GRAPHS);
    finalize_bn_kernel<<<1, HDIM, 0, stream>>>(statsG, bn_fc_w, bn_fc_b, acG, HDIM, 1.0f / N_GRAPHS);
    hipMemsetAsync(statsG1, 0, 2 * HDIM * 4, stream);
    mm_kernel<HDIM, true, false, true, true><<<gridG, 192, 0, stream>>>(g, Wl, bl, acG, g1, statsG1, N_GRAPHS);
    finalize_bn_kernel<<<1, HDIM, 0, stream>>>(statsG1, bn_hid_w, bn_hid_b, acHid, HDIM, 1.0f / N_GRAPHS);

    head_kernel<<<2, 256, 0, stream>>>(g1, acHid, Wc, bc, out, N_GRAPHS);
}

// Round 10
// 345.377 us; speedup vs baseline: 1.6651x; 1.0758x over previous
//
#include <hip/hip_runtime.h>

#define N_NODES 50000
#define N_EDGES 800000
#define N_GRAPHS 512
#define F_IN 128
#define HDIM 96
#define NCLS 10
#define BN_EPS 1e-5f

// partitioned CSR fill geometry
#define NPB 128
#define NBUCK2 ((N_NODES + NPB - 1) / NPB) // 391 buckets
#define NEB 128
#define EPB ((N_EDGES + NEB - 1) / NEB)    // 6250 edges per block

typedef unsigned int u32;
typedef unsigned short u16;
typedef __attribute__((ext_vector_type(8))) short bf16x8;
typedef __attribute__((ext_vector_type(4))) float f32x4;

__device__ __forceinline__ u16 f2bf(float f) {
    u32 u = __float_as_uint(f);
    u32 r = (u + 0x7fffu + ((u >> 16) & 1u)) >> 16;   // RNE
    return (u16)r;
}
__device__ __forceinline__ float bflo(u32 w) { return __uint_as_float(w << 16); }
__device__ __forceinline__ float bfhi(u32 w) { return __uint_as_float(w & 0xffff0000u); }

// ---------------- column stats, vectorized ----------------
template<int NC>
__global__ __launch_bounds__(256) void colstats4_kernel(const float* __restrict__ in,
                                                        float* __restrict__ stats,
                                                        int nrows) {
    constexpr int CG  = NC / 4;
    constexpr int RPB = 256 / CG;
    const int cg = threadIdx.x % CG;
    const int rg = threadIdx.x / CG;
    float4 s = make_float4(0.f, 0.f, 0.f, 0.f);
    float4 q = make_float4(0.f, 0.f, 0.f, 0.f);
    for (int r = blockIdx.x * RPB + rg; r < nrows; r += gridDim.x * RPB) {
        float4 v = *(const float4*)&in[(size_t)r * NC + cg * 4];
        s.x += v.x; s.y += v.y; s.z += v.z; s.w += v.w;
        q.x += v.x * v.x; q.y += v.y * v.y; q.z += v.z * v.z; q.w += v.w * v.w;
    }
    __shared__ float ss[RPB][NC], sq[RPB][NC];
    *(float4*)&ss[rg][cg * 4] = s;
    *(float4*)&sq[rg][cg * 4] = q;
    __syncthreads();
    if (threadIdx.x < NC) {
        float a = 0.f, b = 0.f;
        #pragma unroll
        for (int r = 0; r < RPB; r++) { a += ss[r][threadIdx.x]; b += sq[r][threadIdx.x]; }
        atomicAdd(&stats[threadIdx.x],      a);
        atomicAdd(&stats[NC + threadIdx.x], b);
    }
}

template<int NC>
__global__ __launch_bounds__(2*NC) void colstats_kernel(const float* __restrict__ in,
                                                        float* __restrict__ stats,
                                                        int nrows) {
    const int col  = threadIdx.x % NC;
    const int half = threadIdx.x / NC;
    float s = 0.f, ss = 0.f;
    for (int r = blockIdx.x * 2 + half; r < nrows; r += gridDim.x * 2) {
        float v = in[(size_t)r * NC + col];
        s += v; ss += v * v;
    }
    __shared__ float shs[2][NC], shq[2][NC];
    shs[half][col] = s; shq[half][col] = ss;
    __syncthreads();
    if (half == 0) {
        atomicAdd(&stats[col],      s  + shs[1][col]);
        atomicAdd(&stats[NC + col], ss + shq[1][col]);
    }
}

__global__ void finalize_bn_kernel(const float* __restrict__ stats,
                                   const float* __restrict__ w,
                                   const float* __restrict__ b,
                                   float* __restrict__ ac, int ncols, float inv_n) {
    int k = blockIdx.x * blockDim.x + threadIdx.x;
    if (k < ncols) {
        float mu  = stats[k] * inv_n;
        float var = stats[ncols + k] * inv_n - mu * mu;
        float a   = w[k] * rsqrtf(var + BN_EPS);
        ac[k]         = a;
        ac[ncols + k] = b[k] - mu * a;
    }
}

// ---------------- fused weight prep: all 7 weights in one launch ----------------
#define WPF_BLOCKS 48   // ceil(128*96/256)
#define WPH_BLOCKS 36   // 96*96/256
__global__ __launch_bounds__(256) void wprep_all_kernel(
        const float* __restrict__ Wf, const float* __restrict__ bf, const float* __restrict__ acX,
        const float* __restrict__ W0a, const float* __restrict__ b0a,
        const float* __restrict__ W0b, const float* __restrict__ b0b,
        const float* __restrict__ W1a, const float* __restrict__ b1a,
        const float* __restrict__ W1b, const float* __restrict__ b1b,
        const float* __restrict__ W2a, const float* __restrict__ b2a,
        const float* __restrict__ W2b, const float* __restrict__ b2b,
        u16* __restrict__ wtF, float* __restrict__ bFm,
        u16* __restrict__ wtbase, float* __restrict__ bmbase) {
    const int tid = threadIdx.x;
    int blk = blockIdx.x;
    if (blk < WPF_BLOCKS) {
        int i = blk * 256 + tid;
        if (i < F_IN * 96) {
            int k = i / 96, n = i % 96;
            wtF[n * F_IN + k] = f2bf(Wf[i] * acX[k]);
        }
        if (blk == 0 && tid < 96) {
            float b = bf[tid];
            for (int k = 0; k < F_IN; k++) b += acX[F_IN + k] * Wf[k * 96 + tid];
            bFm[tid] = b;
        }
        return;
    }
    blk -= WPF_BLOCKS;
    const int s  = blk / WPH_BLOCKS;
    const int b2 = blk % WPH_BLOCKS;
    const float* W; const float* bias;
    switch (s) {
        case 0: W = W0a; bias = b0a; break;
        case 1: W = W0b; bias = b0b; break;
        case 2: W = W1a; bias = b1a; break;
        case 3: W = W1b; bias = b1b; break;
        case 4: W = W2a; bias = b2a; break;
        default: W = W2b; bias = b2b; break;
    }
    u16*   wtb  = wtbase + (size_t)s * 96 * HDIM;
    float* bmod = bmbase + (size_t)s * 96;
    int i = b2 * 256 + tid;
    if (i < HDIM * 96) {
        int k = i / 96, n = i % 96;
        wtb[n * HDIM + k] = f2bf(W[i]);
    }
    if (b2 == 0 && tid < 96) bmod[tid] = bias[tid];
}

// ---------------- CSR build ----------------
__global__ __launch_bounds__(1024) void scan1_kernel(const int* __restrict__ in,
                                                     int* __restrict__ tmp,
                                                     int* __restrict__ partial, int n) {
    __shared__ int sh[1024];
    const int i = blockIdx.x * 1024 + threadIdx.x;
    const int d = (i < n) ? in[i] : 0;
    sh[threadIdx.x] = d;
    __syncthreads();
    for (int off = 1; off < 1024; off <<= 1) {
        int v = 0;
        if (threadIdx.x >= off) v = sh[threadIdx.x - off];
        __syncthreads();
        sh[threadIdx.x] += v;
        __syncthreads();
    }
    if (i < n) tmp[i] = sh[threadIdx.x] - d;
    if (threadIdx.x == 1023) partial[blockIdx.x] = sh[1023];
}

__global__ __launch_bounds__(1024) void scan3_rowptr_kernel(const int* __restrict__ tmp,
                                                            const int* __restrict__ partial,
                                                            const int* __restrict__ deg,
                                                            int* __restrict__ row_ptr,
                                                            int n, int nparts) {
    __shared__ int offs;
    if (threadIdx.x < 64) {
        int v = (threadIdx.x < blockIdx.x && threadIdx.x < nparts) ? partial[threadIdx.x] : 0;
        for (int o = 32; o > 0; o >>= 1) v += __shfl_down(v, o, 64);
        if (threadIdx.x == 0) offs = v;
    }
    __syncthreads();
    const int i = blockIdx.x * 1024 + threadIdx.x;
    if (i < n) {
        int v = tmp[i] + offs;
        row_ptr[i] = v;
        if (i == n - 1) row_ptr[n] = v + deg[i];
    }
}

__global__ __launch_bounds__(1024) void scan3_kernel(const int* __restrict__ tmp,
                                                     const int* __restrict__ partial,
                                                     int* __restrict__ out,
                                                     int n, int nparts) {
    __shared__ int offs;
    if (threadIdx.x < 64) {
        int v = (threadIdx.x < blockIdx.x && threadIdx.x < nparts) ? partial[threadIdx.x] : 0;
        for (int o = 32; o > 0; o >>= 1) v += __shfl_down(v, o, 64);
        if (threadIdx.x == 0) offs = v;
    }
    __syncthreads();
    const int i = blockIdx.x * 1024 + threadIdx.x;
    if (i < n) out[i] = tmp[i] + offs;
}

__global__ __launch_bounds__(256) void count_kernel(const int* __restrict__ dst,
                                                    int* __restrict__ deg,
                                                    int* __restrict__ cnt) {
    __shared__ int lc[NBUCK2];
    for (int i = threadIdx.x; i < NBUCK2; i += 256) lc[i] = 0;
    __syncthreads();
    const int lo = blockIdx.x * EPB;
    const int hi = min(lo + EPB, N_EDGES);
    for (int e = lo + threadIdx.x; e < hi; e += 256) {
        int d = dst[e];
        atomicAdd(&lc[d / NPB], 1);
        atomicAdd(&deg[d], 1);
    }
    __syncthreads();
    for (int i = threadIdx.x; i < NBUCK2; i += 256)
        cnt[i * NEB + blockIdx.x] = lc[i];
}

__global__ __launch_bounds__(256) void distribute_kernel(const int* __restrict__ src,
                                                         const int* __restrict__ dst,
                                                         const int* __restrict__ ofs,
                                                         u32* __restrict__ ebuf) {
    __shared__ int lofs[NBUCK2];
    for (int i = threadIdx.x; i < NBUCK2; i += 256) lofs[i] = ofs[i * NEB + blockIdx.x];
    __syncthreads();
    const int lo = blockIdx.x * EPB;
    const int hi = min(lo + EPB, N_EDGES);
    for (int e = lo + threadIdx.x; e < hi; e += 256) {
        int d = dst[e];
        int q = atomicAdd(&lofs[d / NPB], 1);
        ebuf[q] = ((u32)src[e] << 7) | (u32)(d & (NPB - 1));
    }
}

__global__ __launch_bounds__(256) void bucket_fill_kernel(const u32* __restrict__ ebuf,
                                                          const int* __restrict__ ofs,
                                                          const int* __restrict__ row_ptr,
                                                          int* __restrict__ csr) {
    __shared__ int cur[NPB];
    const int p    = blockIdx.x;
    const int base = p * NPB;
    const int nn   = min(NPB, N_NODES - base);
    for (int i = threadIdx.x; i < nn; i += 256) cur[i] = row_ptr[base + i];
    __syncthreads();
    const int e0 = ofs[p * NEB];
    const int e1 = (p + 1 < NBUCK2) ? ofs[(p + 1) * NEB] : N_EDGES;
    for (int e = e0 + threadIdx.x; e < e1; e += 256) {
        u32 v = ebuf[e];
        int pos = atomicAdd(&cur[v & (NPB - 1)], 1);
        csr[pos] = (int)(v >> 7);
    }
}

// ---------------- GIN aggregation (bf16 in/out, 12 thr/node, 16B gathers) ----------------
__global__ __launch_bounds__(192) void agg_kernel(const u16* __restrict__ hb,
                                                  const int* __restrict__ row_ptr,
                                                  const int* __restrict__ csr,
                                                  u16* __restrict__ mb, int n) {
    const int jj   = threadIdx.x % 12;
    const int node = blockIdx.x * 16 + threadIdx.x / 12;
    if (node >= n) return;
    const int p0 = row_ptr[node], p1 = row_ptr[node + 1];
    uint4 sv = *(const uint4*)&hb[(size_t)node * 96 + jj * 8];
    float a0 = bflo(sv.x), a1 = bfhi(sv.x), a2 = bflo(sv.y), a3 = bfhi(sv.y);
    float a4 = bflo(sv.z), a5 = bfhi(sv.z), a6 = bflo(sv.w), a7 = bfhi(sv.w);
    int p = p0;
    for (; p + 8 <= p1; p += 8) {
        int s0 = csr[p],     s1 = csr[p + 1], s2 = csr[p + 2], s3 = csr[p + 3];
        int s4 = csr[p + 4], s5 = csr[p + 5], s6 = csr[p + 6], s7 = csr[p + 7];
        uint4 v0 = *(const uint4*)&hb[(size_t)s0 * 96 + jj * 8];
        uint4 v1 = *(const uint4*)&hb[(size_t)s1 * 96 + jj * 8];
        uint4 v2 = *(const uint4*)&hb[(size_t)s2 * 96 + jj * 8];
        uint4 v3 = *(const uint4*)&hb[(size_t)s3 * 96 + jj * 8];
        uint4 v4 = *(const uint4*)&hb[(size_t)s4 * 96 + jj * 8];
        uint4 v5 = *(const uint4*)&hb[(size_t)s5 * 96 + jj * 8];
        uint4 v6 = *(const uint4*)&hb[(size_t)s6 * 96 + jj * 8];
        uint4 v7 = *(const uint4*)&hb[(size_t)s7 * 96 + jj * 8];
        a0 += ((bflo(v0.x) + bflo(v1.x)) + (bflo(v2.x) + bflo(v3.x)))
            + ((bflo(v4.x) + bflo(v5.x)) + (bflo(v6.x) + bflo(v7.x)));
        a1 += ((bfhi(v0.x) + bfhi(v1.x)) + (bfhi(v2.x) + bfhi(v3.x)))
            + ((bfhi(v4.x) + bfhi(v5.x)) + (bfhi(v6.x) + bfhi(v7.x)));
        a2 += ((bflo(v0.y) + bflo(v1.y)) + (bflo(v2.y) + bflo(v3.y)))
            + ((bflo(v4.y) + bflo(v5.y)) + (bflo(v6.y) + bflo(v7.y)));
        a3 += ((bfhi(v0.y) + bfhi(v1.y)) + (bfhi(v2.y) + bfhi(v3.y)))
            + ((bfhi(v4.y) + bfhi(v5.y)) + (bfhi(v6.y) + bfhi(v7.y)));
        a4 += ((bflo(v0.z) + bflo(v1.z)) + (bflo(v2.z) + bflo(v3.z)))
            + ((bflo(v4.z) + bflo(v5.z)) + (bflo(v6.z) + bflo(v7.z)));
        a5 += ((bfhi(v0.z) + bfhi(v1.z)) + (bfhi(v2.z) + bfhi(v3.z)))
            + ((bfhi(v4.z) + bfhi(v5.z)) + (bfhi(v6.z) + bfhi(v7.z)));
        a6 += ((bflo(v0.w) + bflo(v1.w)) + (bflo(v2.w) + bflo(v3.w)))
            + ((bflo(v4.w) + bflo(v5.w)) + (bflo(v6.w) + bflo(v7.w)));
        a7 += ((bfhi(v0.w) + bfhi(v1.w)) + (bfhi(v2.w) + bfhi(v3.w)))
            + ((bfhi(v4.w) + bfhi(v5.w)) + (bfhi(v6.w) + bfhi(v7.w)));
    }
    for (; p + 4 <= p1; p += 4) {
        int s0 = csr[p], s1 = csr[p + 1], s2 = csr[p + 2], s3 = csr[p + 3];
        uint4 v0 = *(const uint4*)&hb[(size_t)s0 * 96 + jj * 8];
        uint4 v1 = *(const uint4*)&hb[(size_t)s1 * 96 + jj * 8];
        uint4 v2 = *(const uint4*)&hb[(size_t)s2 * 96 + jj * 8];
        uint4 v3 = *(const uint4*)&hb[(size_t)s3 * 96 + jj * 8];
        a0 += (bflo(v0.x) + bflo(v1.x)) + (bflo(v2.x) + bflo(v3.x));
        a1 += (bfhi(v0.x) + bfhi(v1.x)) + (bfhi(v2.x) + bfhi(v3.x));
        a2 += (bflo(v0.y) + bflo(v1.y)) + (bflo(v2.y) + bflo(v3.y));
        a3 += (bfhi(v0.y) + bfhi(v1.y)) + (bfhi(v2.y) + bfhi(v3.y));
        a4 += (bflo(v0.z) + bflo(v1.z)) + (bflo(v2.z) + bflo(v3.z));
        a5 += (bfhi(v0.z) + bfhi(v1.z)) + (bfhi(v2.z) + bfhi(v3.z));
        a6 += (bflo(v0.w) + bflo(v1.w)) + (bflo(v2.w) + bflo(v3.w));
        a7 += (bfhi(v0.w) + bfhi(v1.w)) + (bfhi(v2.w) + bfhi(v3.w));
    }
    for (; p < p1; p++) {
        int s = csr[p];
        uint4 v = *(const uint4*)&hb[(size_t)s * 96 + jj * 8];
        a0 += bflo(v.x); a1 += bfhi(v.x); a2 += bflo(v.y); a3 += bfhi(v.y);
        a4 += bflo(v.z); a5 += bfhi(v.z); a6 += bflo(v.w); a7 += bfhi(v.w);
    }
    uint4 o;
    o.x = (u32)f2bf(a0) | ((u32)f2bf(a1) << 16);
    o.y = (u32)f2bf(a2) | ((u32)f2bf(a3) << 16);
    o.z = (u32)f2bf(a4) | ((u32)f2bf(a5) << 16);
    o.w = (u32)f2bf(a6) | ((u32)f2bf(a7) << 16);
    *(uint4*)&mb[(size_t)node * 96 + jj * 8] = o;
}

// ---------------- MFMA matmul ----------------
// IN_F32 path now supports IN_AFF_RELU (affine+relu applied in f32 BEFORE the single
// bf16 rounding at LDS staging — removes a rounding stage vs bf16-stored t).
template<int KDIM, bool IN_F32, bool IN_AFF_RELU, bool OUT_RELU, bool STATS, bool OUT_BF16, bool POOL>
__global__ __launch_bounds__(256) void mmx_kernel(const void* __restrict__ in_,
                                                  const u16* __restrict__ wt,
                                                  const float* __restrict__ bias,
                                                  const float* __restrict__ ac,
                                                  void* __restrict__ out_,
                                                  float* __restrict__ stats,
                                                  const int* __restrict__ batch,
                                                  int nrows) {
    constexpr int KP = KDIM + 8;
    constexpr int KB = KDIM / 32;
    __shared__ u16 wlds[96 * KP];
    __shared__ u16 alds[64 * KP];
    __shared__ float sred[2][4][96];
    const int tid = threadIdx.x;

    for (int i = tid; i < 96 * (KDIM / 8); i += 256) {
        int nn = i / (KDIM / 8), c8 = i % (KDIM / 8);
        *(uint4*)&wlds[nn * KP + c8 * 8] = *(const uint4*)&wt[nn * KDIM + c8 * 8];
    }

    const int w    = tid >> 6;
    const int lane = tid & 63;
    const int r16  = lane & 15;
    const int kg   = lane >> 4;
    const int m0   = w * 16;
    float bn[6];
    #pragma unroll
    for (int nt = 0; nt < 6; nt++) bn[nt] = bias[nt * 16 + r16];
    float scol[6] = {0,0,0,0,0,0}, qcol[6] = {0,0,0,0,0,0};

    const int nchunks = (nrows + 63) / 64;
    for (int chunk = blockIdx.x; chunk < nchunks; chunk += gridDim.x) {
        const int row0 = chunk * 64;
        __syncthreads();
        if constexpr (IN_F32) {
            const float* inf = (const float*)in_;
            for (int i = tid; i < 64 * (KDIM / 4); i += 256) {
                int r = i / (KDIM / 4), c4 = i % (KDIM / 4);
                int gr = row0 + r;
                float4 v = (gr < nrows) ? *(const float4*)&inf[(size_t)gr * KDIM + c4 * 4]
                                        : make_float4(0.f, 0.f, 0.f, 0.f);
                if constexpr (IN_AFF_RELU) {
                    float4 a = *(const float4*)&ac[c4 * 4];
                    float4 c = *(const float4*)&ac[KDIM + c4 * 4];
                    v.x = fmaxf(v.x * a.x + c.x, 0.f);
                    v.y = fmaxf(v.y * a.y + c.y, 0.f);
                    v.z = fmaxf(v.z * a.z + c.z, 0.f);
                    v.w = fmaxf(v.w * a.w + c.w, 0.f);
                }
                ushort4 o; o.x = f2bf(v.x); o.y = f2bf(v.y); o.z = f2bf(v.z); o.w = f2bf(v.w);
                *(ushort4*)&alds[r * KP + c4 * 4] = o;
            }
        } else {
            const u16* inb = (const u16*)in_;
            for (int i = tid; i < 64 * (KDIM / 8); i += 256) {
                int r = i / (KDIM / 8), c8 = i % (KDIM / 8);
                int gr = row0 + r;
                uint4 v = (gr < nrows) ? *(const uint4*)&inb[(size_t)gr * KDIM + c8 * 8]
                                       : make_uint4(0u, 0u, 0u, 0u);
                if constexpr (IN_AFF_RELU) {
                    u32 words[4] = {v.x, v.y, v.z, v.w};
                    #pragma unroll
                    for (int t2 = 0; t2 < 4; t2++) {
                        int k0 = c8 * 8 + t2 * 2;
                        float lo = fmaxf(bflo(words[t2]) * ac[k0]     + ac[KDIM + k0],     0.f);
                        float hi = fmaxf(bfhi(words[t2]) * ac[k0 + 1] + ac[KDIM + k0 + 1], 0.f);
                        words[t2] = (u32)f2bf(lo) | ((u32)f2bf(hi) << 16);
                    }
                    v.x = words[0]; v.y = words[1]; v.z = words[2]; v.w = words[3];
                }
                *(uint4*)&alds[r * KP + c8 * 8] = v;
            }
        }
        __syncthreads();

        bf16x8 af[KB];
        #pragma unroll
        for (int kb = 0; kb < KB; kb++)
            af[kb] = *(const bf16x8*)&alds[(m0 + r16) * KP + kb * 32 + kg * 8];

        f32x4 acc[6];
        #pragma unroll
        for (int nt = 0; nt < 6; nt++) acc[nt] = (f32x4){bn[nt], bn[nt], bn[nt], bn[nt]};
        #pragma unroll
        for (int kb = 0; kb < KB; kb++) {
            #pragma unroll
            for (int nt = 0; nt < 6; nt++) {
                bf16x8 bfr = *(const bf16x8*)&wlds[(nt * 16 + r16) * KP + kb * 32 + kg * 8];
                acc[nt] = __builtin_amdgcn_mfma_f32_16x16x32_bf16(af[kb], bfr, acc[nt], 0, 0, 0);
            }
        }

        const int gr0  = row0 + m0 + kg * 4;
        const bool full = (gr0 + 3 < nrows);
        if constexpr (POOL) {
            float* gbuf = (float*)out_;
            int bl = -1, bh = -2;
            if (full) { bl = batch[gr0]; bh = batch[gr0 + 3]; }
            #pragma unroll
            for (int nt = 0; nt < 6; nt++) {
                float v0 = acc[nt][0], v1 = acc[nt][1], v2 = acc[nt][2], v3 = acc[nt][3];
                if constexpr (OUT_RELU) {
                    v0 = fmaxf(v0, 0.f); v1 = fmaxf(v1, 0.f);
                    v2 = fmaxf(v2, 0.f); v3 = fmaxf(v3, 0.f);
                }
                const int n = nt * 16 + r16;
                if (full) {
                    if (bl == bh) {
                        atomicAdd(&gbuf[(size_t)bl * 96 + n], (v0 + v1) + (v2 + v3));
                    } else {
                        atomicAdd(&gbuf[(size_t)batch[gr0]     * 96 + n], v0);
                        atomicAdd(&gbuf[(size_t)batch[gr0 + 1] * 96 + n], v1);
                        atomicAdd(&gbuf[(size_t)batch[gr0 + 2] * 96 + n], v2);
                        atomicAdd(&gbuf[(size_t)batch[gr0 + 3] * 96 + n], v3);
                    }
                } else {
                    if (gr0     < nrows) atomicAdd(&gbuf[(size_t)batch[gr0]     * 96 + n], v0);
                    if (gr0 + 1 < nrows) atomicAdd(&gbuf[(size_t)batch[gr0 + 1] * 96 + n], v1);
                    if (gr0 + 2 < nrows) atomicAdd(&gbuf[(size_t)batch[gr0 + 2] * 96 + n], v2);
                }
            }
        } else {
            #pragma unroll
            for (int nt = 0; nt < 6; nt++) {
                float v[4] = {acc[nt][0], acc[nt][1], acc[nt][2], acc[nt][3]};
                if constexpr (OUT_RELU) {
                    #pragma unroll
                    for (int rr = 0; rr < 4; rr++) v[rr] = fmaxf(v[rr], 0.f);
                }
                const int n = nt * 16 + r16;
                #pragma unroll
                for (int rr = 0; rr < 4; rr++) {
                    const int gr = gr0 + rr;
                    if (full || gr < nrows) {
                        if constexpr (OUT_BF16) ((u16*)out_)[(size_t)gr * 96 + n] = f2bf(v[rr]);
                        else                    ((float*)out_)[(size_t)gr * 96 + n] = v[rr];
                        if constexpr (STATS) { scol[nt] += v[rr]; qcol[nt] += v[rr] * v[rr]; }
                    }
                }
            }
        }
    }

    if constexpr (STATS) {
        #pragma unroll
        for (int nt = 0; nt < 6; nt++) {
            scol[nt] += __shfl_xor(scol[nt], 16);
            scol[nt] += __shfl_xor(scol[nt], 32);
            qcol[nt] += __shfl_xor(qcol[nt], 16);
            qcol[nt] += __shfl_xor(qcol[nt], 32);
        }
        __syncthreads();
        if (kg == 0) {
            #pragma unroll
            for (int nt = 0; nt < 6; nt++) {
                sred[0][w][nt * 16 + r16] = scol[nt];
                sred[1][w][nt * 16 + r16] = qcol[nt];
            }
        }
        __syncthreads();
        if (tid < 96) {
            float a = sred[0][0][tid] + sred[0][1][tid] + sred[0][2][tid] + sred[0][3][tid];
            float b = sred[1][0][tid] + sred[1][1][tid] + sred[1][2][tid] + sred[1][3][tid];
            atomicAdd(&stats[tid],      a);
            atomicAdd(&stats[96 + tid], b);
        }
    }
}

// ---------------- f32 small matmul (G-sized tail) ----------------
template<int KDIM, bool IN_AFF, bool IN_RELU, bool OUT_RELU, bool STATS>
__global__ __launch_bounds__(192) void mm_kernel(const float* __restrict__ in,
                                                 const float* __restrict__ W,
                                                 const float* __restrict__ bias,
                                                 const float* __restrict__ ac,
                                                 float* __restrict__ out,
                                                 float* __restrict__ stats, int nrows) {
    constexpr int KG = KDIM / 4;
    __shared__ float ws[KDIM][96];
    __shared__ float xs[32][KDIM];
    const int tid = threadIdx.x;
    const int cg  = tid % 24;
    const int rg  = tid / 24;
    for (int i = tid; i < KDIM * 24; i += 192) {
        int k = i / 24, c4 = i % 24;
        *(float4*)&ws[k][c4 * 4] = *(const float4*)&W[(size_t)k * 96 + c4 * 4];
    }
    const float4 bj = *(const float4*)&bias[cg * 4];
    float s0=0,s1=0,s2=0,s3=0, q0=0,q1=0,q2=0,q3=0;
    const int nchunks = (nrows + 31) / 32;
    for (int chunk = blockIdx.x; chunk < nchunks; chunk += gridDim.x) {
        const int row0 = chunk * 32;
        __syncthreads();
        for (int i = tid; i < 32 * KG; i += 192) {
            int r = i / KG, g = i % KG;
            int gr = row0 + r;
            float4 v = make_float4(0.f, 0.f, 0.f, 0.f);
            if (gr < nrows) v = *(const float4*)&in[(size_t)gr * KDIM + g * 4];
            if constexpr (IN_AFF) {
                float4 a = *(const float4*)&ac[g * 4];
                float4 c = *(const float4*)&ac[KDIM + g * 4];
                v.x = v.x * a.x + c.x; v.y = v.y * a.y + c.y;
                v.z = v.z * a.z + c.z; v.w = v.w * a.w + c.w;
            }
            if constexpr (IN_RELU) {
                v.x = fmaxf(v.x, 0.f); v.y = fmaxf(v.y, 0.f);
                v.z = fmaxf(v.z, 0.f); v.w = fmaxf(v.w, 0.f);
            }
            *(float4*)&xs[r][4 * (g ^ (r & 7))] = v;
        }
        __syncthreads();
        float acc[4][4];
        #pragma unroll
        for (int m = 0; m < 4; m++) {
            acc[m][0] = bj.x; acc[m][1] = bj.y; acc[m][2] = bj.z; acc[m][3] = bj.w;
        }
        #pragma unroll 4
        for (int g = 0; g < KG; g++) {
            const int xi = 4 * (g ^ rg);
            float4 xv0 = *(const float4*)&xs[rg     ][xi];
            float4 xv1 = *(const float4*)&xs[rg +  8][xi];
            float4 xv2 = *(const float4*)&xs[rg + 16][xi];
            float4 xv3 = *(const float4*)&xs[rg + 24][xi];
            #pragma unroll
            for (int i = 0; i < 4; i++) {
                float4 wv = *(const float4*)&ws[g * 4 + i][cg * 4];
                float x0 = (i==0)?xv0.x:(i==1)?xv0.y:(i==2)?xv0.z:xv0.w;
                float x1 = (i==0)?xv1.x:(i==1)?xv1.y:(i==2)?xv1.z:xv1.w;
                float x2 = (i==0)?xv2.x:(i==1)?xv2.y:(i==2)?xv2.z:xv2.w;
                float x3 = (i==0)?xv3.x:(i==1)?xv3.y:(i==2)?xv3.z:xv3.w;
                acc[0][0] = fmaf(x0, wv.x, acc[0][0]); acc[0][1] = fmaf(x0, wv.y, acc[0][1]);
                acc[0][2] = fmaf(x0, wv.z, acc[0][2]); acc[0][3] = fmaf(x0, wv.w, acc[0][3]);
                acc[1][0] = fmaf(x1, wv.x, acc[1][0]); acc[1][1] = fmaf(x1, wv.y, acc[1][1]);
                acc[1][2] = fmaf(x1, wv.z, acc[1][2]); acc[1][3] = fmaf(x1, wv.w, acc[1][3]);
                acc[2][0] = fmaf(x2, wv.x, acc[2][0]); acc[2][1] = fmaf(x2, wv.y, acc[2][1]);
                acc[2][2] = fmaf(x2, wv.z, acc[2][2]); acc[2][3] = fmaf(x2, wv.w, acc[2][3]);
                acc[3][0] = fmaf(x3, wv.x, acc[3][0]); acc[3][1] = fmaf(x3, wv.y, acc[3][1]);
                acc[3][2] = fmaf(x3, wv.z, acc[3][2]); acc[3][3] = fmaf(x3, wv.w, acc[3][3]);
            }
        }
        #pragma unroll
        for (int m = 0; m < 4; m++) {
            const int gr = row0 + rg + 8 * m;
            if (gr < nrows) {
                float4 o = make_float4(acc[m][0], acc[m][1], acc[m][2], acc[m][3]);
                if constexpr (OUT_RELU) {
                    o.x = fmaxf(o.x, 0.f); o.y = fmaxf(o.y, 0.f);
                    o.z = fmaxf(o.z, 0.f); o.w = fmaxf(o.w, 0.f);
                }
                *(float4*)&out[(size_t)gr * 96 + cg * 4] = o;
                if constexpr (STATS) {
                    s0 += o.x; q0 += o.x * o.x; s1 += o.y; q1 += o.y * o.y;
                    s2 += o.z; q2 += o.z * o.z; s3 += o.w; q3 += o.w * o.w;
                }
            }
        }
    }
    if constexpr (STATS) {
        __syncthreads();
        float* rs = &xs[0][0];
        float* rq = rs + 8 * 96;
        rs[rg * 96 + cg * 4 + 0] = s0; rs[rg * 96 + cg * 4 + 1] = s1;
        rs[rg * 96 + cg * 4 + 2] = s2; rs[rg * 96 + cg * 4 + 3] = s3;
        rq[rg * 96 + cg * 4 + 0] = q0; rq[rg * 96 + cg * 4 + 1] = q1;
        rq[rg * 96 + cg * 4 + 2] = q2; rq[rg * 96 + cg * 4 + 3] = q3;
        __syncthreads();
        if (tid < 96) {
            float a = 0.f, b = 0.f;
            #pragma unroll
            for (int r = 0; r < 8; r++) { a += rs[r * 96 + tid]; b += rq[r * 96 + tid]; }
            atomicAdd(&stats[tid],      a);
            atomicAdd(&stats[96 + tid], b);
        }
    }
}

// ---------------- head ----------------
__global__ void head_kernel(const float* __restrict__ g1, const float* __restrict__ ac,
                            const float* __restrict__ Wc, const float* __restrict__ bc,
                            float* __restrict__ out, int ngraphs) {
    int gi = blockIdx.x * blockDim.x + threadIdx.x;
    if (gi >= ngraphs) return;
    float v[NCLS];
    #pragma unroll
    for (int c = 0; c < NCLS; c++) v[c] = bc[c];
    for (int k = 0; k < HDIM; k++) {
        float x = g1[(size_t)gi * HDIM + k] * ac[k] + ac[HDIM + k];
        #pragma unroll
        for (int c = 0; c < NCLS; c++) v[c] = fmaf(x, Wc[k * NCLS + c], v[c]);
    }
    float mx = v[0];
    #pragma unroll
    for (int c = 1; c < NCLS; c++) mx = fmaxf(mx, v[c]);
    float sum = 0.f;
    #pragma unroll
    for (int c = 0; c < NCLS; c++) sum += expf(v[c] - mx);
    float lse = mx + logf(sum);
    #pragma unroll
    for (int c = 0; c < NCLS; c++) out[(size_t)gi * NCLS + c] = v[c] - lse;
}

extern "C" void kernel_launch(void* const* d_in, const int* in_sizes, int n_in,
                              void* d_out, int out_size, void* d_ws, size_t ws_size,
                              hipStream_t stream) {
    const float* x         = (const float*)d_in[0];
    const int*   ei        = (const int*)  d_in[1];
    const int*   batch     = (const int*)  d_in[2];
    const float* bn_feat_w = (const float*)d_in[3];
    const float* bn_feat_b = (const float*)d_in[4];
    const float* Wf        = (const float*)d_in[5];
    const float* bfv       = (const float*)d_in[6];
    const float* bn_fc_w   = (const float*)d_in[7];
    const float* bn_fc_b   = (const float*)d_in[8];
    const float* Wl        = (const float*)d_in[9];
    const float* bl        = (const float*)d_in[10];
    const float* bn_hid_w  = (const float*)d_in[11];
    const float* bn_hid_b  = (const float*)d_in[12];
    const float* Wc        = (const float*)d_in[13];
    const float* bc        = (const float*)d_in[14];
    float* out = (float*)d_out;

    char* p = (char*)d_ws;
    auto alloc = [&](size_t bytes) { char* q = p; p += (bytes + 255) & ~(size_t)255; return q; };

    // ---- zero-region (ONE memset) ----
    char* zbase   = p;
    float* statsX = (float*)alloc(2 * F_IN * 4);
    float* statsT0= (float*)alloc(2 * HDIM * 4);
    float* statsT1= (float*)alloc(2 * HDIM * 4);
    float* statsT2= (float*)alloc(2 * HDIM * 4);
    float* statsG = (float*)alloc(2 * HDIM * 4);
    float* statsG1= (float*)alloc(2 * HDIM * 4);
    int*   deg    = (int*)  alloc((size_t)N_NODES * 4);
    float* g      = (float*)alloc((size_t)N_GRAPHS * HDIM * 4);
    size_t zsize  = (size_t)(p - zbase);
    float* statsT[3] = {statsT0, statsT1, statsT2};

    u16*   hb     = (u16*)  alloc((size_t)N_NODES * HDIM * 2);
    u16*   mb     = (u16*)  alloc((size_t)N_NODES * HDIM * 2);
    float* tf     = (float*)alloc((size_t)N_NODES * HDIM * 4);   // f32 t (mm1 out)
    float* g1     = (float*)alloc((size_t)N_GRAPHS * HDIM * 4);
    float* acX    = (float*)alloc(2 * F_IN * 4);
    float* acT    = (float*)alloc(2 * HDIM * 4);
    float* acG    = (float*)alloc(2 * HDIM * 4);
    float* acHid  = (float*)alloc(2 * HDIM * 4);
    u16*   wtF    = (u16*)  alloc(96 * F_IN * 2);
    float* bFmod  = (float*)alloc(96 * 4);
    u16*   wtH    = (u16*)  alloc((size_t)6 * 96 * HDIM * 2);
    float* bmH    = (float*)alloc((size_t)6 * 96 * 4);
    int* row_ptr  = (int*)alloc((size_t)(N_NODES + 1) * 4);
    int* csr      = (int*)alloc((size_t)N_EDGES * 4);
    int* stmp     = (int*)alloc((size_t)N_NODES * 4);
    int* spart    = (int*)alloc(64 * 4);
    int* cnt      = (int*)alloc((size_t)NBUCK2 * NEB * 4);
    int* ofs      = (int*)alloc((size_t)NBUCK2 * NEB * 4);
    int* stmp2    = (int*)alloc((size_t)NBUCK2 * NEB * 4);
    int* spart2   = (int*)alloc(64 * 4);
    u32* ebuf     = (u32*)alloc((size_t)N_EDGES * 4);

    const int* srcp = ei;
    const int* dstp = ei + N_EDGES;

    const int nch64  = (N_NODES + 63) / 64;
    const int gridF  = (nch64 < 768) ? nch64 : 768;
    const int grid96 = (nch64 < 1024) ? nch64 : 1024;
    const int gridG  = (N_GRAPHS + 31) / 32;
    const int nscan  = (N_NODES + 1023) / 1024;
    const int ncb    = NBUCK2 * NEB;
    const int nscan2 = (ncb + 1023) / 1024;

    hipMemsetAsync(zbase, 0, zsize, stream);

    // BN(x) stats -> fold into Wf -> h = relu(x @ Wf' + bf')  (bf16 out)
    colstats4_kernel<F_IN><<<256, 256, 0, stream>>>(x, statsX, N_NODES);
    finalize_bn_kernel<<<1, F_IN, 0, stream>>>(statsX, bn_feat_w, bn_feat_b, acX, F_IN, 1.0f / N_NODES);
    wprep_all_kernel<<<WPF_BLOCKS + 6 * WPH_BLOCKS, 256, 0, stream>>>(
        Wf, bfv, acX,
        (const float*)d_in[15], (const float*)d_in[16],
        (const float*)d_in[19], (const float*)d_in[20],
        (const float*)d_in[21], (const float*)d_in[22],
        (const float*)d_in[25], (const float*)d_in[26],
        (const float*)d_in[27], (const float*)d_in[28],
        (const float*)d_in[31], (const float*)d_in[32],
        wtF, bFmod, wtH, bmH);
    mmx_kernel<F_IN, true, false, true, false, true, false><<<gridF, 256, 0, stream>>>(x, wtF, bFmod, nullptr, hb, nullptr, nullptr, N_NODES);

    // CSR build
    count_kernel<<<NEB, 256, 0, stream>>>(dstp, deg, cnt);
    scan1_kernel<<<nscan, 1024, 0, stream>>>(deg, stmp, spart, N_NODES);
    scan3_rowptr_kernel<<<nscan, 1024, 0, stream>>>(stmp, spart, deg, row_ptr, N_NODES, nscan);
    scan1_kernel<<<nscan2, 1024, 0, stream>>>(cnt, stmp2, spart2, ncb);
    scan3_kernel<<<nscan2, 1024, 0, stream>>>(stmp2, spart2, ofs, ncb, nscan2);
    distribute_kernel<<<NEB, 256, 0, stream>>>(srcp, dstp, ofs, ebuf);
    bucket_fill_kernel<<<NBUCK2, 256, 0, stream>>>(ebuf, ofs, row_ptr, csr);

    for (int l = 0; l < 3; l++) {
        const float* bw = (const float*)d_in[17 + 6 * l];
        const float* bb = (const float*)d_in[18 + 6 * l];
        u16*   wt1 = wtH + (size_t)(2 * l)     * 96 * HDIM;
        u16*   wt2 = wtH + (size_t)(2 * l + 1) * 96 * HDIM;
        float* b1m = bmH + (size_t)(2 * l)     * 96;
        float* b2m = bmH + (size_t)(2 * l + 1) * 96;
        // m = h + sum_nbr(h)  (bf16)
        agg_kernel<<<(N_NODES + 15) / 16, 192, 0, stream>>>(hb, row_ptr, csr, mb, N_NODES);
        // t = m @ W1 + b1  -> f32 tf (stats consistent with stored t)
        mmx_kernel<HDIM, false, false, false, true, false, false><<<grid96, 256, 0, stream>>>(mb, wt1, b1m, nullptr, tf, statsT[l], nullptr, N_NODES);
        finalize_bn_kernel<<<1, HDIM, 0, stream>>>(statsT[l], bw, bb, acT, HDIM, 1.0f / N_NODES);
        // h = relu( relu(BN(t_f32)) @ W2 + b2 ): BN applied in f32, one bf16 rounding
        if (l < 2) {
            mmx_kernel<HDIM, true, true, true, false, true, false><<<grid96, 256, 0, stream>>>(tf, wt2, b2m, acT, hb, nullptr, nullptr, N_NODES);
        } else {
            mmx_kernel<HDIM, true, true, true, false, false, true><<<grid96, 256, 0, stream>>>(tf, wt2, b2m, acT, g, nullptr, batch, N_NODES);
        }
    }

    // g1 = relu(BN_fc(g) @ Wl + bl), fused stats(g1)
    colstats_kernel<HDIM><<<64, 2 * HDIM, 0, stream>>>(g, statsG, N_GRAPHS);
    finalize_bn_kernel<<<1, HDIM, 0, stream>>>(statsG, bn_fc_w, bn_fc_b, acG, HDIM, 1.0f / N_GRAPHS);
    mm_kernel<HDIM, true, false, true, true><<<gridG, 192, 0, stream>>>(g, Wl, bl, acG, g1, statsG1, N_GRAPHS);
    finalize_bn_kernel<<<1, HDIM, 0, stream>>>(statsG1, bn_hid_w, bn_hid_b, acHid, HDIM, 1.0f / N_GRAPHS);

    head_kernel<<<2, 256, 0, stream>>>(g1, acHid, Wc, bc, out, N_GRAPHS);
}